// Round 8
// baseline (727.663 us; speedup 1.0000x reference)
//
#include <hip/hip_runtime.h>
#include <math.h>

// ---------------------------------------------------------------------------
// TreeEnergyLoss on MI355X.
// softmax -> k_edges (parallel chunked f64 edge distances via LDS-upsampled
// embeddings; ds_read2-friendly H/V edge loops; reg-resident taps) ->
// k_boruvka (512t: Boruvka MST under strict (dist,edge-idx) order ==
// reference's stable Kruskal) -> k_root (512t Euler-tour rooting via Wyllie
// list-ranking) -> k_filter0/k_filter123: pointer-doubling tree filters with
// ALL doubling state in LDS ping-pong buffers (R7 post-mortem: register
// version spilled to scratch, 133us at 0.07% VALU) -> ROI-masked L1 loss.
// ---------------------------------------------------------------------------

#define HH 48
#define WW 48
#define NN (HH*WW)          // 2304 nodes
#define EHH (HH*(WW-1))     // 2256 horizontal edges
#define EEE (2*EHH)         // 4512 edges
#define BB 8
#define KK 4
#define TPB 256
#define TPW 512             // boruvka kernel
#define TPR 512             // rooting kernel
#define TPF 256             // filter kernels
#define NH_PT 9             // edges per thread per orientation (2256/256 ceil)
#define ESLOT (4*NN)        // 9216 directed-edge slots
#define LVE (2*(NN-1))      // 4606 valid directed edges
#define SENTN 0xFFFFu

// per-problem structure record in ws (ints): node-indexed int4 (parent,w,depth,0) | maxdepth
#define SSTRIDE_W (4*NN+8)
#define PK_OFF 0
#define D_OFF (4*NN)

struct Tap { int o00,o01,o10,o11; float w00,w01,w10,w11; };

__device__ __forceinline__ Tap mk_tap(int r,int c,int sh,int sw){
  float sy=(float)sh/48.0f, sx=(float)sw/48.0f;          // exact (pow2 ratios)
  float ys=fmaxf(((float)r+0.5f)*sy-0.5f,0.0f);
  float xs=fmaxf(((float)c+0.5f)*sx-0.5f,0.0f);
  int y0=(int)ys; if(y0>sh-1) y0=sh-1;
  int x0=(int)xs; if(x0>sw-1) x0=sw-1;
  int y1=y0+1; if(y1>sh-1) y1=sh-1;
  int x1=x0+1; if(x1>sw-1) x1=sw-1;
  float wy=ys-(float)y0, wx=xs-(float)x0;
  Tap t;
  t.o00=y0*sw+x0; t.o01=y0*sw+x1; t.o10=y1*sw+x0; t.o11=y1*sw+x1;
  t.w00=(1.0f-wy)*(1.0f-wx); t.w01=(1.0f-wy)*wx;
  t.w10=wy*(1.0f-wx);        t.w11=wy*wx;
  return t;
}

__device__ __forceinline__ float tap_val(const float* __restrict__ p, const Tap& t){
  return t.w00*p[t.o00]+t.w01*p[t.o01]+t.w10*p[t.o10]+t.w11*p[t.o11];
}

// numpy edge order: horizontal (row-major) first, then vertical.
__device__ __forceinline__ void edge_uv(int e,int& u,int& v){
  if(e<EHH){ int r=e/(WW-1); int c=e-r*(WW-1); u=r*WW+c; v=u+1; }
  else     { int t=e-EHH; u=t; v=t+WW; }
}

__device__ __forceinline__ void pick_src(int f, const float* lowf, const float* hf1,
                                         const float* hf2, const float* hf3,
                                         const float*& src, int& sh, int& C){
  if(f==0){src=lowf; sh=192; C=3;}
  else if(f==1){src=hf1; sh=24; C=512;}
  else if(f==2){src=hf2; sh=12; C=512;}
  else        {src=hf3; sh=6;  C=512;}
}

// ---------------------------------------------------------------------------
__global__ __launch_bounds__(TPB) void k_prob(const float* __restrict__ preds,
                                              float* __restrict__ probf){
  int t=blockIdx.x*TPB+threadIdx.x;
  if(t>=BB*NN) return;
  int b=t/NN, i=t-b*NN;
  const float* p=preds+(size_t)b*KK*NN+i;
  float x0=p[0],x1=p[NN],x2=p[2*NN],x3=p[3*NN];
  float mx=fmaxf(fmaxf(x0,x1),fmaxf(x2,x3));
  float e0=expf(x0-mx),e1=expf(x1-mx),e2=expf(x2-mx),e3=expf(x3-mx);
  float s=((e0+e1)+(e2+e3));
  float* q=probf+(size_t)b*KK*NN+i;
  q[0]=e0/s; q[NN]=e1/s; q[2*NN]=e2/s; q[3*NN]=e3/s;
}

// ---------------------------------------------------------------------------
// Parallel edge-distance partials.  One block = (problem, channel-chunk).
// H/V split edge loops -> constant LDS offset deltas (+1 / +WW dwords) so the
// backend fuses the two reads per (edge,channel) into ds_read2_b32.
__global__ __launch_bounds__(TPB) void k_edges(
  const float* __restrict__ lowf, const float* __restrict__ hf1,
  const float* __restrict__ hf2, const float* __restrict__ hf3,
  double* __restrict__ pd_low, double* __restrict__ pd_hf, int nchunk)
{
  __shared__ float up[8*NN];   // 73728 B
  const int tid=threadIdx.x;
  int pidx, chunk, hfidx=0;
  if(blockIdx.x<8){ pidx=blockIdx.x; chunk=0; }
  else { int t=blockIdx.x-8; hfidx=t/nchunk; chunk=t-hfidx*nchunk; pidx=8+hfidx; }
  const int f=pidx>>3, b=pidx&7;
  const float* src; int sh,C;
  pick_src(f,lowf,hf1,hf2,hf3,src,sh,C);
  const int shw=sh*sh;
  const float* srcb=src+(size_t)b*C*shw;
  const int cpc=(f==0)?3:(512/nchunk);
  const int c_begin=chunk*cpc;
  const int c_end=(c_begin+cpc<C)?(c_begin+cpc):C;

  // taps for the 9 owned upsample nodes, once (reused across substages)
  Tap tp[9];
  #pragma unroll
  for(int k=0;k<9;k++){
    int i=tid+k*TPB;
    int r=i/WW;
    tp[k]=mk_tap(r,i-r*WW,sh,sh);
  }

  double accH[NH_PT], accV[NH_PT];
  #pragma unroll
  for(int j=0;j<NH_PT;j++){ accH[j]=0.0; accV[j]=0.0; }

  for(int c0=c_begin;c0<c_end;c0+=8){
    const int nc=(c_end-c0<8)?(c_end-c0):8;
    __syncthreads();               // protect previous sub-stage reads
    #pragma unroll
    for(int k=0;k<9;k++){
      int i=tid+k*TPB;
      const float* pl=srcb+(size_t)c0*shw;
      for(int c=0;c<nc;c++) up[c*NN+i]=tap_val(pl+(size_t)c*shw,tp[k]);
    }
    __syncthreads();
    if(nc==8){
      #pragma unroll
      for(int j=0;j<NH_PT;j++){
        int e=tid+j*TPB;
        if(e<EHH){
          int r=e/(WW-1); int u=r*WW+(e-r*(WW-1));
          const float* pu=up+u;
          #pragma unroll
          for(int c=0;c<8;c++){
            double d=(double)pu[c*NN]-(double)pu[c*NN+1];
            accH[j]=fma(d,d,accH[j]);
          }
        }
      }
      #pragma unroll
      for(int j=0;j<NH_PT;j++){
        int u=tid+j*TPB;
        if(u<EHH){                       // vertical edge index EHH+u
          const float* pu=up+u;
          #pragma unroll
          for(int c=0;c<8;c++){
            double d=(double)pu[c*NN]-(double)pu[c*NN+WW];
            accV[j]=fma(d,d,accV[j]);
          }
        }
      }
    } else {
      for(int j=0;j<NH_PT;j++){
        int e=tid+j*TPB;
        if(e<EHH){
          int r=e/(WW-1); int u=r*WW+(e-r*(WW-1));
          const float* pu=up+u;
          for(int c=0;c<nc;c++){
            double d=(double)pu[c*NN]-(double)pu[c*NN+1];
            accH[j]=fma(d,d,accH[j]);
          }
        }
      }
      for(int j=0;j<NH_PT;j++){
        int u=tid+j*TPB;
        if(u<EHH){
          const float* pu=up+u;
          for(int c=0;c<nc;c++){
            double d=(double)pu[c*NN]-(double)pu[c*NN+WW];
            accV[j]=fma(d,d,accV[j]);
          }
        }
      }
    }
  }
  double* outp=(f==0)? pd_low+(size_t)pidx*EEE
                     : pd_hf+((size_t)hfidx*nchunk+chunk)*EEE;
  #pragma unroll
  for(int j=0;j<NH_PT;j++){
    int e=tid+j*TPB;
    if(e<EHH){ outp[e]=accH[j]; outp[EHH+e]=accV[j]; }
  }
}

// ---------------------------------------------------------------------------
// 512-thread Boruvka per (forest,batch).
// Outputs per-node tree-adjacency mask (L,R,U,D bits) + per-direction weights.
__global__ __launch_bounds__(TPW) void k_boruvka(
  const double* __restrict__ pd_low, const double* __restrict__ pd_hf,
  int nchunk, float4* __restrict__ adjwG, unsigned char* __restrict__ adjG)
{
  __shared__ double dkey[EEE];                  // 36096 B
  __shared__ unsigned long long bestd[NN];      // 18432 B
  __shared__ int comp[NN];
  __shared__ int lnk[NN];
  __shared__ int beste[NN];
  __shared__ unsigned char mstf[EEE];
  __shared__ int flags[2];

  const int tid=threadIdx.x;
  const int pidx=blockIdx.x;
  const int f=pidx>>3;
  const float sigma=(f==0)?0.02f:1.0f;

  // ---- gather edge distances: fixed chunk order (deterministic) ----
  const double* p0=(f==0)? pd_low+(size_t)pidx*EEE
                         : pd_hf+((size_t)(pidx-8)*nchunk)*EEE;
  const int nck=(f==0)?1:nchunk;
  for(int e=tid;e<EEE;e+=TPW){
    double s=0.0;
    for(int k=0;k<nck;k++) s+=p0[(size_t)k*EEE+e];
    dkey[e]=s;
  }
  for(int i=tid;i<NN;i+=TPW) comp[i]=i;
  for(int e=tid;e<EEE;e+=TPW) mstf[e]=0;
  __syncthreads();

  // ---- Boruvka: unique MST under strict (dist_bits, edge_index) order ----
  for(int round=0;round<24;++round){
    for(int i=tid;i<NN;i+=TPW){ bestd[i]=~0ull; beste[i]=0x7fffffff; lnk[i]=i; }
    if(tid==0) flags[1]=0;
    __syncthreads();
    for(int e=tid;e<EEE;e+=TPW){
      int u,v; edge_uv(e,u,v);
      int cu=comp[u], cv=comp[v];
      if(cu!=cv){
        unsigned long long db=(unsigned long long)__double_as_longlong(dkey[e]);
        atomicMin(&bestd[cu],db);
        atomicMin(&bestd[cv],db);
      }
    }
    __syncthreads();
    for(int e=tid;e<EEE;e+=TPW){
      int u,v; edge_uv(e,u,v);
      int cu=comp[u], cv=comp[v];
      if(cu!=cv){
        unsigned long long db=(unsigned long long)__double_as_longlong(dkey[e]);
        if(db==bestd[cu]) atomicMin(&beste[cu],e);
        if(db==bestd[cv]) atomicMin(&beste[cv],e);
      }
    }
    __syncthreads();
    // hook (mutual pair resolved toward smaller id; mutual => SAME edge since order strict)
    for(int i=tid;i<NN;i+=TPW){
      if(comp[i]==i && beste[i]!=0x7fffffff){
        int e=beste[i]; int u,v; edge_uv(e,u,v);
        int cu=comp[u], cv=comp[v];
        int other=(cu==i)?cv:cu;
        bool mutual=(beste[other]==e);
        if(!mutual || other<i){ lnk[i]=other; mstf[e]=1; flags[1]=1; }
      }
    }
    __syncthreads();
    if(flags[1]==0) break;          // no hooks => forest complete
    // ---- racy barrier-free pointer jumping (monotone-convergent) ----
    {
      volatile int* vl=lnk;
      for(int it=0;it<12;++it){
        for(int i=tid;i<NN;i+=TPW){ int a=vl[i]; int b2=vl[a]; if(a!=b2) vl[i]=b2; }
      }
      for(;;){
        if(tid==0) flags[0]=0;
        __syncthreads();
        for(int i=tid;i<NN;i+=TPW){
          int a=vl[i]; int b2=vl[a];
          if(a!=b2){ vl[i]=b2; flags[0]=1; }
        }
        __syncthreads();
        int ch=flags[0];
        __syncthreads();
        if(!ch) break;
      }
    }
    for(int i=tid;i<NN;i+=TPW) comp[i]=lnk[comp[i]];
    __syncthreads();
  }

  // ---- emit per-node adjacency mask + per-direction weights ----
  for(int i=tid;i<NN;i+=TPW){
    int r=i/WW, c=i-r*WW;
    int mask=0; float4 w; w.x=0.0f; w.y=0.0f; w.z=0.0f; w.w=0.0f;
    if(c>0    && mstf[r*(WW-1)+c-1]){ mask|=1; w.x=expf(-(float)dkey[r*(WW-1)+c-1]/sigma); }
    if(c<WW-1 && mstf[r*(WW-1)+c])  { mask|=2; w.y=expf(-(float)dkey[r*(WW-1)+c]/sigma); }
    if(r>0    && mstf[EHH+i-WW])    { mask|=4; w.z=expf(-(float)dkey[EHH+i-WW]/sigma); }
    if(r<HH-1 && mstf[EHH+i])       { mask|=8; w.w=expf(-(float)dkey[EHH+i]/sigma); }
    adjwG[(size_t)pidx*NN+i]=w;
    adjG[(size_t)pidx*NN+i]=(unsigned char)mask;
  }
}

// ---------------------------------------------------------------------------
// 512-thread Euler-tour rooting via Wyllie list-ranking.
// Emits node-indexed int4 (parent, w_bits, depth, 0) + maxdepth.
__global__ __launch_bounds__(TPR) void k_root(
  const float4* __restrict__ adjwG, const unsigned char* __restrict__ adjG,
  int* __restrict__ sbase)
{
  __shared__ unsigned int eA[ESLOT];   // 36864 B  (ping: (nxt<<16)|dist)
  __shared__ unsigned int eB[ESLOT];   // 36864 B  (pong; later pos[])
  __shared__ float4 adjwS[NN];         // 36864 B
  __shared__ unsigned char adjS[NN];   // 2304 B
  __shared__ int chunkS[TPR];          // 2048 B
  __shared__ int maxdS;

  const int tid=threadIdx.x;
  const int pidx=blockIdx.x;
  {
    const float4* aw=adjwG+(size_t)pidx*NN;
    for(int t=tid;t<NN;t+=TPR) adjwS[t]=aw[t];
    const int* a4=(const int*)(adjG+(size_t)pidx*NN);
    int* s4=(int*)adjS;
    for(int t=tid;t<NN/4;t+=TPR) s4[t]=a4[t];
  }
  if(tid==0) maxdS=0;
  __syncthreads();

  const int m0=adjS[0];
  const int d0=(m0&1)?0:((m0&2)?1:((m0&4)?2:3));
  const int e0=d0;   // node 0 * 4 + d0

  // ---- build successor list, init dist=1 ----
  for(int t=tid;t<ESLOT;t+=TPR){
    int u=t>>2, d=t&3;
    unsigned int pk=0;                       // dist==0 marks invalid slot
    if(adjS[u]&(1<<d)){
      int v=(d==0)?u-1:(d==1)?u+1:(d==2)?u-WW:u+WW;
      int rd=d^1;
      int mv=adjS[v];
      int nd=rd;
      #pragma unroll
      for(int k2=4;k2>=1;k2--){ int dd=(rd+k2)&3; if(mv&(1<<dd)) nd=dd; }
      int ne=(v<<2)|nd;
      unsigned int nxt=(ne==e0)?SENTN:(unsigned int)ne;
      pk=(nxt<<16)|1u;
    }
    eA[t]=pk;
  }
  __syncthreads();

  // ---- Wyllie doubling: 13 rounds (2^13 >= 4606) ----
  unsigned int* P=eA; unsigned int* Q=eB;
  for(int r2=0;r2<13;r2++){
    for(int t=tid;t<ESLOT;t+=TPR){
      unsigned int pk=P[t];
      unsigned int dist=pk&0xFFFFu, nxt=pk>>16;
      if(dist && nxt!=SENTN){
        unsigned int pk2=P[nxt];
        dist+=pk2&0xFFFFu;
        nxt=pk2>>16;
        pk=(nxt<<16)|dist;
      }
      Q[t]=pk;
    }
    __syncthreads();
    unsigned int* tmp=P; P=Q; Q=tmp;
  }
  for(int t=tid;t<ESLOT;t+=TPR){
    unsigned int dist=P[t]&0xFFFFu;
    Q[t]=dist?(unsigned int)(LVE-(int)dist):0xFFFFFFFFu;
  }
  __syncthreads();

  // ---- scatter +-1 into scan array ----
  int* scanA=(int*)P;
  for(int t=tid;t<ESLOT;t+=TPR){
    unsigned int pos=Q[t];
    if(pos!=0xFFFFFFFFu){
      int u=t>>2, d=t&3;
      int v=(d==0)?u-1:(d==1)?u+1:(d==2)?u-WW:u+WW;
      unsigned int rpos=Q[(v<<2)|(d^1)];
      scanA[pos]=(pos<rpos)?1:-1;
    }
  }
  __syncthreads();

  // ---- blocked inclusive scan over scanA[0..LVE-1] ----
  const int base=tid*9;
  int vals[9]; int lsum=0;
  #pragma unroll
  for(int j=0;j<9;j++){
    int p=base+j;
    int v=(p<LVE)?scanA[p]:0;
    lsum+=v; vals[j]=lsum;
  }
  chunkS[tid]=lsum;
  __syncthreads();
  for(int off=1;off<TPR;off<<=1){
    int v=chunkS[tid];
    int vv=(tid>=off)?chunkS[tid-off]:0;
    __syncthreads();
    chunkS[tid]=v+vv;
    __syncthreads();
  }
  const int myoff=(tid>0)?chunkS[tid-1]:0;
  int mymax=0;
  #pragma unroll
  for(int j=0;j<9;j++){
    int p=base+j;
    if(p<LVE){ int s=vals[j]+myoff; scanA[p]=s; if(s>mymax) mymax=s; }
  }
  if(mymax>0) atomicMax(&maxdS,mymax);
  __syncthreads();

  // ---- emit per-node records ----
  int* sp=sbase+(size_t)pidx*SSTRIDE_W;
  int4* g_pk=(int4*)(sp+PK_OFF);
  if(tid==0){
    g_pk[0]=make_int4(0,__float_as_int(0.0f),0,0);
    sp[D_OFF]=maxdS;
  }
  for(int t=tid;t<ESLOT;t+=TPR){
    unsigned int pos=Q[t];
    if(pos!=0xFFFFFFFFu){
      int u=t>>2, d=t&3;
      int v=(d==0)?u-1:(d==1)?u+1:(d==2)?u-WW:u+WW;
      unsigned int rpos=Q[(v<<2)|(d^1)];
      if(pos<rpos){                       // down edge: u = parent(v)
        float4 w4=adjwS[u];
        float w=(d==0)?w4.x:(d==1)?w4.y:(d==2)?w4.z:w4.w;
        g_pk[v]=make_int4(u,__float_as_int(w),scanA[pos],0);
      }
    }
  }
}

// ---------------------------------------------------------------------------
// Pointer-doubling tree filter core, ALL state in LDS (no register arrays ->
// no scratch spills).  bufA/bufB are 5*NN ping-pong value buffers; ancL/prmL
// are the doubling tables; depS gates the upward scatter.
// Upward round t (semantics == R6): S_new = S_old + scatter(prod_t * S_old).
// Downward: affine (a,b) composition doubling, F = a*F_root + b.
// ---------------------------------------------------------------------------
#define FILTER_CORE(X_LOAD)                                                    \
  const int tid=threadIdx.x;                                                   \
  const int maxD=sp[D_OFF];                                                    \
  int T=1; while((1<<T)<=maxD) T++;                                            \
  const int4* g_pk=(const int4*)(sp+PK_OFF);                                   \
  for(int i=tid;i<NN;i+=TPF){                                                  \
    int4 rec=g_pk[i];                                                          \
    ancL[0][i]=rec.x; prmL[0][i]=__int_as_float(rec.y); depS[i]=rec.z;         \
  }                                                                            \
  { X_LOAD }                                                                   \
  __syncthreads();                                                             \
  float* Sp=bufA; float* Sq=bufB;                                              \
  int ping=0;                                                                  \
  for(int t=0;t<T;t++){                                                        \
    for(int t2=tid;t2<5*NN;t2+=TPF) Sq[t2]=Sp[t2];                             \
    __syncthreads();                                                           \
    int bit=1<<t;                                                              \
    for(int i=tid;i<NN;i+=TPF){                                                \
      int a=ancL[ping][i]; float pw=prmL[ping][i];                             \
      if(depS[i]>=bit){                                                        \
        atomicAdd(&Sq[a],      pw*Sp[i]);                                      \
        atomicAdd(&Sq[NN+a],   pw*Sp[NN+i]);                                   \
        atomicAdd(&Sq[2*NN+a], pw*Sp[2*NN+i]);                                 \
        atomicAdd(&Sq[3*NN+a], pw*Sp[3*NN+i]);                                 \
        atomicAdd(&Sq[4*NN+a], pw*Sp[4*NN+i]);                                 \
      }                                                                        \
      ancL[1-ping][i]=ancL[ping][a];                                           \
      prmL[1-ping][i]=pw*prmL[ping][a];                                        \
    }                                                                          \
    __syncthreads();                                                           \
    ping^=1; { float* tmp=Sp; Sp=Sq; Sq=tmp; }                                 \
  }                                                                            \
  /* Sp = A_up.  Downward init: b = (1-w^2)*A_up (root: w=0 -> b=A_up). */     \
  for(int i=tid;i<NN;i+=TPF){                                                  \
    int4 rec=g_pk[i];                                                          \
    float w=__int_as_float(rec.y); float fq=1.0f-w*w;                          \
    ancL[0][i]=rec.x; prmL[0][i]=w;                                            \
    Sq[i]     =fq*Sp[i];      Sq[NN+i]  =fq*Sp[NN+i];                          \
    Sq[2*NN+i]=fq*Sp[2*NN+i]; Sq[3*NN+i]=fq*Sp[3*NN+i];                        \
    Sq[4*NN+i]=fq*Sp[4*NN+i];                                                  \
  }                                                                            \
  __syncthreads();                                                             \
  ping=0; { float* tmp=Sp; Sp=Sq; Sq=tmp; }   /* Sp=b, Sq=dead A_up */         \
  for(int t=0;t<T;t++){                                                        \
    for(int i=tid;i<NN;i+=TPF){                                                \
      int a=ancL[ping][i]; float ai=prmL[ping][i];                             \
      Sq[i]     =fmaf(ai,Sp[a],      Sp[i]);                                   \
      Sq[NN+i]  =fmaf(ai,Sp[NN+a],   Sp[NN+i]);                                \
      Sq[2*NN+i]=fmaf(ai,Sp[2*NN+a], Sp[2*NN+i]);                              \
      Sq[3*NN+i]=fmaf(ai,Sp[3*NN+a], Sp[3*NN+i]);                              \
      Sq[4*NN+i]=fmaf(ai,Sp[4*NN+a], Sp[4*NN+i]);                              \
      ancL[1-ping][i]=ancL[ping][a];                                           \
      prmL[1-ping][i]=ai*prmL[ping][a];                                        \
    }                                                                          \
    __syncthreads();                                                           \
    ping^=1; { float* tmp=Sp; Sp=Sq; Sq=tmp; }                                 \
  }                                                                            \
  const float r0=Sp[0],r1=Sp[NN],r2=Sp[2*NN],r3=Sp[3*NN],r4=Sp[4*NN];          \
  float* aFin=prmL[ping]; float* bFin=Sp;

// ---------------------------------------------------------------------------
__global__ __launch_bounds__(TPF) void k_filter0(
  const float* __restrict__ probf, const int* __restrict__ sbase,
  float* __restrict__ AS)
{
  __shared__ float bufA[5*NN];   // 46080 B
  __shared__ float bufB[5*NN];   // 46080 B
  __shared__ int   ancL[2][NN];  // 18432 B
  __shared__ float prmL[2][NN];  // 18432 B
  __shared__ int   depS[NN];     // 9216 B
  const int b=blockIdx.x;
  const int* sp=sbase+(size_t)b*SSTRIDE_W;
  FILTER_CORE(
    const float4* pf4=(const float4*)(probf+(size_t)b*KK*NN);
    float4* S4=(float4*)bufA;
    for(int t2=tid;t2<(KK*NN)/4;t2+=TPF) S4[t2]=pf4[t2];
    for(int t2=KK*NN+tid;t2<5*NN;t2+=TPF) bufA[t2]=1.0f;
  )
  float* o=AS+(size_t)b*KK*NN;
  for(int i=tid;i<NN;i+=TPF){
    float aF=aFin[i];
    float F4=fmaf(aF,r4,bFin[4*NN+i]);
    float inv=1.0f/F4;
    o[i]     =fmaf(aF,r0,bFin[i])*inv;
    o[NN+i]  =fmaf(aF,r1,bFin[NN+i])*inv;
    o[2*NN+i]=fmaf(aF,r2,bFin[2*NN+i])*inv;
    o[3*NN+i]=fmaf(aF,r3,bFin[3*NN+i])*inv;
  }
}

// ---------------------------------------------------------------------------
__global__ __launch_bounds__(TPF) void k_filter123(
  const float* __restrict__ AS, const float* __restrict__ probf,
  const float* __restrict__ rois, const int* __restrict__ sbase,
  float* __restrict__ partials)
{
  __shared__ float bufA[5*NN];
  __shared__ float bufB[5*NN];
  __shared__ int   ancL[2][NN];
  __shared__ float prmL[2][NN];
  __shared__ int   depS[NN];
  __shared__ float red[TPF];
  const int fm1=blockIdx.x/BB, b=blockIdx.x%BB;
  const int pidx=(fm1+1)*BB+b;
  const int* sp=sbase+(size_t)pidx*SSTRIDE_W;
  FILTER_CORE(
    const float4* pf4=(const float4*)(AS+(size_t)b*KK*NN);
    float4* S4=(float4*)bufA;
    for(int t2=tid;t2<(KK*NN)/4;t2+=TPF) S4[t2]=pf4[t2];
    for(int t2=KK*NN+tid;t2<5*NN;t2+=TPF) bufA[t2]=1.0f;
  )
  float part=0.0f;
  const float* pb=probf+(size_t)b*KK*NN;
  for(int i=tid;i<NN;i+=TPF){
    int r=i/WW, c2=i-r*WW;
    float roi=rois[(size_t)b*(192*192)+(4*r)*192+(4*c2)];
    float aF=aFin[i];
    float F4=fmaf(aF,r4,bFin[4*NN+i]);
    float inv=1.0f/F4;
    float s=fabsf(pb[i]      - fmaf(aF,r0,bFin[i])*inv)
          + fabsf(pb[NN+i]   - fmaf(aF,r1,bFin[NN+i])*inv)
          + fabsf(pb[2*NN+i] - fmaf(aF,r2,bFin[2*NN+i])*inv)
          + fabsf(pb[3*NN+i] - fmaf(aF,r3,bFin[3*NN+i])*inv);
    part+=roi*s;
  }
  red[tid]=part; __syncthreads();
  for(int s2=TPF/2;s2>0;s2>>=1){ if(tid<s2) red[tid]+=red[tid+s2]; __syncthreads(); }
  if(tid==0) partials[blockIdx.x]=red[0];
}

// ---------------------------------------------------------------------------
__global__ __launch_bounds__(TPB) void k_final(const float* __restrict__ rois,
    const float* __restrict__ partials, const float* __restrict__ wt,
    float* __restrict__ out)
{
  __shared__ float red[TPB];
  const int tid=threadIdx.x;
  float n=0.0f;
  for(int t=tid;t<BB*NN;t+=TPB){
    int b=t/NN, i=t-b*NN; int r=i/WW, c=i-r*WW;
    n += rois[(size_t)b*(192*192)+(4*r)*192+(4*c)];
  }
  red[tid]=n; __syncthreads();
  for(int s=TPB/2;s>0;s>>=1){ if(tid<s) red[tid]+=red[tid+s]; __syncthreads(); }
  if(tid==0){
    float loss=0.0f;
    for(int j=0;j<3*BB;j++) loss+=partials[j];
    float N=red[0];
    out[0]=wt[0]*((N>0.0f)?(loss/N):loss);
  }
}

// ---------------------------------------------------------------------------
extern "C" void kernel_launch(void* const* d_in, const int* in_sizes, int n_in,
                              void* d_out, int out_size, void* d_ws, size_t ws_size,
                              hipStream_t stream) {
  (void)in_sizes; (void)n_in; (void)out_size;
  const float* preds=(const float*)d_in[0];
  const float* lowf =(const float*)d_in[1];
  const float* hf1  =(const float*)d_in[2];
  const float* hf2  =(const float*)d_in[3];
  const float* hf3  =(const float*)d_in[4];
  const float* rois =(const float*)d_in[5];
  const float* wt   =(const float*)d_in[6];
  float* out=(float*)d_out;

  char* ws=(char*)d_ws;
  float* partials=(float*)ws;                                  // 24 floats @0
  float* probf=(float*)(ws+256);                               // 294912 B
  float* AS   =(float*)(ws+256+(size_t)BB*KK*NN*4);            // 294912 B
  size_t sb_off=256+(size_t)2*BB*KK*NN*4;                      // 590080
  int*   sbase=(int*)(ws+sb_off);                              // 1,180,672 B
  size_t aw_off=sb_off+(size_t)32*SSTRIDE_W*4;                 // 1,770,752
  float4* adjwG=(float4*)(ws+aw_off);                          // 1,179,648 B
  size_t aj_off=aw_off+(size_t)32*NN*16;                       // 2,950,400
  unsigned char* adjG=(unsigned char*)(ws+aj_off);             // 73,728 B
  size_t pl_off=aj_off+(size_t)32*NN;                          // 3,024,128 (8-mult)
  double* pd_low=(double*)(ws+pl_off);                         // 8*EEE*8 = 288,768 B
  size_t ph_off=pl_off+(size_t)8*EEE*8;                        // 3,312,896
  double* pd_hf=(double*)(ws+ph_off);                          // 24*nchunk*EEE*8

  int nchunk=32;
  while(nchunk>1 && ph_off+(size_t)24*nchunk*EEE*8>ws_size) nchunk>>=1;

  k_prob<<<(BB*NN+TPB-1)/TPB,TPB,0,stream>>>(preds,probf);
  k_edges<<<8+24*nchunk,TPB,0,stream>>>(lowf,hf1,hf2,hf3,pd_low,pd_hf,nchunk);
  k_boruvka<<<32,TPW,0,stream>>>(pd_low,pd_hf,nchunk,adjwG,adjG);
  k_root<<<32,TPR,0,stream>>>(adjwG,adjG,sbase);
  k_filter0<<<BB,TPF,0,stream>>>(probf,sbase,AS);
  k_filter123<<<3*BB,TPF,0,stream>>>(AS,probf,rois,sbase,partials);
  k_final<<<1,TPB,0,stream>>>(rois,partials,wt,out);
}

// Round 9
// 591.236 us; speedup vs baseline: 1.2307x; 1.2307x over previous
//
#include <hip/hip_runtime.h>
#include <math.h>

// ---------------------------------------------------------------------------
// TreeEnergyLoss on MI355X.
// softmax -> k_edges (parallel chunked f64 edge distances via LDS-upsampled
// embeddings; 4-channel substages for 4 blocks/CU; H/V const-offset loops;
// taps recomputed per substage -- R8 post-mortem: hoisted taps spilled) ->
// k_boruvka (512t Boruvka MST under strict (dist,edge-idx) order ==
// reference's stable Kruskal) -> k_root (512t Euler-tour rooting via Wyllie
// list-ranking) -> pointer-doubling tree filters (upward: register-snapshot
// + in-place LDS atomic scatter, no per-round copy; downward: copy-free
// affine ping-pong) -> ROI-masked L1 loss.
// ---------------------------------------------------------------------------

#define HH 48
#define WW 48
#define NN (HH*WW)          // 2304 nodes
#define EHH (HH*(WW-1))     // 2256 horizontal edges
#define EEE (2*EHH)         // 4512 edges
#define BB 8
#define KK 4
#define TPB 256
#define TPW 512             // boruvka kernel
#define TPR 512             // rooting kernel
#define TPF 256             // filter kernels
#define NPL 9               // nodes per lane in filters (2304/256)
#define NH_PT 9             // edges per thread per orientation (2256/256 ceil)
#define ESLOT (4*NN)        // 9216 directed-edge slots
#define LVE (2*(NN-1))      // 4606 valid directed edges
#define SENTN 0xFFFFu
#define NCHUNK 16

// per-problem structure record in ws (ints): node-indexed int4 (parent,w,depth,0) | maxdepth
#define SSTRIDE_W (4*NN+8)
#define PK_OFF 0
#define D_OFF (4*NN)

struct Tap { int o00,o01,o10,o11; float w00,w01,w10,w11; };

__device__ __forceinline__ Tap mk_tap(int r,int c,int sh,int sw){
  float sy=(float)sh/48.0f, sx=(float)sw/48.0f;          // exact (pow2 ratios)
  float ys=fmaxf(((float)r+0.5f)*sy-0.5f,0.0f);
  float xs=fmaxf(((float)c+0.5f)*sx-0.5f,0.0f);
  int y0=(int)ys; if(y0>sh-1) y0=sh-1;
  int x0=(int)xs; if(x0>sw-1) x0=sw-1;
  int y1=y0+1; if(y1>sh-1) y1=sh-1;
  int x1=x0+1; if(x1>sw-1) x1=sw-1;
  float wy=ys-(float)y0, wx=xs-(float)x0;
  Tap t;
  t.o00=y0*sw+x0; t.o01=y0*sw+x1; t.o10=y1*sw+x0; t.o11=y1*sw+x1;
  t.w00=(1.0f-wy)*(1.0f-wx); t.w01=(1.0f-wy)*wx;
  t.w10=wy*(1.0f-wx);        t.w11=wy*wx;
  return t;
}

__device__ __forceinline__ float tap_val(const float* __restrict__ p, const Tap& t){
  return t.w00*p[t.o00]+t.w01*p[t.o01]+t.w10*p[t.o10]+t.w11*p[t.o11];
}

// numpy edge order: horizontal (row-major) first, then vertical.
__device__ __forceinline__ void edge_uv(int e,int& u,int& v){
  if(e<EHH){ int r=e/(WW-1); int c=e-r*(WW-1); u=r*WW+c; v=u+1; }
  else     { int t=e-EHH; u=t; v=t+WW; }
}

__device__ __forceinline__ void pick_src(int f, const float* lowf, const float* hf1,
                                         const float* hf2, const float* hf3,
                                         const float*& src, int& sh, int& C){
  if(f==0){src=lowf; sh=192; C=3;}
  else if(f==1){src=hf1; sh=24; C=512;}
  else if(f==2){src=hf2; sh=12; C=512;}
  else        {src=hf3; sh=6;  C=512;}
}

// ---------------------------------------------------------------------------
__global__ __launch_bounds__(TPB) void k_prob(const float* __restrict__ preds,
                                              float* __restrict__ probf){
  int t=blockIdx.x*TPB+threadIdx.x;
  if(t>=BB*NN) return;
  int b=t/NN, i=t-b*NN;
  const float* p=preds+(size_t)b*KK*NN+i;
  float x0=p[0],x1=p[NN],x2=p[2*NN],x3=p[3*NN];
  float mx=fmaxf(fmaxf(x0,x1),fmaxf(x2,x3));
  float e0=expf(x0-mx),e1=expf(x1-mx),e2=expf(x2-mx),e3=expf(x3-mx);
  float s=((e0+e1)+(e2+e3));
  float* q=probf+(size_t)b*KK*NN+i;
  q[0]=e0/s; q[NN]=e1/s; q[2*NN]=e2/s; q[3*NN]=e3/s;
}

// ---------------------------------------------------------------------------
// Parallel edge-distance partials.  One block = (problem, channel-chunk).
// 4-channel substages (36 KB LDS -> 4 blocks/CU).  Taps recomputed per
// substage (keeps VGPR ~90, no scratch).  Per-edge channel accumulation is
// ascending within a chunk -> dkey bit-identical to prior rounds.
__global__ __launch_bounds__(TPB) void k_edges(
  const float* __restrict__ lowf, const float* __restrict__ hf1,
  const float* __restrict__ hf2, const float* __restrict__ hf3,
  double* __restrict__ pd_low, double* __restrict__ pd_hf)
{
  __shared__ float up[4*NN];   // 36864 B
  const int tid=threadIdx.x;
  int pidx, chunk, hfidx=0;
  if(blockIdx.x<8){ pidx=blockIdx.x; chunk=0; }
  else { int t=blockIdx.x-8; hfidx=t/NCHUNK; chunk=t-hfidx*NCHUNK; pidx=8+hfidx; }
  const int f=pidx>>3, b=pidx&7;
  const float* src; int sh,C;
  pick_src(f,lowf,hf1,hf2,hf3,src,sh,C);
  const int shw=sh*sh;
  const float* srcb=src+(size_t)b*C*shw;
  const int cpc=(f==0)?3:(512/NCHUNK);
  const int c_begin=chunk*cpc;
  const int c_end=(c_begin+cpc<C)?(c_begin+cpc):C;

  double accH[NH_PT], accV[NH_PT];
  #pragma unroll
  for(int j=0;j<NH_PT;j++){ accH[j]=0.0; accV[j]=0.0; }

  for(int c0=c_begin;c0<c_end;c0+=4){
    const int nc=(c_end-c0<4)?(c_end-c0):4;
    __syncthreads();               // protect previous sub-stage reads
    for(int i=tid;i<NN;i+=TPB){
      int r=i/WW;
      Tap t=mk_tap(r,i-r*WW,sh,sh);
      const float* pl=srcb+(size_t)c0*shw;
      for(int c=0;c<nc;c++) up[c*NN+i]=tap_val(pl+(size_t)c*shw,t);
    }
    __syncthreads();
    for(int j=0;j<NH_PT;j++){
      int e=tid+j*TPB;
      if(e<EHH){
        int r=e/(WW-1); int u=r*WW+(e-r*(WW-1));
        const float* pu=up+u;
        for(int c=0;c<nc;c++){
          double d=(double)pu[c*NN]-(double)pu[c*NN+1];
          accH[j]=fma(d,d,accH[j]);
        }
      }
    }
    for(int j=0;j<NH_PT;j++){
      int u=tid+j*TPB;
      if(u<EHH){                       // vertical edge index EHH+u
        const float* pu=up+u;
        for(int c=0;c<nc;c++){
          double d=(double)pu[c*NN]-(double)pu[c*NN+WW];
          accV[j]=fma(d,d,accV[j]);
        }
      }
    }
  }
  double* outp=(f==0)? pd_low+(size_t)pidx*EEE
                     : pd_hf+((size_t)hfidx*NCHUNK+chunk)*EEE;
  #pragma unroll
  for(int j=0;j<NH_PT;j++){
    int e=tid+j*TPB;
    if(e<EHH){ outp[e]=accH[j]; outp[EHH+e]=accV[j]; }
  }
}

// ---------------------------------------------------------------------------
// 512-thread Boruvka per (forest,batch).
// Outputs per-node tree-adjacency mask (L,R,U,D bits) + per-direction weights.
__global__ __launch_bounds__(TPW) void k_boruvka(
  const double* __restrict__ pd_low, const double* __restrict__ pd_hf,
  float4* __restrict__ adjwG, unsigned char* __restrict__ adjG)
{
  __shared__ double dkey[EEE];                  // 36096 B
  __shared__ unsigned long long bestd[NN];      // 18432 B
  __shared__ int comp[NN];
  __shared__ int lnk[NN];
  __shared__ int beste[NN];
  __shared__ unsigned char mstf[EEE];
  __shared__ int flags[2];

  const int tid=threadIdx.x;
  const int pidx=blockIdx.x;
  const int f=pidx>>3;
  const float sigma=(f==0)?0.02f:1.0f;

  // ---- gather edge distances: fixed chunk order (deterministic) ----
  const double* p0=(f==0)? pd_low+(size_t)pidx*EEE
                         : pd_hf+((size_t)(pidx-8)*NCHUNK)*EEE;
  const int nck=(f==0)?1:NCHUNK;
  for(int e=tid;e<EEE;e+=TPW){
    double s=0.0;
    for(int k=0;k<nck;k++) s+=p0[(size_t)k*EEE+e];
    dkey[e]=s;
  }
  for(int i=tid;i<NN;i+=TPW) comp[i]=i;
  for(int e=tid;e<EEE;e+=TPW) mstf[e]=0;
  __syncthreads();

  // ---- Boruvka: unique MST under strict (dist_bits, edge_index) order ----
  for(int round=0;round<24;++round){
    for(int i=tid;i<NN;i+=TPW){ bestd[i]=~0ull; beste[i]=0x7fffffff; lnk[i]=i; }
    if(tid==0) flags[1]=0;
    __syncthreads();
    for(int e=tid;e<EEE;e+=TPW){
      int u,v; edge_uv(e,u,v);
      int cu=comp[u], cv=comp[v];
      if(cu!=cv){
        unsigned long long db=(unsigned long long)__double_as_longlong(dkey[e]);
        atomicMin(&bestd[cu],db);
        atomicMin(&bestd[cv],db);
      }
    }
    __syncthreads();
    for(int e=tid;e<EEE;e+=TPW){
      int u,v; edge_uv(e,u,v);
      int cu=comp[u], cv=comp[v];
      if(cu!=cv){
        unsigned long long db=(unsigned long long)__double_as_longlong(dkey[e]);
        if(db==bestd[cu]) atomicMin(&beste[cu],e);
        if(db==bestd[cv]) atomicMin(&beste[cv],e);
      }
    }
    __syncthreads();
    // hook (mutual pair resolved toward smaller id; mutual => SAME edge since order strict)
    for(int i=tid;i<NN;i+=TPW){
      if(comp[i]==i && beste[i]!=0x7fffffff){
        int e=beste[i]; int u,v; edge_uv(e,u,v);
        int cu=comp[u], cv=comp[v];
        int other=(cu==i)?cv:cu;
        bool mutual=(beste[other]==e);
        if(!mutual || other<i){ lnk[i]=other; mstf[e]=1; flags[1]=1; }
      }
    }
    __syncthreads();
    if(flags[1]==0) break;          // no hooks => forest complete
    // ---- racy barrier-free pointer jumping (monotone-convergent) ----
    {
      volatile int* vl=lnk;
      for(int it=0;it<12;++it){
        for(int i=tid;i<NN;i+=TPW){ int a=vl[i]; int b2=vl[a]; if(a!=b2) vl[i]=b2; }
      }
      for(;;){
        if(tid==0) flags[0]=0;
        __syncthreads();
        for(int i=tid;i<NN;i+=TPW){
          int a=vl[i]; int b2=vl[a];
          if(a!=b2){ vl[i]=b2; flags[0]=1; }
        }
        __syncthreads();
        int ch=flags[0];
        __syncthreads();
        if(!ch) break;
      }
    }
    for(int i=tid;i<NN;i+=TPW) comp[i]=lnk[comp[i]];
    __syncthreads();
  }

  // ---- emit per-node adjacency mask + per-direction weights ----
  for(int i=tid;i<NN;i+=TPW){
    int r=i/WW, c=i-r*WW;
    int mask=0; float4 w; w.x=0.0f; w.y=0.0f; w.z=0.0f; w.w=0.0f;
    if(c>0    && mstf[r*(WW-1)+c-1]){ mask|=1; w.x=expf(-(float)dkey[r*(WW-1)+c-1]/sigma); }
    if(c<WW-1 && mstf[r*(WW-1)+c])  { mask|=2; w.y=expf(-(float)dkey[r*(WW-1)+c]/sigma); }
    if(r>0    && mstf[EHH+i-WW])    { mask|=4; w.z=expf(-(float)dkey[EHH+i-WW]/sigma); }
    if(r<HH-1 && mstf[EHH+i])       { mask|=8; w.w=expf(-(float)dkey[EHH+i]/sigma); }
    adjwG[(size_t)pidx*NN+i]=w;
    adjG[(size_t)pidx*NN+i]=(unsigned char)mask;
  }
}

// ---------------------------------------------------------------------------
// 512-thread Euler-tour rooting via Wyllie list-ranking.
// Emits node-indexed int4 (parent, w_bits, depth, 0) + maxdepth.
__global__ __launch_bounds__(TPR) void k_root(
  const float4* __restrict__ adjwG, const unsigned char* __restrict__ adjG,
  int* __restrict__ sbase)
{
  __shared__ unsigned int eA[ESLOT];   // 36864 B  (ping: (nxt<<16)|dist)
  __shared__ unsigned int eB[ESLOT];   // 36864 B  (pong; later pos[])
  __shared__ float4 adjwS[NN];         // 36864 B
  __shared__ unsigned char adjS[NN];   // 2304 B
  __shared__ int chunkS[TPR];          // 2048 B
  __shared__ int maxdS;

  const int tid=threadIdx.x;
  const int pidx=blockIdx.x;
  {
    const float4* aw=adjwG+(size_t)pidx*NN;
    for(int t=tid;t<NN;t+=TPR) adjwS[t]=aw[t];
    const int* a4=(const int*)(adjG+(size_t)pidx*NN);
    int* s4=(int*)adjS;
    for(int t=tid;t<NN/4;t+=TPR) s4[t]=a4[t];
  }
  if(tid==0) maxdS=0;
  __syncthreads();

  const int m0=adjS[0];
  const int d0=(m0&1)?0:((m0&2)?1:((m0&4)?2:3));
  const int e0=d0;   // node 0 * 4 + d0

  // ---- build successor list, init dist=1 ----
  for(int t=tid;t<ESLOT;t+=TPR){
    int u=t>>2, d=t&3;
    unsigned int pk=0;                       // dist==0 marks invalid slot
    if(adjS[u]&(1<<d)){
      int v=(d==0)?u-1:(d==1)?u+1:(d==2)?u-WW:u+WW;
      int rd=d^1;
      int mv=adjS[v];
      int nd=rd;
      #pragma unroll
      for(int k2=4;k2>=1;k2--){ int dd=(rd+k2)&3; if(mv&(1<<dd)) nd=dd; }
      int ne=(v<<2)|nd;
      unsigned int nxt=(ne==e0)?SENTN:(unsigned int)ne;
      pk=(nxt<<16)|1u;
    }
    eA[t]=pk;
  }
  __syncthreads();

  // ---- Wyllie doubling: 13 rounds (2^13 >= 4606) ----
  unsigned int* P=eA; unsigned int* Q=eB;
  for(int r2=0;r2<13;r2++){
    for(int t=tid;t<ESLOT;t+=TPR){
      unsigned int pk=P[t];
      unsigned int dist=pk&0xFFFFu, nxt=pk>>16;
      if(dist && nxt!=SENTN){
        unsigned int pk2=P[nxt];
        dist+=pk2&0xFFFFu;
        nxt=pk2>>16;
        pk=(nxt<<16)|dist;
      }
      Q[t]=pk;
    }
    __syncthreads();
    unsigned int* tmp=P; P=Q; Q=tmp;
  }
  for(int t=tid;t<ESLOT;t+=TPR){
    unsigned int dist=P[t]&0xFFFFu;
    Q[t]=dist?(unsigned int)(LVE-(int)dist):0xFFFFFFFFu;
  }
  __syncthreads();

  // ---- scatter +-1 into scan array ----
  int* scanA=(int*)P;
  for(int t=tid;t<ESLOT;t+=TPR){
    unsigned int pos=Q[t];
    if(pos!=0xFFFFFFFFu){
      int u=t>>2, d=t&3;
      int v=(d==0)?u-1:(d==1)?u+1:(d==2)?u-WW:u+WW;
      unsigned int rpos=Q[(v<<2)|(d^1)];
      scanA[pos]=(pos<rpos)?1:-1;
    }
  }
  __syncthreads();

  // ---- blocked inclusive scan over scanA[0..LVE-1] ----
  const int base=tid*9;
  int vals[9]; int lsum=0;
  #pragma unroll
  for(int j=0;j<9;j++){
    int p=base+j;
    int v=(p<LVE)?scanA[p]:0;
    lsum+=v; vals[j]=lsum;
  }
  chunkS[tid]=lsum;
  __syncthreads();
  for(int off=1;off<TPR;off<<=1){
    int v=chunkS[tid];
    int vv=(tid>=off)?chunkS[tid-off]:0;
    __syncthreads();
    chunkS[tid]=v+vv;
    __syncthreads();
  }
  const int myoff=(tid>0)?chunkS[tid-1]:0;
  int mymax=0;
  #pragma unroll
  for(int j=0;j<9;j++){
    int p=base+j;
    if(p<LVE){ int s=vals[j]+myoff; scanA[p]=s; if(s>mymax) mymax=s; }
  }
  if(mymax>0) atomicMax(&maxdS,mymax);
  __syncthreads();

  // ---- emit per-node records ----
  int* sp=sbase+(size_t)pidx*SSTRIDE_W;
  int4* g_pk=(int4*)(sp+PK_OFF);
  if(tid==0){
    g_pk[0]=make_int4(0,__float_as_int(0.0f),0,0);
    sp[D_OFF]=maxdS;
  }
  for(int t=tid;t<ESLOT;t+=TPR){
    unsigned int pos=Q[t];
    if(pos!=0xFFFFFFFFu){
      int u=t>>2, d=t&3;
      int v=(d==0)?u-1:(d==1)?u+1:(d==2)?u-WW:u+WW;
      unsigned int rpos=Q[(v<<2)|(d^1)];
      if(pos<rpos){                       // down edge: u = parent(v)
        float4 w4=adjwS[u];
        float w=(d==0)?w4.x:(d==1)?w4.y:(d==2)?w4.z:w4.w;
        g_pk[v]=make_int4(u,__float_as_int(w),scanA[pos],0);
      }
    }
  }
}

// ---------------------------------------------------------------------------
// Pointer-doubling tree filter core.
// Upward round t: register snapshot of own 5x9 values -> barrier -> in-place
// atomicAdd scatter to 2^t-ancestor (dep-gated) + table doubling in LDS.
// (No per-round full-buffer copy; snapshot is round-scoped so no spills.)
// Downward: affine (a,b) composition doubling, copy-free ping-pong.
// ---------------------------------------------------------------------------
#define FILTER_CORE(X_LOAD)                                                    \
  const int tid=threadIdx.x;                                                   \
  const int maxD=sp[D_OFF];                                                    \
  int T=1; while((1<<T)<=maxD) T++;                                            \
  const int4* g_pk=(const int4*)(sp+PK_OFF);                                   \
  for(int i=tid;i<NN;i+=TPF){                                                  \
    int4 rec=g_pk[i];                                                          \
    ancL[0][i]=rec.x; prmL[0][i]=__int_as_float(rec.y); depS[i]=rec.z;         \
  }                                                                            \
  { X_LOAD }                                                                   \
  __syncthreads();                                                             \
  int ping=0;                                                                  \
  for(int t=0;t<T;t++){                                                        \
    float s0[NPL],s1[NPL],s2[NPL],s3[NPL],s4[NPL];                             \
    int aJ[NPL]; float pwJ[NPL]; int dpJ[NPL];                                 \
    _Pragma("unroll")                                                          \
    for(int j=0;j<NPL;j++){                                                    \
      int i=tid+j*TPF;                                                         \
      s0[j]=S[i]; s1[j]=S[NN+i]; s2[j]=S[2*NN+i];                              \
      s3[j]=S[3*NN+i]; s4[j]=S[4*NN+i];                                        \
      aJ[j]=ancL[ping][i]; pwJ[j]=prmL[ping][i]; dpJ[j]=depS[i];               \
    }                                                                          \
    __syncthreads();                                                           \
    int bit=1<<t;                                                              \
    _Pragma("unroll")                                                          \
    for(int j=0;j<NPL;j++){                                                    \
      int i=tid+j*TPF; int a=aJ[j]; float pw=pwJ[j];                           \
      if(dpJ[j]>=bit){                                                         \
        atomicAdd(&S[a],      pw*s0[j]);                                       \
        atomicAdd(&S[NN+a],   pw*s1[j]);                                       \
        atomicAdd(&S[2*NN+a], pw*s2[j]);                                       \
        atomicAdd(&S[3*NN+a], pw*s3[j]);                                       \
        atomicAdd(&S[4*NN+a], pw*s4[j]);                                       \
      }                                                                        \
      ancL[1-ping][i]=ancL[ping][a];                                           \
      prmL[1-ping][i]=pw*prmL[ping][a];                                        \
    }                                                                          \
    __syncthreads();                                                           \
    ping^=1;                                                                   \
  }                                                                            \
  /* S = A_up.  Downward init: b = (1-w^2)*A_up (root: w=0 -> b=A_up). */      \
  for(int i=tid;i<NN;i+=TPF){                                                  \
    int4 rec=g_pk[i];                                                          \
    float w=__int_as_float(rec.y); float fq=1.0f-w*w;                          \
    ancL[0][i]=rec.x; prmL[0][i]=w;                                            \
    bufB[i]     =fq*S[i];      bufB[NN+i]  =fq*S[NN+i];                        \
    bufB[2*NN+i]=fq*S[2*NN+i]; bufB[3*NN+i]=fq*S[3*NN+i];                      \
    bufB[4*NN+i]=fq*S[4*NN+i];                                                 \
  }                                                                            \
  __syncthreads();                                                             \
  ping=0;                                                                      \
  float* Sp=bufB; float* Sq=S;                                                 \
  for(int t=0;t<T;t++){                                                        \
    for(int i=tid;i<NN;i+=TPF){                                                \
      int a=ancL[ping][i]; float ai=prmL[ping][i];                             \
      Sq[i]     =fmaf(ai,Sp[a],      Sp[i]);                                   \
      Sq[NN+i]  =fmaf(ai,Sp[NN+a],   Sp[NN+i]);                                \
      Sq[2*NN+i]=fmaf(ai,Sp[2*NN+a], Sp[2*NN+i]);                              \
      Sq[3*NN+i]=fmaf(ai,Sp[3*NN+a], Sp[3*NN+i]);                              \
      Sq[4*NN+i]=fmaf(ai,Sp[4*NN+a], Sp[4*NN+i]);                              \
      ancL[1-ping][i]=ancL[ping][a];                                           \
      prmL[1-ping][i]=ai*prmL[ping][a];                                        \
    }                                                                          \
    __syncthreads();                                                           \
    ping^=1; { float* tmp=Sp; Sp=Sq; Sq=tmp; }                                 \
  }                                                                            \
  const float r0=Sp[0],r1=Sp[NN],r2=Sp[2*NN],r3=Sp[3*NN],r4=Sp[4*NN];          \
  float* aFin=prmL[ping]; float* bFin=Sp;

// ---------------------------------------------------------------------------
__global__ __launch_bounds__(TPF) void k_filter0(
  const float* __restrict__ probf, const int* __restrict__ sbase,
  float* __restrict__ AS)
{
  __shared__ float S[5*NN];      // 46080 B
  __shared__ float bufB[5*NN];   // 46080 B
  __shared__ int   ancL[2][NN];  // 18432 B
  __shared__ float prmL[2][NN];  // 18432 B
  __shared__ int   depS[NN];     // 9216 B
  const int b=blockIdx.x;
  const int* sp=sbase+(size_t)b*SSTRIDE_W;
  FILTER_CORE(
    const float4* pf4=(const float4*)(probf+(size_t)b*KK*NN);
    float4* S4=(float4*)S;
    for(int t2=tid;t2<(KK*NN)/4;t2+=TPF) S4[t2]=pf4[t2];
    for(int t2=KK*NN+tid;t2<5*NN;t2+=TPF) S[t2]=1.0f;
  )
  float* o=AS+(size_t)b*KK*NN;
  for(int i=tid;i<NN;i+=TPF){
    float aF=aFin[i];
    float F4=fmaf(aF,r4,bFin[4*NN+i]);
    float inv=1.0f/F4;
    o[i]     =fmaf(aF,r0,bFin[i])*inv;
    o[NN+i]  =fmaf(aF,r1,bFin[NN+i])*inv;
    o[2*NN+i]=fmaf(aF,r2,bFin[2*NN+i])*inv;
    o[3*NN+i]=fmaf(aF,r3,bFin[3*NN+i])*inv;
  }
}

// ---------------------------------------------------------------------------
__global__ __launch_bounds__(TPF) void k_filter123(
  const float* __restrict__ AS, const float* __restrict__ probf,
  const float* __restrict__ rois, const int* __restrict__ sbase,
  float* __restrict__ partials)
{
  __shared__ float S[5*NN];
  __shared__ float bufB[5*NN];
  __shared__ int   ancL[2][NN];
  __shared__ float prmL[2][NN];
  __shared__ int   depS[NN];
  __shared__ float red[TPF];
  const int fm1=blockIdx.x/BB, b=blockIdx.x%BB;
  const int pidx=(fm1+1)*BB+b;
  const int* sp=sbase+(size_t)pidx*SSTRIDE_W;
  FILTER_CORE(
    const float4* pf4=(const float4*)(AS+(size_t)b*KK*NN);
    float4* S4=(float4*)S;
    for(int t2=tid;t2<(KK*NN)/4;t2+=TPF) S4[t2]=pf4[t2];
    for(int t2=KK*NN+tid;t2<5*NN;t2+=TPF) S[t2]=1.0f;
  )
  float part=0.0f;
  const float* pb=probf+(size_t)b*KK*NN;
  for(int i=tid;i<NN;i+=TPF){
    int r=i/WW, c2=i-r*WW;
    float roi=rois[(size_t)b*(192*192)+(4*r)*192+(4*c2)];
    float aF=aFin[i];
    float F4=fmaf(aF,r4,bFin[4*NN+i]);
    float inv=1.0f/F4;
    float s=fabsf(pb[i]      - fmaf(aF,r0,bFin[i])*inv)
          + fabsf(pb[NN+i]   - fmaf(aF,r1,bFin[NN+i])*inv)
          + fabsf(pb[2*NN+i] - fmaf(aF,r2,bFin[2*NN+i])*inv)
          + fabsf(pb[3*NN+i] - fmaf(aF,r3,bFin[3*NN+i])*inv);
    part+=roi*s;
  }
  red[tid]=part; __syncthreads();
  for(int s2=TPF/2;s2>0;s2>>=1){ if(tid<s2) red[tid]+=red[tid+s2]; __syncthreads(); }
  if(tid==0) partials[blockIdx.x]=red[0];
}

// ---------------------------------------------------------------------------
__global__ __launch_bounds__(TPB) void k_final(const float* __restrict__ rois,
    const float* __restrict__ partials, const float* __restrict__ wt,
    float* __restrict__ out)
{
  __shared__ float red[TPB];
  const int tid=threadIdx.x;
  float n=0.0f;
  for(int t=tid;t<BB*NN;t+=TPB){
    int b=t/NN, i=t-b*NN; int r=i/WW, c=i-r*WW;
    n += rois[(size_t)b*(192*192)+(4*r)*192+(4*c)];
  }
  red[tid]=n; __syncthreads();
  for(int s=TPB/2;s>0;s>>=1){ if(tid<s) red[tid]+=red[tid+s]; __syncthreads(); }
  if(tid==0){
    float loss=0.0f;
    for(int j=0;j<3*BB;j++) loss+=partials[j];
    float N=red[0];
    out[0]=wt[0]*((N>0.0f)?(loss/N):loss);
  }
}

// ---------------------------------------------------------------------------
extern "C" void kernel_launch(void* const* d_in, const int* in_sizes, int n_in,
                              void* d_out, int out_size, void* d_ws, size_t ws_size,
                              hipStream_t stream) {
  (void)in_sizes; (void)n_in; (void)out_size; (void)ws_size;
  const float* preds=(const float*)d_in[0];
  const float* lowf =(const float*)d_in[1];
  const float* hf1  =(const float*)d_in[2];
  const float* hf2  =(const float*)d_in[3];
  const float* hf3  =(const float*)d_in[4];
  const float* rois =(const float*)d_in[5];
  const float* wt   =(const float*)d_in[6];
  float* out=(float*)d_out;

  char* ws=(char*)d_ws;
  float* partials=(float*)ws;                                  // 24 floats @0
  float* probf=(float*)(ws+256);                               // 294912 B
  float* AS   =(float*)(ws+256+(size_t)BB*KK*NN*4);            // 294912 B
  size_t sb_off=256+(size_t)2*BB*KK*NN*4;                      // 590080
  int*   sbase=(int*)(ws+sb_off);                              // 1,180,672 B
  size_t aw_off=sb_off+(size_t)32*SSTRIDE_W*4;                 // 1,770,752
  float4* adjwG=(float4*)(ws+aw_off);                          // 1,179,648 B
  size_t aj_off=aw_off+(size_t)32*NN*16;                       // 2,950,400
  unsigned char* adjG=(unsigned char*)(ws+aj_off);             // 73,728 B
  size_t pl_off=aj_off+(size_t)32*NN;                          // 3,024,128 (8-mult)
  double* pd_low=(double*)(ws+pl_off);                         // 8*EEE*8 = 288,768 B
  size_t ph_off=pl_off+(size_t)8*EEE*8;                        // 3,312,896
  double* pd_hf=(double*)(ws+ph_off);                          // 24*NCHUNK*EEE*8 = 13.9 MB

  k_prob<<<(BB*NN+TPB-1)/TPB,TPB,0,stream>>>(preds,probf);
  k_edges<<<8+24*NCHUNK,TPB,0,stream>>>(lowf,hf1,hf2,hf3,pd_low,pd_hf);
  k_boruvka<<<32,TPW,0,stream>>>(pd_low,pd_hf,adjwG,adjG);
  k_root<<<32,TPR,0,stream>>>(adjwG,adjG,sbase);
  k_filter0<<<BB,TPF,0,stream>>>(probf,sbase,AS);
  k_filter123<<<3*BB,TPF,0,stream>>>(AS,probf,rois,sbase,partials);
  k_final<<<1,TPB,0,stream>>>(rois,partials,wt,out);
}

// Round 10
// 469.715 us; speedup vs baseline: 1.5492x; 1.2587x over previous
//
#include <hip/hip_runtime.h>
#include <math.h>

// ---------------------------------------------------------------------------
// TreeEnergyLoss on MI355X.
// softmax -> k_edges (parallel chunked f64 edge distances via LDS-upsampled
// embeddings; 512t blocks, nchunk=32 -> ~24 waves/CU) -> k_boruvka (1024t
// Boruvka MST under strict (dist,edge-idx) order == reference's stable
// Kruskal) -> k_root (1024t Euler-tour rooting via Wyllie list-ranking) ->
// pointer-doubling tree filters (512t; upward: register-snapshot + in-place
// LDS atomic scatter; downward: copy-free affine ping-pong) -> masked L1.
// R10 theme: wave supply. R9 post-mortem showed every stage grid-starved
// (k_edges 6 waves/CU, boruvka/root 32 CUs busy, filters 8-24 blocks).
// ---------------------------------------------------------------------------

#define HH 48
#define WW 48
#define NN (HH*WW)          // 2304 nodes
#define EHH (HH*(WW-1))     // 2256 horizontal edges
#define EEE (2*EHH)         // 4512 edges
#define BB 8
#define KK 4
#define TPB 256
#define TPE 512             // edges kernel
#define TPW 1024            // boruvka kernel
#define TPR 1024            // rooting kernel
#define TPF 512             // filter kernels
#define NPL 5               // nodes per lane in filters (ceil 2304/512)
#define NHE ((EHH+TPE-1)/TPE)   // 5 edges per thread per orientation
#define ESLOT (4*NN)        // 9216 directed-edge slots
#define LVE (2*(NN-1))      // 4606 valid directed edges
#define RIPT ((LVE+TPR-1)/TPR)  // 5 scan items per thread
#define SENTN 0xFFFFu

// per-problem structure record in ws (ints): node-indexed int4 (parent,w,depth,0) | maxdepth
#define SSTRIDE_W (4*NN+8)
#define PK_OFF 0
#define D_OFF (4*NN)

struct Tap { int o00,o01,o10,o11; float w00,w01,w10,w11; };

__device__ __forceinline__ Tap mk_tap(int r,int c,int sh,int sw){
  float sy=(float)sh/48.0f, sx=(float)sw/48.0f;          // exact (pow2 ratios)
  float ys=fmaxf(((float)r+0.5f)*sy-0.5f,0.0f);
  float xs=fmaxf(((float)c+0.5f)*sx-0.5f,0.0f);
  int y0=(int)ys; if(y0>sh-1) y0=sh-1;
  int x0=(int)xs; if(x0>sw-1) x0=sw-1;
  int y1=y0+1; if(y1>sh-1) y1=sh-1;
  int x1=x0+1; if(x1>sw-1) x1=sw-1;
  float wy=ys-(float)y0, wx=xs-(float)x0;
  Tap t;
  t.o00=y0*sw+x0; t.o01=y0*sw+x1; t.o10=y1*sw+x0; t.o11=y1*sw+x1;
  t.w00=(1.0f-wy)*(1.0f-wx); t.w01=(1.0f-wy)*wx;
  t.w10=wy*(1.0f-wx);        t.w11=wy*wx;
  return t;
}

__device__ __forceinline__ float tap_val(const float* __restrict__ p, const Tap& t){
  return t.w00*p[t.o00]+t.w01*p[t.o01]+t.w10*p[t.o10]+t.w11*p[t.o11];
}

// numpy edge order: horizontal (row-major) first, then vertical.
__device__ __forceinline__ void edge_uv(int e,int& u,int& v){
  if(e<EHH){ int r=e/(WW-1); int c=e-r*(WW-1); u=r*WW+c; v=u+1; }
  else     { int t=e-EHH; u=t; v=t+WW; }
}

__device__ __forceinline__ void pick_src(int f, const float* lowf, const float* hf1,
                                         const float* hf2, const float* hf3,
                                         const float*& src, int& sh, int& C){
  if(f==0){src=lowf; sh=192; C=3;}
  else if(f==1){src=hf1; sh=24; C=512;}
  else if(f==2){src=hf2; sh=12; C=512;}
  else        {src=hf3; sh=6;  C=512;}
}

// ---------------------------------------------------------------------------
__global__ __launch_bounds__(TPB) void k_prob(const float* __restrict__ preds,
                                              float* __restrict__ probf){
  int t=blockIdx.x*TPB+threadIdx.x;
  if(t>=BB*NN) return;
  int b=t/NN, i=t-b*NN;
  const float* p=preds+(size_t)b*KK*NN+i;
  float x0=p[0],x1=p[NN],x2=p[2*NN],x3=p[3*NN];
  float mx=fmaxf(fmaxf(x0,x1),fmaxf(x2,x3));
  float e0=expf(x0-mx),e1=expf(x1-mx),e2=expf(x2-mx),e3=expf(x3-mx);
  float s=((e0+e1)+(e2+e3));
  float* q=probf+(size_t)b*KK*NN+i;
  q[0]=e0/s; q[NN]=e1/s; q[2*NN]=e2/s; q[3*NN]=e3/s;
}

// ---------------------------------------------------------------------------
// Parallel edge-distance partials.  One block = (problem, channel-chunk).
// 512 threads, 4-channel substages (36 KB LDS).  Per-edge channel order is
// ascending and chunk-sum order fixed -> cross-edge consistency preserved
// (structural ties stay exact; proven absmax 0.0 since R1).
__global__ __launch_bounds__(TPE) void k_edges(
  const float* __restrict__ lowf, const float* __restrict__ hf1,
  const float* __restrict__ hf2, const float* __restrict__ hf3,
  double* __restrict__ pd_low, double* __restrict__ pd_hf, int nchunk)
{
  __shared__ float up[4*NN];   // 36864 B
  const int tid=threadIdx.x;
  int pidx, chunk, hfidx=0;
  if(blockIdx.x<8){ pidx=blockIdx.x; chunk=0; }
  else { int t=blockIdx.x-8; hfidx=t/nchunk; chunk=t-hfidx*nchunk; pidx=8+hfidx; }
  const int f=pidx>>3, b=pidx&7;
  const float* src; int sh,C;
  pick_src(f,lowf,hf1,hf2,hf3,src,sh,C);
  const int shw=sh*sh;
  const float* srcb=src+(size_t)b*C*shw;
  const int cpc=(f==0)?3:(512/nchunk);
  const int c_begin=chunk*cpc;
  const int c_end=(c_begin+cpc<C)?(c_begin+cpc):C;

  double accH[NHE], accV[NHE];
  #pragma unroll
  for(int j=0;j<NHE;j++){ accH[j]=0.0; accV[j]=0.0; }

  for(int c0=c_begin;c0<c_end;c0+=4){
    const int nc=(c_end-c0<4)?(c_end-c0):4;
    __syncthreads();               // protect previous sub-stage reads
    for(int i=tid;i<NN;i+=TPE){
      int r=i/WW;
      Tap t=mk_tap(r,i-r*WW,sh,sh);
      const float* pl=srcb+(size_t)c0*shw;
      for(int c=0;c<nc;c++) up[c*NN+i]=tap_val(pl+(size_t)c*shw,t);
    }
    __syncthreads();
    for(int j=0;j<NHE;j++){
      int e=tid+j*TPE;
      if(e<EHH){
        int r=e/(WW-1); int u=r*WW+(e-r*(WW-1));
        const float* pu=up+u;
        for(int c=0;c<nc;c++){
          double d=(double)pu[c*NN]-(double)pu[c*NN+1];
          accH[j]=fma(d,d,accH[j]);
        }
      }
    }
    for(int j=0;j<NHE;j++){
      int u=tid+j*TPE;
      if(u<EHH){                       // vertical edge index EHH+u
        const float* pu=up+u;
        for(int c=0;c<nc;c++){
          double d=(double)pu[c*NN]-(double)pu[c*NN+WW];
          accV[j]=fma(d,d,accV[j]);
        }
      }
    }
  }
  double* outp=(f==0)? pd_low+(size_t)pidx*EEE
                     : pd_hf+((size_t)hfidx*nchunk+chunk)*EEE;
  #pragma unroll
  for(int j=0;j<NHE;j++){
    int e=tid+j*TPE;
    if(e<EHH){ outp[e]=accH[j]; outp[EHH+e]=accV[j]; }
  }
}

// ---------------------------------------------------------------------------
// 1024-thread Boruvka per (forest,batch).
// Outputs per-node tree-adjacency mask (L,R,U,D bits) + per-direction weights.
__global__ __launch_bounds__(TPW) void k_boruvka(
  const double* __restrict__ pd_low, const double* __restrict__ pd_hf,
  int nchunk, float4* __restrict__ adjwG, unsigned char* __restrict__ adjG)
{
  __shared__ double dkey[EEE];                  // 36096 B
  __shared__ unsigned long long bestd[NN];      // 18432 B
  __shared__ int comp[NN];
  __shared__ int lnk[NN];
  __shared__ int beste[NN];
  __shared__ unsigned char mstf[EEE];
  __shared__ int flags[2];

  const int tid=threadIdx.x;
  const int pidx=blockIdx.x;
  const int f=pidx>>3;
  const float sigma=(f==0)?0.02f:1.0f;

  // ---- gather edge distances: fixed chunk order (deterministic) ----
  const double* p0=(f==0)? pd_low+(size_t)pidx*EEE
                         : pd_hf+((size_t)(pidx-8)*nchunk)*EEE;
  const int nck=(f==0)?1:nchunk;
  for(int e=tid;e<EEE;e+=TPW){
    double s=0.0;
    for(int k=0;k<nck;k++) s+=p0[(size_t)k*EEE+e];
    dkey[e]=s;
  }
  for(int i=tid;i<NN;i+=TPW) comp[i]=i;
  for(int e=tid;e<EEE;e+=TPW) mstf[e]=0;
  __syncthreads();

  // ---- Boruvka: unique MST under strict (dist_bits, edge_index) order ----
  for(int round=0;round<24;++round){
    for(int i=tid;i<NN;i+=TPW){ bestd[i]=~0ull; beste[i]=0x7fffffff; lnk[i]=i; }
    if(tid==0) flags[1]=0;
    __syncthreads();
    for(int e=tid;e<EEE;e+=TPW){
      int u,v; edge_uv(e,u,v);
      int cu=comp[u], cv=comp[v];
      if(cu!=cv){
        unsigned long long db=(unsigned long long)__double_as_longlong(dkey[e]);
        atomicMin(&bestd[cu],db);
        atomicMin(&bestd[cv],db);
      }
    }
    __syncthreads();
    for(int e=tid;e<EEE;e+=TPW){
      int u,v; edge_uv(e,u,v);
      int cu=comp[u], cv=comp[v];
      if(cu!=cv){
        unsigned long long db=(unsigned long long)__double_as_longlong(dkey[e]);
        if(db==bestd[cu]) atomicMin(&beste[cu],e);
        if(db==bestd[cv]) atomicMin(&beste[cv],e);
      }
    }
    __syncthreads();
    // hook (mutual pair resolved toward smaller id; mutual => SAME edge since order strict)
    for(int i=tid;i<NN;i+=TPW){
      if(comp[i]==i && beste[i]!=0x7fffffff){
        int e=beste[i]; int u,v; edge_uv(e,u,v);
        int cu=comp[u], cv=comp[v];
        int other=(cu==i)?cv:cu;
        bool mutual=(beste[other]==e);
        if(!mutual || other<i){ lnk[i]=other; mstf[e]=1; flags[1]=1; }
      }
    }
    __syncthreads();
    if(flags[1]==0) break;          // no hooks => forest complete
    // ---- racy barrier-free pointer jumping (monotone-convergent) ----
    {
      volatile int* vl=lnk;
      for(int it=0;it<12;++it){
        for(int i=tid;i<NN;i+=TPW){ int a=vl[i]; int b2=vl[a]; if(a!=b2) vl[i]=b2; }
      }
      for(;;){
        if(tid==0) flags[0]=0;
        __syncthreads();
        for(int i=tid;i<NN;i+=TPW){
          int a=vl[i]; int b2=vl[a];
          if(a!=b2){ vl[i]=b2; flags[0]=1; }
        }
        __syncthreads();
        int ch=flags[0];
        __syncthreads();
        if(!ch) break;
      }
    }
    for(int i=tid;i<NN;i+=TPW) comp[i]=lnk[comp[i]];
    __syncthreads();
  }

  // ---- emit per-node adjacency mask + per-direction weights ----
  for(int i=tid;i<NN;i+=TPW){
    int r=i/WW, c=i-r*WW;
    int mask=0; float4 w; w.x=0.0f; w.y=0.0f; w.z=0.0f; w.w=0.0f;
    if(c>0    && mstf[r*(WW-1)+c-1]){ mask|=1; w.x=expf(-(float)dkey[r*(WW-1)+c-1]/sigma); }
    if(c<WW-1 && mstf[r*(WW-1)+c])  { mask|=2; w.y=expf(-(float)dkey[r*(WW-1)+c]/sigma); }
    if(r>0    && mstf[EHH+i-WW])    { mask|=4; w.z=expf(-(float)dkey[EHH+i-WW]/sigma); }
    if(r<HH-1 && mstf[EHH+i])       { mask|=8; w.w=expf(-(float)dkey[EHH+i]/sigma); }
    adjwG[(size_t)pidx*NN+i]=w;
    adjG[(size_t)pidx*NN+i]=(unsigned char)mask;
  }
}

// ---------------------------------------------------------------------------
// 1024-thread Euler-tour rooting via Wyllie list-ranking.
// Emits node-indexed int4 (parent, w_bits, depth, 0) + maxdepth.
__global__ __launch_bounds__(TPR) void k_root(
  const float4* __restrict__ adjwG, const unsigned char* __restrict__ adjG,
  int* __restrict__ sbase)
{
  __shared__ unsigned int eA[ESLOT];   // 36864 B  (ping: (nxt<<16)|dist)
  __shared__ unsigned int eB[ESLOT];   // 36864 B  (pong; later pos[])
  __shared__ float4 adjwS[NN];         // 36864 B
  __shared__ unsigned char adjS[NN];   // 2304 B
  __shared__ int chunkS[TPR];          // 4096 B
  __shared__ int maxdS;

  const int tid=threadIdx.x;
  const int pidx=blockIdx.x;
  {
    const float4* aw=adjwG+(size_t)pidx*NN;
    for(int t=tid;t<NN;t+=TPR) adjwS[t]=aw[t];
    const int* a4=(const int*)(adjG+(size_t)pidx*NN);
    int* s4=(int*)adjS;
    for(int t=tid;t<NN/4;t+=TPR) s4[t]=a4[t];
  }
  if(tid==0) maxdS=0;
  __syncthreads();

  const int m0=adjS[0];
  const int d0=(m0&1)?0:((m0&2)?1:((m0&4)?2:3));
  const int e0=d0;   // node 0 * 4 + d0

  // ---- build successor list, init dist=1 ----
  for(int t=tid;t<ESLOT;t+=TPR){
    int u=t>>2, d=t&3;
    unsigned int pk=0;                       // dist==0 marks invalid slot
    if(adjS[u]&(1<<d)){
      int v=(d==0)?u-1:(d==1)?u+1:(d==2)?u-WW:u+WW;
      int rd=d^1;
      int mv=adjS[v];
      int nd=rd;
      #pragma unroll
      for(int k2=4;k2>=1;k2--){ int dd=(rd+k2)&3; if(mv&(1<<dd)) nd=dd; }
      int ne=(v<<2)|nd;
      unsigned int nxt=(ne==e0)?SENTN:(unsigned int)ne;
      pk=(nxt<<16)|1u;
    }
    eA[t]=pk;
  }
  __syncthreads();

  // ---- Wyllie doubling: 13 rounds (2^13 >= 4606) ----
  unsigned int* P=eA; unsigned int* Q=eB;
  for(int r2=0;r2<13;r2++){
    for(int t=tid;t<ESLOT;t+=TPR){
      unsigned int pk=P[t];
      unsigned int dist=pk&0xFFFFu, nxt=pk>>16;
      if(dist && nxt!=SENTN){
        unsigned int pk2=P[nxt];
        dist+=pk2&0xFFFFu;
        nxt=pk2>>16;
        pk=(nxt<<16)|dist;
      }
      Q[t]=pk;
    }
    __syncthreads();
    unsigned int* tmp=P; P=Q; Q=tmp;
  }
  for(int t=tid;t<ESLOT;t+=TPR){
    unsigned int dist=P[t]&0xFFFFu;
    Q[t]=dist?(unsigned int)(LVE-(int)dist):0xFFFFFFFFu;
  }
  __syncthreads();

  // ---- scatter +-1 into scan array ----
  int* scanA=(int*)P;
  for(int t=tid;t<ESLOT;t+=TPR){
    unsigned int pos=Q[t];
    if(pos!=0xFFFFFFFFu){
      int u=t>>2, d=t&3;
      int v=(d==0)?u-1:(d==1)?u+1:(d==2)?u-WW:u+WW;
      unsigned int rpos=Q[(v<<2)|(d^1)];
      scanA[pos]=(pos<rpos)?1:-1;
    }
  }
  __syncthreads();

  // ---- blocked inclusive scan over scanA[0..LVE-1] ----
  const int base=tid*RIPT;
  int vals[RIPT]; int lsum=0;
  #pragma unroll
  for(int j=0;j<RIPT;j++){
    int p=base+j;
    int v=(p<LVE)?scanA[p]:0;
    lsum+=v; vals[j]=lsum;
  }
  chunkS[tid]=lsum;
  __syncthreads();
  for(int off=1;off<TPR;off<<=1){
    int v=chunkS[tid];
    int vv=(tid>=off)?chunkS[tid-off]:0;
    __syncthreads();
    chunkS[tid]=v+vv;
    __syncthreads();
  }
  const int myoff=(tid>0)?chunkS[tid-1]:0;
  int mymax=0;
  #pragma unroll
  for(int j=0;j<RIPT;j++){
    int p=base+j;
    if(p<LVE){ int s=vals[j]+myoff; scanA[p]=s; if(s>mymax) mymax=s; }
  }
  if(mymax>0) atomicMax(&maxdS,mymax);
  __syncthreads();

  // ---- emit per-node records ----
  int* sp=sbase+(size_t)pidx*SSTRIDE_W;
  int4* g_pk=(int4*)(sp+PK_OFF);
  if(tid==0){
    g_pk[0]=make_int4(0,__float_as_int(0.0f),0,0);
    sp[D_OFF]=maxdS;
  }
  for(int t=tid;t<ESLOT;t+=TPR){
    unsigned int pos=Q[t];
    if(pos!=0xFFFFFFFFu){
      int u=t>>2, d=t&3;
      int v=(d==0)?u-1:(d==1)?u+1:(d==2)?u-WW:u+WW;
      unsigned int rpos=Q[(v<<2)|(d^1)];
      if(pos<rpos){                       // down edge: u = parent(v)
        float4 w4=adjwS[u];
        float w=(d==0)?w4.x:(d==1)?w4.y:(d==2)?w4.z:w4.w;
        g_pk[v]=make_int4(u,__float_as_int(w),scanA[pos],0);
      }
    }
  }
}

// ---------------------------------------------------------------------------
// Pointer-doubling tree filter core (512 threads, NPL=5 guarded).
// Upward round t: register snapshot -> barrier -> in-place atomicAdd scatter
// to 2^t-ancestor (dep-gated) + table doubling in LDS.
// Downward: affine (a,b) composition doubling, copy-free ping-pong.
// ---------------------------------------------------------------------------
#define FILTER_CORE(X_LOAD)                                                    \
  const int tid=threadIdx.x;                                                   \
  const int maxD=sp[D_OFF];                                                    \
  int T=1; while((1<<T)<=maxD) T++;                                            \
  const int4* g_pk=(const int4*)(sp+PK_OFF);                                   \
  for(int i=tid;i<NN;i+=TPF){                                                  \
    int4 rec=g_pk[i];                                                          \
    ancL[0][i]=rec.x; prmL[0][i]=__int_as_float(rec.y); depS[i]=rec.z;         \
  }                                                                            \
  { X_LOAD }                                                                   \
  __syncthreads();                                                             \
  int ping=0;                                                                  \
  for(int t=0;t<T;t++){                                                        \
    float s0[NPL],s1[NPL],s2[NPL],s3[NPL],s4[NPL];                             \
    int aJ[NPL]; float pwJ[NPL]; int dpJ[NPL];                                 \
    _Pragma("unroll")                                                          \
    for(int j=0;j<NPL;j++){                                                    \
      int i=tid+j*TPF;                                                         \
      if(i<NN){                                                                \
        s0[j]=S[i]; s1[j]=S[NN+i]; s2[j]=S[2*NN+i];                            \
        s3[j]=S[3*NN+i]; s4[j]=S[4*NN+i];                                      \
        aJ[j]=ancL[ping][i]; pwJ[j]=prmL[ping][i]; dpJ[j]=depS[i];             \
      } else { dpJ[j]=-1; aJ[j]=0; pwJ[j]=0.0f;                                \
               s0[j]=s1[j]=s2[j]=s3[j]=s4[j]=0.0f; }                           \
    }                                                                          \
    __syncthreads();                                                           \
    int bit=1<<t;                                                              \
    _Pragma("unroll")                                                          \
    for(int j=0;j<NPL;j++){                                                    \
      int i=tid+j*TPF;                                                         \
      if(i<NN){                                                                \
        int a=aJ[j]; float pw=pwJ[j];                                          \
        if(dpJ[j]>=bit){                                                       \
          atomicAdd(&S[a],      pw*s0[j]);                                     \
          atomicAdd(&S[NN+a],   pw*s1[j]);                                     \
          atomicAdd(&S[2*NN+a], pw*s2[j]);                                     \
          atomicAdd(&S[3*NN+a], pw*s3[j]);                                     \
          atomicAdd(&S[4*NN+a], pw*s4[j]);                                     \
        }                                                                      \
        ancL[1-ping][i]=ancL[ping][a];                                         \
        prmL[1-ping][i]=pw*prmL[ping][a];                                      \
      }                                                                        \
    }                                                                          \
    __syncthreads();                                                           \
    ping^=1;                                                                   \
  }                                                                            \
  /* S = A_up.  Downward init: b = (1-w^2)*A_up (root: w=0 -> b=A_up). */      \
  for(int i=tid;i<NN;i+=TPF){                                                  \
    int4 rec=g_pk[i];                                                          \
    float w=__int_as_float(rec.y); float fq=1.0f-w*w;                          \
    ancL[0][i]=rec.x; prmL[0][i]=w;                                            \
    bufB[i]     =fq*S[i];      bufB[NN+i]  =fq*S[NN+i];                        \
    bufB[2*NN+i]=fq*S[2*NN+i]; bufB[3*NN+i]=fq*S[3*NN+i];                      \
    bufB[4*NN+i]=fq*S[4*NN+i];                                                 \
  }                                                                            \
  __syncthreads();                                                             \
  ping=0;                                                                      \
  float* Sp=bufB; float* Sq=S;                                                 \
  for(int t=0;t<T;t++){                                                        \
    for(int i=tid;i<NN;i+=TPF){                                                \
      int a=ancL[ping][i]; float ai=prmL[ping][i];                             \
      Sq[i]     =fmaf(ai,Sp[a],      Sp[i]);                                   \
      Sq[NN+i]  =fmaf(ai,Sp[NN+a],   Sp[NN+i]);                                \
      Sq[2*NN+i]=fmaf(ai,Sp[2*NN+a], Sp[2*NN+i]);                              \
      Sq[3*NN+i]=fmaf(ai,Sp[3*NN+a], Sp[3*NN+i]);                              \
      Sq[4*NN+i]=fmaf(ai,Sp[4*NN+a], Sp[4*NN+i]);                              \
      ancL[1-ping][i]=ancL[ping][a];                                           \
      prmL[1-ping][i]=ai*prmL[ping][a];                                        \
    }                                                                          \
    __syncthreads();                                                           \
    ping^=1; { float* tmp=Sp; Sp=Sq; Sq=tmp; }                                 \
  }                                                                            \
  const float r0=Sp[0],r1=Sp[NN],r2=Sp[2*NN],r3=Sp[3*NN],r4=Sp[4*NN];          \
  float* aFin=prmL[ping]; float* bFin=Sp;

// ---------------------------------------------------------------------------
__global__ __launch_bounds__(TPF) void k_filter0(
  const float* __restrict__ probf, const int* __restrict__ sbase,
  float* __restrict__ AS)
{
  __shared__ float S[5*NN];      // 46080 B
  __shared__ float bufB[5*NN];   // 46080 B
  __shared__ int   ancL[2][NN];  // 18432 B
  __shared__ float prmL[2][NN];  // 18432 B
  __shared__ int   depS[NN];     // 9216 B
  const int b=blockIdx.x;
  const int* sp=sbase+(size_t)b*SSTRIDE_W;
  FILTER_CORE(
    const float4* pf4=(const float4*)(probf+(size_t)b*KK*NN);
    float4* S4=(float4*)S;
    for(int t2=tid;t2<(KK*NN)/4;t2+=TPF) S4[t2]=pf4[t2];
    for(int t2=KK*NN+tid;t2<5*NN;t2+=TPF) S[t2]=1.0f;
  )
  float* o=AS+(size_t)b*KK*NN;
  for(int i=tid;i<NN;i+=TPF){
    float aF=aFin[i];
    float F4=fmaf(aF,r4,bFin[4*NN+i]);
    float inv=1.0f/F4;
    o[i]     =fmaf(aF,r0,bFin[i])*inv;
    o[NN+i]  =fmaf(aF,r1,bFin[NN+i])*inv;
    o[2*NN+i]=fmaf(aF,r2,bFin[2*NN+i])*inv;
    o[3*NN+i]=fmaf(aF,r3,bFin[3*NN+i])*inv;
  }
}

// ---------------------------------------------------------------------------
__global__ __launch_bounds__(TPF) void k_filter123(
  const float* __restrict__ AS, const float* __restrict__ probf,
  const float* __restrict__ rois, const int* __restrict__ sbase,
  float* __restrict__ partials)
{
  __shared__ float S[5*NN];
  __shared__ float bufB[5*NN];
  __shared__ int   ancL[2][NN];
  __shared__ float prmL[2][NN];
  __shared__ int   depS[NN];
  __shared__ float red[TPF];
  const int fm1=blockIdx.x/BB, b=blockIdx.x%BB;
  const int pidx=(fm1+1)*BB+b;
  const int* sp=sbase+(size_t)pidx*SSTRIDE_W;
  FILTER_CORE(
    const float4* pf4=(const float4*)(AS+(size_t)b*KK*NN);
    float4* S4=(float4*)S;
    for(int t2=tid;t2<(KK*NN)/4;t2+=TPF) S4[t2]=pf4[t2];
    for(int t2=KK*NN+tid;t2<5*NN;t2+=TPF) S[t2]=1.0f;
  )
  float part=0.0f;
  const float* pb=probf+(size_t)b*KK*NN;
  for(int i=tid;i<NN;i+=TPF){
    int r=i/WW, c2=i-r*WW;
    float roi=rois[(size_t)b*(192*192)+(4*r)*192+(4*c2)];
    float aF=aFin[i];
    float F4=fmaf(aF,r4,bFin[4*NN+i]);
    float inv=1.0f/F4;
    float s=fabsf(pb[i]      - fmaf(aF,r0,bFin[i])*inv)
          + fabsf(pb[NN+i]   - fmaf(aF,r1,bFin[NN+i])*inv)
          + fabsf(pb[2*NN+i] - fmaf(aF,r2,bFin[2*NN+i])*inv)
          + fabsf(pb[3*NN+i] - fmaf(aF,r3,bFin[3*NN+i])*inv);
    part+=roi*s;
  }
  red[tid]=part; __syncthreads();
  for(int s2=TPF/2;s2>0;s2>>=1){ if(tid<s2) red[tid]+=red[tid+s2]; __syncthreads(); }
  if(tid==0) partials[blockIdx.x]=red[0];
}

// ---------------------------------------------------------------------------
__global__ __launch_bounds__(TPB) void k_final(const float* __restrict__ rois,
    const float* __restrict__ partials, const float* __restrict__ wt,
    float* __restrict__ out)
{
  __shared__ float red[TPB];
  const int tid=threadIdx.x;
  float n=0.0f;
  for(int t=tid;t<BB*NN;t+=TPB){
    int b=t/NN, i=t-b*NN; int r=i/WW, c=i-r*WW;
    n += rois[(size_t)b*(192*192)+(4*r)*192+(4*c)];
  }
  red[tid]=n; __syncthreads();
  for(int s=TPB/2;s>0;s>>=1){ if(tid<s) red[tid]+=red[tid+s]; __syncthreads(); }
  if(tid==0){
    float loss=0.0f;
    for(int j=0;j<3*BB;j++) loss+=partials[j];
    float N=red[0];
    out[0]=wt[0]*((N>0.0f)?(loss/N):loss);
  }
}

// ---------------------------------------------------------------------------
extern "C" void kernel_launch(void* const* d_in, const int* in_sizes, int n_in,
                              void* d_out, int out_size, void* d_ws, size_t ws_size,
                              hipStream_t stream) {
  (void)in_sizes; (void)n_in; (void)out_size;
  const float* preds=(const float*)d_in[0];
  const float* lowf =(const float*)d_in[1];
  const float* hf1  =(const float*)d_in[2];
  const float* hf2  =(const float*)d_in[3];
  const float* hf3  =(const float*)d_in[4];
  const float* rois =(const float*)d_in[5];
  const float* wt   =(const float*)d_in[6];
  float* out=(float*)d_out;

  char* ws=(char*)d_ws;
  float* partials=(float*)ws;                                  // 24 floats @0
  float* probf=(float*)(ws+256);                               // 294912 B
  float* AS   =(float*)(ws+256+(size_t)BB*KK*NN*4);            // 294912 B
  size_t sb_off=256+(size_t)2*BB*KK*NN*4;                      // 590080
  int*   sbase=(int*)(ws+sb_off);                              // 1,180,672 B
  size_t aw_off=sb_off+(size_t)32*SSTRIDE_W*4;                 // 1,770,752
  float4* adjwG=(float4*)(ws+aw_off);                          // 1,179,648 B
  size_t aj_off=aw_off+(size_t)32*NN*16;                       // 2,950,400
  unsigned char* adjG=(unsigned char*)(ws+aj_off);             // 73,728 B
  size_t pl_off=aj_off+(size_t)32*NN;                          // 3,024,128 (8-mult)
  double* pd_low=(double*)(ws+pl_off);                         // 8*EEE*8 = 288,768 B
  size_t ph_off=pl_off+(size_t)8*EEE*8;                        // 3,312,896
  double* pd_hf=(double*)(ws+ph_off);                          // 24*nchunk*EEE*8

  int nchunk=32;   // 27.7 MB partials; fallback halves until ws fits
  while(nchunk>1 && ph_off+(size_t)24*nchunk*EEE*8>ws_size) nchunk>>=1;

  k_prob<<<(BB*NN+TPB-1)/TPB,TPB,0,stream>>>(preds,probf);
  k_edges<<<8+24*nchunk,TPE,0,stream>>>(lowf,hf1,hf2,hf3,pd_low,pd_hf,nchunk);
  k_boruvka<<<32,TPW,0,stream>>>(pd_low,pd_hf,nchunk,adjwG,adjG);
  k_root<<<32,TPR,0,stream>>>(adjwG,adjG,sbase);
  k_filter0<<<BB,TPF,0,stream>>>(probf,sbase,AS);
  k_filter123<<<3*BB,TPF,0,stream>>>(AS,probf,rois,sbase,partials);
  k_final<<<1,TPB,0,stream>>>(rois,partials,wt,out);
}

// Round 11
// 291.400 us; speedup vs baseline: 2.4971x; 1.6119x over previous
//
#include <hip/hip_runtime.h>
#include <math.h>

// ---------------------------------------------------------------------------
// TreeEnergyLoss on MI355X.
// softmax -> k_edges (chunked f64 edge distances via LDS-upsampled embeddings)
// -> k_boruvka (1024t Boruvka MST under strict (dist,edge-idx) order ==
// reference's stable Kruskal) -> k_root (1024t Euler-tour rooting, Wyllie)
// -> k_tables (precompute pointer-doubling levels (anc_t, prod_t) per problem;
//    stored in ws aliased over dead pd_hf) -> k_fchan (one block PER
//    (problem, channel): value-only doubling passes, tables read own-indexed
//    coalesced, 18KB LDS) -> k_div0 / k_loss / k_final.
// R11 theme: filters were 2x132us at 0.3% VALU (8-24 blocks on 256 CUs);
// level tables are value-independent -> hoist once, split channels 5-way.
// ---------------------------------------------------------------------------

#define HH 48
#define WW 48
#define NN (HH*WW)          // 2304 nodes
#define EHH (HH*(WW-1))     // 2256 horizontal edges
#define EEE (2*EHH)         // 4512 edges
#define BB 8
#define KK 4
#define TPB 256
#define TPE 512             // edges kernel
#define TPW 1024            // boruvka kernel
#define TPR 1024            // rooting kernel
#define TPF 512             // fchan/table kernels
#define NPL 5               // nodes per lane (ceil 2304/512)
#define NHE ((EHH+TPE-1)/TPE)   // 5 edges per thread per orientation
#define ESLOT (4*NN)        // 9216 directed-edge slots
#define LVE (2*(NN-1))      // 4606 valid directed edges
#define RIPT ((LVE+TPR-1)/TPR)  // 5 scan items per thread
#define SENTN 0xFFFFu
#define MAXT 12             // 2^12 = 4096 > max possible depth (2303)

// per-problem structure record in ws (ints): node-indexed int4 (parent,w,depth,0) | maxdepth
#define SSTRIDE_W (4*NN+8)
#define PK_OFF 0
#define D_OFF (4*NN)

struct Tap { int o00,o01,o10,o11; float w00,w01,w10,w11; };

__device__ __forceinline__ Tap mk_tap(int r,int c,int sh,int sw){
  float sy=(float)sh/48.0f, sx=(float)sw/48.0f;          // exact (pow2 ratios)
  float ys=fmaxf(((float)r+0.5f)*sy-0.5f,0.0f);
  float xs=fmaxf(((float)c+0.5f)*sx-0.5f,0.0f);
  int y0=(int)ys; if(y0>sh-1) y0=sh-1;
  int x0=(int)xs; if(x0>sw-1) x0=sw-1;
  int y1=y0+1; if(y1>sh-1) y1=sh-1;
  int x1=x0+1; if(x1>sw-1) x1=sw-1;
  float wy=ys-(float)y0, wx=xs-(float)x0;
  Tap t;
  t.o00=y0*sw+x0; t.o01=y0*sw+x1; t.o10=y1*sw+x0; t.o11=y1*sw+x1;
  t.w00=(1.0f-wy)*(1.0f-wx); t.w01=(1.0f-wy)*wx;
  t.w10=wy*(1.0f-wx);        t.w11=wy*wx;
  return t;
}

__device__ __forceinline__ float tap_val(const float* __restrict__ p, const Tap& t){
  return t.w00*p[t.o00]+t.w01*p[t.o01]+t.w10*p[t.o10]+t.w11*p[t.o11];
}

// numpy edge order: horizontal (row-major) first, then vertical.
__device__ __forceinline__ void edge_uv(int e,int& u,int& v){
  if(e<EHH){ int r=e/(WW-1); int c=e-r*(WW-1); u=r*WW+c; v=u+1; }
  else     { int t=e-EHH; u=t; v=t+WW; }
}

__device__ __forceinline__ void pick_src(int f, const float* lowf, const float* hf1,
                                         const float* hf2, const float* hf3,
                                         const float*& src, int& sh, int& C){
  if(f==0){src=lowf; sh=192; C=3;}
  else if(f==1){src=hf1; sh=24; C=512;}
  else if(f==2){src=hf2; sh=12; C=512;}
  else        {src=hf3; sh=6;  C=512;}
}

// ---------------------------------------------------------------------------
__global__ __launch_bounds__(TPB) void k_prob(const float* __restrict__ preds,
                                              float* __restrict__ probf){
  int t=blockIdx.x*TPB+threadIdx.x;
  if(t>=BB*NN) return;
  int b=t/NN, i=t-b*NN;
  const float* p=preds+(size_t)b*KK*NN+i;
  float x0=p[0],x1=p[NN],x2=p[2*NN],x3=p[3*NN];
  float mx=fmaxf(fmaxf(x0,x1),fmaxf(x2,x3));
  float e0=expf(x0-mx),e1=expf(x1-mx),e2=expf(x2-mx),e3=expf(x3-mx);
  float s=((e0+e1)+(e2+e3));
  float* q=probf+(size_t)b*KK*NN+i;
  q[0]=e0/s; q[NN]=e1/s; q[2*NN]=e2/s; q[3*NN]=e3/s;
}

// ---------------------------------------------------------------------------
// Parallel edge-distance partials.  One block = (problem, channel-chunk).
__global__ __launch_bounds__(TPE) void k_edges(
  const float* __restrict__ lowf, const float* __restrict__ hf1,
  const float* __restrict__ hf2, const float* __restrict__ hf3,
  double* __restrict__ pd_low, double* __restrict__ pd_hf, int nchunk)
{
  __shared__ float up[4*NN];   // 36864 B
  const int tid=threadIdx.x;
  int pidx, chunk, hfidx=0;
  if(blockIdx.x<8){ pidx=blockIdx.x; chunk=0; }
  else { int t=blockIdx.x-8; hfidx=t/nchunk; chunk=t-hfidx*nchunk; pidx=8+hfidx; }
  const int f=pidx>>3, b=pidx&7;
  const float* src; int sh,C;
  pick_src(f,lowf,hf1,hf2,hf3,src,sh,C);
  const int shw=sh*sh;
  const float* srcb=src+(size_t)b*C*shw;
  const int cpc=(f==0)?3:(512/nchunk);
  const int c_begin=chunk*cpc;
  const int c_end=(c_begin+cpc<C)?(c_begin+cpc):C;

  double accH[NHE], accV[NHE];
  #pragma unroll
  for(int j=0;j<NHE;j++){ accH[j]=0.0; accV[j]=0.0; }

  for(int c0=c_begin;c0<c_end;c0+=4){
    const int nc=(c_end-c0<4)?(c_end-c0):4;
    __syncthreads();               // protect previous sub-stage reads
    for(int i=tid;i<NN;i+=TPE){
      int r=i/WW;
      Tap t=mk_tap(r,i-r*WW,sh,sh);
      const float* pl=srcb+(size_t)c0*shw;
      for(int c=0;c<nc;c++) up[c*NN+i]=tap_val(pl+(size_t)c*shw,t);
    }
    __syncthreads();
    for(int j=0;j<NHE;j++){
      int e=tid+j*TPE;
      if(e<EHH){
        int r=e/(WW-1); int u=r*WW+(e-r*(WW-1));
        const float* pu=up+u;
        for(int c=0;c<nc;c++){
          double d=(double)pu[c*NN]-(double)pu[c*NN+1];
          accH[j]=fma(d,d,accH[j]);
        }
      }
    }
    for(int j=0;j<NHE;j++){
      int u=tid+j*TPE;
      if(u<EHH){                       // vertical edge index EHH+u
        const float* pu=up+u;
        for(int c=0;c<nc;c++){
          double d=(double)pu[c*NN]-(double)pu[c*NN+WW];
          accV[j]=fma(d,d,accV[j]);
        }
      }
    }
  }
  double* outp=(f==0)? pd_low+(size_t)pidx*EEE
                     : pd_hf+((size_t)hfidx*nchunk+chunk)*EEE;
  #pragma unroll
  for(int j=0;j<NHE;j++){
    int e=tid+j*TPE;
    if(e<EHH){ outp[e]=accH[j]; outp[EHH+e]=accV[j]; }
  }
}

// ---------------------------------------------------------------------------
// 1024-thread Boruvka per (forest,batch).
__global__ __launch_bounds__(TPW) void k_boruvka(
  const double* __restrict__ pd_low, const double* __restrict__ pd_hf,
  int nchunk, float4* __restrict__ adjwG, unsigned char* __restrict__ adjG)
{
  __shared__ double dkey[EEE];                  // 36096 B
  __shared__ unsigned long long bestd[NN];      // 18432 B
  __shared__ int comp[NN];
  __shared__ int lnk[NN];
  __shared__ int beste[NN];
  __shared__ unsigned char mstf[EEE];
  __shared__ int flags[2];

  const int tid=threadIdx.x;
  const int pidx=blockIdx.x;
  const int f=pidx>>3;
  const float sigma=(f==0)?0.02f:1.0f;

  const double* p0=(f==0)? pd_low+(size_t)pidx*EEE
                         : pd_hf+((size_t)(pidx-8)*nchunk)*EEE;
  const int nck=(f==0)?1:nchunk;
  for(int e=tid;e<EEE;e+=TPW){
    double s=0.0;
    for(int k=0;k<nck;k++) s+=p0[(size_t)k*EEE+e];
    dkey[e]=s;
  }
  for(int i=tid;i<NN;i+=TPW) comp[i]=i;
  for(int e=tid;e<EEE;e+=TPW) mstf[e]=0;
  __syncthreads();

  for(int round=0;round<24;++round){
    for(int i=tid;i<NN;i+=TPW){ bestd[i]=~0ull; beste[i]=0x7fffffff; lnk[i]=i; }
    if(tid==0) flags[1]=0;
    __syncthreads();
    for(int e=tid;e<EEE;e+=TPW){
      int u,v; edge_uv(e,u,v);
      int cu=comp[u], cv=comp[v];
      if(cu!=cv){
        unsigned long long db=(unsigned long long)__double_as_longlong(dkey[e]);
        atomicMin(&bestd[cu],db);
        atomicMin(&bestd[cv],db);
      }
    }
    __syncthreads();
    for(int e=tid;e<EEE;e+=TPW){
      int u,v; edge_uv(e,u,v);
      int cu=comp[u], cv=comp[v];
      if(cu!=cv){
        unsigned long long db=(unsigned long long)__double_as_longlong(dkey[e]);
        if(db==bestd[cu]) atomicMin(&beste[cu],e);
        if(db==bestd[cv]) atomicMin(&beste[cv],e);
      }
    }
    __syncthreads();
    for(int i=tid;i<NN;i+=TPW){
      if(comp[i]==i && beste[i]!=0x7fffffff){
        int e=beste[i]; int u,v; edge_uv(e,u,v);
        int cu=comp[u], cv=comp[v];
        int other=(cu==i)?cv:cu;
        bool mutual=(beste[other]==e);
        if(!mutual || other<i){ lnk[i]=other; mstf[e]=1; flags[1]=1; }
      }
    }
    __syncthreads();
    if(flags[1]==0) break;          // no hooks => forest complete
    {
      volatile int* vl=lnk;
      for(int it=0;it<12;++it){
        for(int i=tid;i<NN;i+=TPW){ int a=vl[i]; int b2=vl[a]; if(a!=b2) vl[i]=b2; }
      }
      for(;;){
        if(tid==0) flags[0]=0;
        __syncthreads();
        for(int i=tid;i<NN;i+=TPW){
          int a=vl[i]; int b2=vl[a];
          if(a!=b2){ vl[i]=b2; flags[0]=1; }
        }
        __syncthreads();
        int ch=flags[0];
        __syncthreads();
        if(!ch) break;
      }
    }
    for(int i=tid;i<NN;i+=TPW) comp[i]=lnk[comp[i]];
    __syncthreads();
  }

  for(int i=tid;i<NN;i+=TPW){
    int r=i/WW, c=i-r*WW;
    int mask=0; float4 w; w.x=0.0f; w.y=0.0f; w.z=0.0f; w.w=0.0f;
    if(c>0    && mstf[r*(WW-1)+c-1]){ mask|=1; w.x=expf(-(float)dkey[r*(WW-1)+c-1]/sigma); }
    if(c<WW-1 && mstf[r*(WW-1)+c])  { mask|=2; w.y=expf(-(float)dkey[r*(WW-1)+c]/sigma); }
    if(r>0    && mstf[EHH+i-WW])    { mask|=4; w.z=expf(-(float)dkey[EHH+i-WW]/sigma); }
    if(r<HH-1 && mstf[EHH+i])       { mask|=8; w.w=expf(-(float)dkey[EHH+i]/sigma); }
    adjwG[(size_t)pidx*NN+i]=w;
    adjG[(size_t)pidx*NN+i]=(unsigned char)mask;
  }
}

// ---------------------------------------------------------------------------
// 1024-thread Euler-tour rooting via Wyllie list-ranking.
__global__ __launch_bounds__(TPR) void k_root(
  const float4* __restrict__ adjwG, const unsigned char* __restrict__ adjG,
  int* __restrict__ sbase)
{
  __shared__ unsigned int eA[ESLOT];   // 36864 B
  __shared__ unsigned int eB[ESLOT];   // 36864 B
  __shared__ float4 adjwS[NN];         // 36864 B
  __shared__ unsigned char adjS[NN];   // 2304 B
  __shared__ int chunkS[TPR];          // 4096 B
  __shared__ int maxdS;

  const int tid=threadIdx.x;
  const int pidx=blockIdx.x;
  {
    const float4* aw=adjwG+(size_t)pidx*NN;
    for(int t=tid;t<NN;t+=TPR) adjwS[t]=aw[t];
    const int* a4=(const int*)(adjG+(size_t)pidx*NN);
    int* s4=(int*)adjS;
    for(int t=tid;t<NN/4;t+=TPR) s4[t]=a4[t];
  }
  if(tid==0) maxdS=0;
  __syncthreads();

  const int m0=adjS[0];
  const int d0=(m0&1)?0:((m0&2)?1:((m0&4)?2:3));
  const int e0=d0;   // node 0 * 4 + d0

  for(int t=tid;t<ESLOT;t+=TPR){
    int u=t>>2, d=t&3;
    unsigned int pk=0;
    if(adjS[u]&(1<<d)){
      int v=(d==0)?u-1:(d==1)?u+1:(d==2)?u-WW:u+WW;
      int rd=d^1;
      int mv=adjS[v];
      int nd=rd;
      #pragma unroll
      for(int k2=4;k2>=1;k2--){ int dd=(rd+k2)&3; if(mv&(1<<dd)) nd=dd; }
      int ne=(v<<2)|nd;
      unsigned int nxt=(ne==e0)?SENTN:(unsigned int)ne;
      pk=(nxt<<16)|1u;
    }
    eA[t]=pk;
  }
  __syncthreads();

  unsigned int* P=eA; unsigned int* Q=eB;
  for(int r2=0;r2<13;r2++){
    for(int t=tid;t<ESLOT;t+=TPR){
      unsigned int pk=P[t];
      unsigned int dist=pk&0xFFFFu, nxt=pk>>16;
      if(dist && nxt!=SENTN){
        unsigned int pk2=P[nxt];
        dist+=pk2&0xFFFFu;
        nxt=pk2>>16;
        pk=(nxt<<16)|dist;
      }
      Q[t]=pk;
    }
    __syncthreads();
    unsigned int* tmp=P; P=Q; Q=tmp;
  }
  for(int t=tid;t<ESLOT;t+=TPR){
    unsigned int dist=P[t]&0xFFFFu;
    Q[t]=dist?(unsigned int)(LVE-(int)dist):0xFFFFFFFFu;
  }
  __syncthreads();

  int* scanA=(int*)P;
  for(int t=tid;t<ESLOT;t+=TPR){
    unsigned int pos=Q[t];
    if(pos!=0xFFFFFFFFu){
      int u=t>>2, d=t&3;
      int v=(d==0)?u-1:(d==1)?u+1:(d==2)?u-WW:u+WW;
      unsigned int rpos=Q[(v<<2)|(d^1)];
      scanA[pos]=(pos<rpos)?1:-1;
    }
  }
  __syncthreads();

  const int base=tid*RIPT;
  int vals[RIPT]; int lsum=0;
  #pragma unroll
  for(int j=0;j<RIPT;j++){
    int p=base+j;
    int v=(p<LVE)?scanA[p]:0;
    lsum+=v; vals[j]=lsum;
  }
  chunkS[tid]=lsum;
  __syncthreads();
  for(int off=1;off<TPR;off<<=1){
    int v=chunkS[tid];
    int vv=(tid>=off)?chunkS[tid-off]:0;
    __syncthreads();
    chunkS[tid]=v+vv;
    __syncthreads();
  }
  const int myoff=(tid>0)?chunkS[tid-1]:0;
  int mymax=0;
  #pragma unroll
  for(int j=0;j<RIPT;j++){
    int p=base+j;
    if(p<LVE){ int s=vals[j]+myoff; scanA[p]=s; if(s>mymax) mymax=s; }
  }
  if(mymax>0) atomicMax(&maxdS,mymax);
  __syncthreads();

  int* sp=sbase+(size_t)pidx*SSTRIDE_W;
  int4* g_pk=(int4*)(sp+PK_OFF);
  if(tid==0){
    g_pk[0]=make_int4(0,__float_as_int(0.0f),0,0);
    sp[D_OFF]=maxdS;
  }
  for(int t=tid;t<ESLOT;t+=TPR){
    unsigned int pos=Q[t];
    if(pos!=0xFFFFFFFFu){
      int u=t>>2, d=t&3;
      int v=(d==0)?u-1:(d==1)?u+1:(d==2)?u-WW:u+WW;
      unsigned int rpos=Q[(v<<2)|(d^1)];
      if(pos<rpos){                       // down edge: u = parent(v)
        float4 w4=adjwS[u];
        float w=(d==0)?w4.x:(d==1)?w4.y:(d==2)?w4.z:w4.w;
        g_pk[v]=make_int4(u,__float_as_int(w),scanA[pos],0);
      }
    }
  }
}

// ---------------------------------------------------------------------------
// Precompute pointer-doubling levels per problem (value-independent):
// level 0 = (parent, w); level t = compose(level t-1, level t-1 at anc).
// Stored to ws: ancT[(pidx*MAXT+t)*NN+i], prodT likewise, t=0..T-1.
__global__ __launch_bounds__(TPF) void k_tables(
  const int* __restrict__ sbase, int* __restrict__ ancT,
  float* __restrict__ prodT)
{
  __shared__ int   ancA[NN], ancB[NN];
  __shared__ float prmA[NN], prmB[NN];
  const int tid=threadIdx.x;
  const int pidx=blockIdx.x;
  const int* sp=sbase+(size_t)pidx*SSTRIDE_W;
  const int4* g_pk=(const int4*)(sp+PK_OFF);
  const int maxD=sp[D_OFF];
  int T=1; while((1<<T)<=maxD) T++;
  int* gA=ancT+(size_t)pidx*MAXT*NN;
  float* gP=prodT+(size_t)pidx*MAXT*NN;
  int* aP=ancA; int* aQ=ancB; float* pP=prmA; float* pQ=prmB;
  for(int i=tid;i<NN;i+=TPF){
    int4 rec=g_pk[i];
    aP[i]=rec.x; pP[i]=__int_as_float(rec.y);
    gA[i]=rec.x; gP[i]=pP[i];
  }
  __syncthreads();
  for(int t=1;t<T;t++){
    for(int i=tid;i<NN;i+=TPF){
      int a=aP[i];
      int a2=aP[a]; float pr=pP[i]*pP[a];
      aQ[i]=a2; pQ[i]=pr;
      gA[(size_t)t*NN+i]=a2; gP[(size_t)t*NN+i]=pr;
    }
    __syncthreads();
    { int* t1=aP; aP=aQ; aQ=t1; float* t2=pP; pP=pQ; pQ=t2; }
  }
}

// ---------------------------------------------------------------------------
// Value-only tree filter, ONE (problem, channel) per block.
// Upward round t: snapshot own values -> barrier -> atomicAdd to level-t
// ancestor gated by depth>=2^t.  Downward round t: b[i] += prod_t[i]*b[anc_t].
// After T rounds a==0 for all nodes -> F = b.  Tables read own-indexed
// (coalesced, L2-resident); only value arrays in LDS (18KB).
__global__ __launch_bounds__(TPF) void k_fchan(
  const float* __restrict__ X, float* __restrict__ Fout,
  const int* __restrict__ sbase, const int* __restrict__ ancT,
  const float* __restrict__ prodT, int pidx0)
{
  __shared__ float S[NN];    // 9216 B
  __shared__ float Sb[NN];   // 9216 B
  const int tid=threadIdx.x;
  const int pg=blockIdx.x/5, c=blockIdx.x%5;
  const int pidx=pidx0+pg;
  const int xb=pg&7;
  const int* sp=sbase+(size_t)pidx*SSTRIDE_W;
  const int4* g_pk=(const int4*)(sp+PK_OFF);
  const int maxD=sp[D_OFF];
  int T=1; while((1<<T)<=maxD) T++;
  const int* ancP=ancT+(size_t)pidx*MAXT*NN;
  const float* prmP=prodT+(size_t)pidx*MAXT*NN;

  int dep[NPL]; float wv[NPL];
  #pragma unroll
  for(int j=0;j<NPL;j++){
    int i=tid+j*TPF;
    if(i<NN){
      int4 rec=g_pk[i];
      dep[j]=rec.z; wv[j]=__int_as_float(rec.y);
      S[i]=(c<4)? X[((size_t)xb*KK+c)*NN+i] : 1.0f;
    } else { dep[j]=-1; wv[j]=0.0f; }
  }
  __syncthreads();

  // ---- upward ----
  for(int t=0;t<T;t++){
    float sn[NPL]; int aj[NPL]; float pj[NPL];
    #pragma unroll
    for(int j=0;j<NPL;j++){
      int i=tid+j*TPF;
      if(i<NN){ sn[j]=S[i]; aj[j]=ancP[(size_t)t*NN+i]; pj[j]=prmP[(size_t)t*NN+i]; }
      else { sn[j]=0.0f; aj[j]=0; pj[j]=0.0f; }
    }
    __syncthreads();
    int bit=1<<t;
    #pragma unroll
    for(int j=0;j<NPL;j++){
      if(dep[j]>=bit) atomicAdd(&S[aj[j]], pj[j]*sn[j]);
    }
    __syncthreads();
  }

  // ---- downward init: b = (1-w^2)*A_up (root w=0 -> b=A_up) ----
  #pragma unroll
  for(int j=0;j<NPL;j++){
    int i=tid+j*TPF;
    if(i<NN){ float fq=1.0f-wv[j]*wv[j]; Sb[i]=fq*S[i]; }
  }
  __syncthreads();

  // ---- downward rounds (copy-free ping-pong) ----
  float* Sp=Sb; float* Sq=S;
  for(int t=0;t<T;t++){
    float bn[NPL];
    #pragma unroll
    for(int j=0;j<NPL;j++){
      int i=tid+j*TPF;
      if(i<NN){
        int a=ancP[(size_t)t*NN+i]; float ai=prmP[(size_t)t*NN+i];
        bn[j]=fmaf(ai,Sp[a],Sp[i]);
      } else bn[j]=0.0f;
    }
    __syncthreads();
    #pragma unroll
    for(int j=0;j<NPL;j++){
      int i=tid+j*TPF;
      if(i<NN) Sq[i]=bn[j];
    }
    __syncthreads();
    { float* tmp=Sp; Sp=Sq; Sq=tmp; }
  }
  // a == 0 for all nodes after T rounds (2^T > maxD) -> F = b
  float* o=Fout+(size_t)blockIdx.x*NN;
  for(int i=tid;i<NN;i+=TPF) o[i]=Sp[i];
}

// ---------------------------------------------------------------------------
__global__ __launch_bounds__(TPB) void k_div0(const float* __restrict__ FA,
                                              float* __restrict__ AS){
  int t=blockIdx.x*TPB+threadIdx.x;
  if(t>=BB*KK*NN) return;
  int b=t/(KK*NN), rem=t-b*(KK*NN), c=rem/NN, i=rem-c*NN;
  float inv=1.0f/FA[((size_t)b*5+4)*NN+i];
  AS[t]=FA[((size_t)b*5+c)*NN+i]*inv;
}

// ---------------------------------------------------------------------------
__global__ __launch_bounds__(TPB) void k_loss(
  const float* __restrict__ FB, const float* __restrict__ probf,
  const float* __restrict__ rois, float* __restrict__ partials)
{
  __shared__ float red[TPB];
  const int tid=threadIdx.x;
  const int fb=blockIdx.x;          // 0..23, same order as old partials
  const int b=fb&7;
  const float* pb=probf+(size_t)b*KK*NN;
  float part=0.0f;
  for(int i=tid;i<NN;i+=TPB){
    int r=i/WW, c2=i-r*WW;
    float roi=rois[(size_t)b*(192*192)+(4*r)*192+(4*c2)];
    float inv=1.0f/FB[((size_t)fb*5+4)*NN+i];
    float s=fabsf(pb[i]      -FB[((size_t)fb*5+0)*NN+i]*inv)
          + fabsf(pb[NN+i]   -FB[((size_t)fb*5+1)*NN+i]*inv)
          + fabsf(pb[2*NN+i] -FB[((size_t)fb*5+2)*NN+i]*inv)
          + fabsf(pb[3*NN+i] -FB[((size_t)fb*5+3)*NN+i]*inv);
    part+=roi*s;
  }
  red[tid]=part; __syncthreads();
  for(int s2=TPB/2;s2>0;s2>>=1){ if(tid<s2) red[tid]+=red[tid+s2]; __syncthreads(); }
  if(tid==0) partials[fb]=red[0];
}

// ---------------------------------------------------------------------------
__global__ __launch_bounds__(TPB) void k_final(const float* __restrict__ rois,
    const float* __restrict__ partials, const float* __restrict__ wt,
    float* __restrict__ out)
{
  __shared__ float red[TPB];
  const int tid=threadIdx.x;
  float n=0.0f;
  for(int t=tid;t<BB*NN;t+=TPB){
    int b=t/NN, i=t-b*NN; int r=i/WW, c=i-r*WW;
    n += rois[(size_t)b*(192*192)+(4*r)*192+(4*c)];
  }
  red[tid]=n; __syncthreads();
  for(int s=TPB/2;s>0;s>>=1){ if(tid<s) red[tid]+=red[tid+s]; __syncthreads(); }
  if(tid==0){
    float loss=0.0f;
    for(int j=0;j<3*BB;j++) loss+=partials[j];
    float N=red[0];
    out[0]=wt[0]*((N>0.0f)?(loss/N):loss);
  }
}

// ---------------------------------------------------------------------------
extern "C" void kernel_launch(void* const* d_in, const int* in_sizes, int n_in,
                              void* d_out, int out_size, void* d_ws, size_t ws_size,
                              hipStream_t stream) {
  (void)in_sizes; (void)n_in; (void)out_size;
  const float* preds=(const float*)d_in[0];
  const float* lowf =(const float*)d_in[1];
  const float* hf1  =(const float*)d_in[2];
  const float* hf2  =(const float*)d_in[3];
  const float* hf3  =(const float*)d_in[4];
  const float* rois =(const float*)d_in[5];
  const float* wt   =(const float*)d_in[6];
  float* out=(float*)d_out;

  char* ws=(char*)d_ws;
  float* partials=(float*)ws;                                  // 24 floats @0
  float* probf=(float*)(ws+256);                               // 294,912 B
  float* AS   =(float*)(ws+256+(size_t)BB*KK*NN*4);            // 294,912 B
  size_t sb_off=256+(size_t)2*BB*KK*NN*4;                      // 590,080
  int*   sbase=(int*)(ws+sb_off);                              // 1,180,672 B
  size_t aw_off=sb_off+(size_t)32*SSTRIDE_W*4;                 // 1,770,752
  float4* adjwG=(float4*)(ws+aw_off);                          // 1,179,648 B
  size_t aj_off=aw_off+(size_t)32*NN*16;                       // 2,950,400
  unsigned char* adjG=(unsigned char*)(ws+aj_off);             // 73,728 B
  size_t pl_off=aj_off+(size_t)32*NN;                          // 3,024,128
  double* pd_low=(double*)(ws+pl_off);                         // 288,768 B
  size_t ph_off=pl_off+(size_t)8*EEE*8;                        // 3,312,896
  double* pd_hf=(double*)(ws+ph_off);                          // 24*nchunk*EEE*8

  // table/F buffers ALIAS pd_hf (dead after k_boruvka); need 8.56 MB <=
  // 13.86 MB (nchunk=16 floor, known to fit from R8).
  int*   ancT =(int*)  (ws+ph_off);                            // 3,538,944 B
  float* prodT=(float*)(ws+ph_off+(size_t)32*MAXT*NN*4);       // 3,538,944 B
  float* FA   =(float*)(ws+ph_off+(size_t)2*32*MAXT*NN*4);     // 40*NN*4
  float* FB   =(float*)(ws+ph_off+(size_t)2*32*MAXT*NN*4+(size_t)40*NN*4); // 120*NN*4

  int nchunk=32;
  if(ph_off+(size_t)24*32*EEE*8>ws_size) nchunk=16;            // floor: fits (R8)

  k_prob<<<(BB*NN+TPB-1)/TPB,TPB,0,stream>>>(preds,probf);
  k_edges<<<8+24*nchunk,TPE,0,stream>>>(lowf,hf1,hf2,hf3,pd_low,pd_hf,nchunk);
  k_boruvka<<<32,TPW,0,stream>>>(pd_low,pd_hf,nchunk,adjwG,adjG);
  k_root<<<32,TPR,0,stream>>>(adjwG,adjG,sbase);
  k_tables<<<32,TPF,0,stream>>>(sbase,ancT,prodT);
  k_fchan<<<40,TPF,0,stream>>>(probf,FA,sbase,ancT,prodT,0);
  k_div0<<<(BB*KK*NN+TPB-1)/TPB,TPB,0,stream>>>(FA,AS);
  k_fchan<<<120,TPF,0,stream>>>(AS,FB,sbase,ancT,prodT,8);
  k_loss<<<3*BB,TPB,0,stream>>>(FB,probf,rois,partials);
  k_final<<<1,TPB,0,stream>>>(rois,partials,wt,out);
}

// Round 12
// 232.560 us; speedup vs baseline: 3.1289x; 1.2530x over previous
//
#include <hip/hip_runtime.h>
#include <math.h>

// ---------------------------------------------------------------------------
// TreeEnergyLoss on MI355X.
// softmax -> k_edges (chunked f64 edge distances via LDS-upsampled embeddings,
// 1-D tap tables in LDS) -> k_redux (parallel fixed-order chunk sum -> dkeyG)
// -> k_boruvka (1024t Boruvka MST under strict (dist,edge-idx) order ==
// reference's stable Kruskal; lock-free path-halving find) -> k_root (1024t
// Euler-tour rooting, Wyllie) -> k_tables (pointer-doubling levels) ->
// k_fchan (one block per (problem,channel) value-only doubling passes) ->
// k_div0 / k_loss / k_final.
// ---------------------------------------------------------------------------

#define HH 48
#define WW 48
#define NN (HH*WW)          // 2304 nodes
#define EHH (HH*(WW-1))     // 2256 horizontal edges
#define EEE (2*EHH)         // 4512 edges
#define BB 8
#define KK 4
#define TPB 256
#define TPE 512             // edges kernel
#define TPW 1024            // boruvka kernel
#define TPR 1024            // rooting kernel
#define TPF 512             // fchan/table kernels
#define NPL 5               // nodes per lane (ceil 2304/512)
#define NHE ((EHH+TPE-1)/TPE)   // 5 edges per thread per orientation
#define ESLOT (4*NN)        // 9216 directed-edge slots
#define LVE (2*(NN-1))      // 4606 valid directed edges
#define RIPT ((LVE+TPR-1)/TPR)  // 5 scan items per thread
#define SENTN 0xFFFFu
#define MAXT 12             // 2^12 = 4096 > max possible depth (2303)

// per-problem structure record in ws (ints): node-indexed int4 (parent,w,depth,0) | maxdepth
#define SSTRIDE_W (4*NN+8)
#define PK_OFF 0
#define D_OFF (4*NN)

__device__ __forceinline__ void edge_uv(int e,int& u,int& v){
  if(e<EHH){ int r=e/(WW-1); int c=e-r*(WW-1); u=r*WW+c; v=u+1; }
  else     { int t=e-EHH; u=t; v=t+WW; }
}

__device__ __forceinline__ void pick_src(int f, const float* lowf, const float* hf1,
                                         const float* hf2, const float* hf3,
                                         const float*& src, int& sh, int& C){
  if(f==0){src=lowf; sh=192; C=3;}
  else if(f==1){src=hf1; sh=24; C=512;}
  else if(f==2){src=hf2; sh=12; C=512;}
  else        {src=hf3; sh=6;  C=512;}
}

// ---------------------------------------------------------------------------
__global__ __launch_bounds__(TPB) void k_prob(const float* __restrict__ preds,
                                              float* __restrict__ probf){
  int t=blockIdx.x*TPB+threadIdx.x;
  if(t>=BB*NN) return;
  int b=t/NN, i=t-b*NN;
  const float* p=preds+(size_t)b*KK*NN+i;
  float x0=p[0],x1=p[NN],x2=p[2*NN],x3=p[3*NN];
  float mx=fmaxf(fmaxf(x0,x1),fmaxf(x2,x3));
  float e0=expf(x0-mx),e1=expf(x1-mx),e2=expf(x2-mx),e3=expf(x3-mx);
  float s=((e0+e1)+(e2+e3));
  float* q=probf+(size_t)b*KK*NN+i;
  q[0]=e0/s; q[NN]=e1/s; q[2*NN]=e2/s; q[3*NN]=e3/s;
}

// ---------------------------------------------------------------------------
// Parallel edge-distance partials.  One block = (problem, channel-chunk).
// 1-D tap tables (y0/y1/wy per output coord; rows==cols since src square)
// built once in LDS; bilinear weights computed with EXACT same float
// expressions as the original mk_tap/tap_val -> upsample bit-identical.
__global__ __launch_bounds__(TPE) void k_edges(
  const float* __restrict__ lowf, const float* __restrict__ hf1,
  const float* __restrict__ hf2, const float* __restrict__ hf3,
  double* __restrict__ pd_low, double* __restrict__ pd_hf, int nchunk)
{
  __shared__ float up[4*NN];   // 36864 B
  __shared__ int   y0t[48], y1t[48];
  __shared__ float wyt[48];
  const int tid=threadIdx.x;
  int pidx, chunk, hfidx=0;
  if(blockIdx.x<8){ pidx=blockIdx.x; chunk=0; }
  else { int t=blockIdx.x-8; hfidx=t/nchunk; chunk=t-hfidx*nchunk; pidx=8+hfidx; }
  const int f=pidx>>3, b=pidx&7;
  const float* src; int sh,C;
  pick_src(f,lowf,hf1,hf2,hf3,src,sh,C);
  const int shw=sh*sh;
  const float* srcb=src+(size_t)b*C*shw;
  const int cpc=(f==0)?3:(512/nchunk);
  const int c_begin=chunk*cpc;
  const int c_end=(c_begin+cpc<C)?(c_begin+cpc):C;

  if(tid<48){
    float sy=(float)sh/48.0f;
    float ys=fmaxf(((float)tid+0.5f)*sy-0.5f,0.0f);
    int y0=(int)ys; if(y0>sh-1) y0=sh-1;
    int y1=y0+1; if(y1>sh-1) y1=sh-1;
    y0t[tid]=y0; y1t[tid]=y1; wyt[tid]=ys-(float)y0;
  }

  double accH[NHE], accV[NHE];
  #pragma unroll
  for(int j=0;j<NHE;j++){ accH[j]=0.0; accV[j]=0.0; }

  for(int c0=c_begin;c0<c_end;c0+=4){
    const int nc=(c_end-c0<4)?(c_end-c0):4;
    __syncthreads();               // protect previous sub-stage reads (and table init)
    for(int i=tid;i<NN;i+=TPE){
      int r=i/WW, c=i-r*WW;
      int y0=y0t[r], y1=y1t[r]; float wy=wyt[r];
      int x0=y0t[c], x1=y1t[c]; float wx=wyt[c];
      float w00=(1.0f-wy)*(1.0f-wx), w01=(1.0f-wy)*wx;
      float w10=wy*(1.0f-wx),        w11=wy*wx;
      int o00=y0*sh+x0, o01=y0*sh+x1, o10=y1*sh+x0, o11=y1*sh+x1;
      const float* pl=srcb+(size_t)c0*shw;
      for(int cc=0;cc<nc;cc++){
        const float* p=pl+(size_t)cc*shw;
        up[cc*NN+i]=w00*p[o00]+w01*p[o01]+w10*p[o10]+w11*p[o11];
      }
    }
    __syncthreads();
    for(int j=0;j<NHE;j++){
      int e=tid+j*TPE;
      if(e<EHH){
        int r=e/(WW-1); int u=r*WW+(e-r*(WW-1));
        const float* pu=up+u;
        for(int c=0;c<nc;c++){
          double d=(double)pu[c*NN]-(double)pu[c*NN+1];
          accH[j]=fma(d,d,accH[j]);
        }
      }
    }
    for(int j=0;j<NHE;j++){
      int u=tid+j*TPE;
      if(u<EHH){                       // vertical edge index EHH+u
        const float* pu=up+u;
        for(int c=0;c<nc;c++){
          double d=(double)pu[c*NN]-(double)pu[c*NN+WW];
          accV[j]=fma(d,d,accV[j]);
        }
      }
    }
  }
  double* outp=(f==0)? pd_low+(size_t)pidx*EEE
                     : pd_hf+((size_t)hfidx*nchunk+chunk)*EEE;
  #pragma unroll
  for(int j=0;j<NHE;j++){
    int e=tid+j*TPE;
    if(e<EHH){ outp[e]=accH[j]; outp[EHH+e]=accV[j]; }
  }
}

// ---------------------------------------------------------------------------
// Parallel fixed-order chunk reduction: dkeyG[pidx][e].  Thread = (pidx,e);
// chunks summed ascending (bit-identical to the old in-boruvka gather).
__global__ __launch_bounds__(TPB) void k_redux(
  const double* __restrict__ pd_low, const double* __restrict__ pd_hf,
  int nchunk, double* __restrict__ dkeyG)
{
  int t=blockIdx.x*TPB+threadIdx.x;
  if(t>=32*EEE) return;
  int pidx=t/EEE, e=t-pidx*EEE;
  double s;
  if(pidx<8) s=pd_low[(size_t)pidx*EEE+e];
  else {
    const double* p0=pd_hf+((size_t)(pidx-8)*nchunk)*EEE+e;
    s=0.0;
    for(int k=0;k<nchunk;k++) s+=p0[(size_t)k*EEE];
  }
  dkeyG[t]=s;
}

// ---------------------------------------------------------------------------
// 1024-thread Boruvka per (forest,batch).  Lock-free path-halving find
// (no barriers inside; LDS word writes are atomic; roots are deterministic).
__global__ __launch_bounds__(TPW) void k_boruvka(
  const double* __restrict__ dkeyG,
  float4* __restrict__ adjwG, unsigned char* __restrict__ adjG)
{
  __shared__ double dkey[EEE];                  // 36096 B
  __shared__ unsigned long long bestd[NN];      // 18432 B
  __shared__ int comp[NN];
  __shared__ int lnk[NN];
  __shared__ int beste[NN];
  __shared__ unsigned char mstf[EEE];
  __shared__ int flags[2];

  const int tid=threadIdx.x;
  const int pidx=blockIdx.x;
  const int f=pidx>>3;
  const float sigma=(f==0)?0.02f:1.0f;

  const double* p0=dkeyG+(size_t)pidx*EEE;
  for(int e=tid;e<EEE;e+=TPW) dkey[e]=p0[e];
  for(int i=tid;i<NN;i+=TPW) comp[i]=i;
  for(int e=tid;e<EEE;e+=TPW) mstf[e]=0;
  __syncthreads();

  for(int round=0;round<20;++round){
    for(int i=tid;i<NN;i+=TPW){ bestd[i]=~0ull; beste[i]=0x7fffffff; lnk[i]=i; }
    if(tid==0) flags[1]=0;
    __syncthreads();
    for(int e=tid;e<EEE;e+=TPW){
      int u,v; edge_uv(e,u,v);
      int cu=comp[u], cv=comp[v];
      if(cu!=cv){
        unsigned long long db=(unsigned long long)__double_as_longlong(dkey[e]);
        atomicMin(&bestd[cu],db);
        atomicMin(&bestd[cv],db);
      }
    }
    __syncthreads();
    for(int e=tid;e<EEE;e+=TPW){
      int u,v; edge_uv(e,u,v);
      int cu=comp[u], cv=comp[v];
      if(cu!=cv){
        unsigned long long db=(unsigned long long)__double_as_longlong(dkey[e]);
        if(db==bestd[cu]) atomicMin(&beste[cu],e);
        if(db==bestd[cv]) atomicMin(&beste[cv],e);
      }
    }
    __syncthreads();
    // hook (mutual pair resolved toward smaller id; mutual => SAME edge since order strict)
    for(int i=tid;i<NN;i+=TPW){
      if(comp[i]==i && beste[i]!=0x7fffffff){
        int e=beste[i]; int u,v; edge_uv(e,u,v);
        int cu=comp[u], cv=comp[v];
        int other=(cu==i)?cv:cu;
        bool mutual=(beste[other]==e);
        if(!mutual || other<i){ lnk[i]=other; mstf[e]=1; flags[1]=1; }
      }
    }
    __syncthreads();
    if(flags[1]==0) break;          // no hooks => forest complete
    // ---- lock-free path-halving find: comp[i] = root of hook tree ----
    {
      volatile int* vl=lnk;
      for(int i=tid;i<NN;i+=TPW){
        int x=comp[i];
        int p=vl[x];
        int gp=vl[p];
        while(p!=gp){
          vl[x]=gp;
          x=p; p=gp; gp=vl[p];
        }
        comp[i]=p;
      }
    }
    __syncthreads();
  }

  // ---- emit per-node adjacency mask + per-direction weights ----
  for(int i=tid;i<NN;i+=TPW){
    int r=i/WW, c=i-r*WW;
    int mask=0; float4 w; w.x=0.0f; w.y=0.0f; w.z=0.0f; w.w=0.0f;
    if(c>0    && mstf[r*(WW-1)+c-1]){ mask|=1; w.x=expf(-(float)dkey[r*(WW-1)+c-1]/sigma); }
    if(c<WW-1 && mstf[r*(WW-1)+c])  { mask|=2; w.y=expf(-(float)dkey[r*(WW-1)+c]/sigma); }
    if(r>0    && mstf[EHH+i-WW])    { mask|=4; w.z=expf(-(float)dkey[EHH+i-WW]/sigma); }
    if(r<HH-1 && mstf[EHH+i])       { mask|=8; w.w=expf(-(float)dkey[EHH+i]/sigma); }
    adjwG[(size_t)pidx*NN+i]=w;
    adjG[(size_t)pidx*NN+i]=(unsigned char)mask;
  }
}

// ---------------------------------------------------------------------------
// 1024-thread Euler-tour rooting via Wyllie list-ranking.
__global__ __launch_bounds__(TPR) void k_root(
  const float4* __restrict__ adjwG, const unsigned char* __restrict__ adjG,
  int* __restrict__ sbase)
{
  __shared__ unsigned int eA[ESLOT];   // 36864 B
  __shared__ unsigned int eB[ESLOT];   // 36864 B
  __shared__ float4 adjwS[NN];         // 36864 B
  __shared__ unsigned char adjS[NN];   // 2304 B
  __shared__ int chunkS[TPR];          // 4096 B
  __shared__ int maxdS;

  const int tid=threadIdx.x;
  const int pidx=blockIdx.x;
  {
    const float4* aw=adjwG+(size_t)pidx*NN;
    for(int t=tid;t<NN;t+=TPR) adjwS[t]=aw[t];
    const int* a4=(const int*)(adjG+(size_t)pidx*NN);
    int* s4=(int*)adjS;
    for(int t=tid;t<NN/4;t+=TPR) s4[t]=a4[t];
  }
  if(tid==0) maxdS=0;
  __syncthreads();

  const int m0=adjS[0];
  const int d0=(m0&1)?0:((m0&2)?1:((m0&4)?2:3));
  const int e0=d0;   // node 0 * 4 + d0

  for(int t=tid;t<ESLOT;t+=TPR){
    int u=t>>2, d=t&3;
    unsigned int pk=0;
    if(adjS[u]&(1<<d)){
      int v=(d==0)?u-1:(d==1)?u+1:(d==2)?u-WW:u+WW;
      int rd=d^1;
      int mv=adjS[v];
      int nd=rd;
      #pragma unroll
      for(int k2=4;k2>=1;k2--){ int dd=(rd+k2)&3; if(mv&(1<<dd)) nd=dd; }
      int ne=(v<<2)|nd;
      unsigned int nxt=(ne==e0)?SENTN:(unsigned int)ne;
      pk=(nxt<<16)|1u;
    }
    eA[t]=pk;
  }
  __syncthreads();

  unsigned int* P=eA; unsigned int* Q=eB;
  for(int r2=0;r2<13;r2++){
    for(int t=tid;t<ESLOT;t+=TPR){
      unsigned int pk=P[t];
      unsigned int dist=pk&0xFFFFu, nxt=pk>>16;
      if(dist && nxt!=SENTN){
        unsigned int pk2=P[nxt];
        dist+=pk2&0xFFFFu;
        nxt=pk2>>16;
        pk=(nxt<<16)|dist;
      }
      Q[t]=pk;
    }
    __syncthreads();
    unsigned int* tmp=P; P=Q; Q=tmp;
  }
  for(int t=tid;t<ESLOT;t+=TPR){
    unsigned int dist=P[t]&0xFFFFu;
    Q[t]=dist?(unsigned int)(LVE-(int)dist):0xFFFFFFFFu;
  }
  __syncthreads();

  int* scanA=(int*)P;
  for(int t=tid;t<ESLOT;t+=TPR){
    unsigned int pos=Q[t];
    if(pos!=0xFFFFFFFFu){
      int u=t>>2, d=t&3;
      int v=(d==0)?u-1:(d==1)?u+1:(d==2)?u-WW:u+WW;
      unsigned int rpos=Q[(v<<2)|(d^1)];
      scanA[pos]=(pos<rpos)?1:-1;
    }
  }
  __syncthreads();

  const int base=tid*RIPT;
  int vals[RIPT]; int lsum=0;
  #pragma unroll
  for(int j=0;j<RIPT;j++){
    int p=base+j;
    int v=(p<LVE)?scanA[p]:0;
    lsum+=v; vals[j]=lsum;
  }
  chunkS[tid]=lsum;
  __syncthreads();
  for(int off=1;off<TPR;off<<=1){
    int v=chunkS[tid];
    int vv=(tid>=off)?chunkS[tid-off]:0;
    __syncthreads();
    chunkS[tid]=v+vv;
    __syncthreads();
  }
  const int myoff=(tid>0)?chunkS[tid-1]:0;
  int mymax=0;
  #pragma unroll
  for(int j=0;j<RIPT;j++){
    int p=base+j;
    if(p<LVE){ int s=vals[j]+myoff; scanA[p]=s; if(s>mymax) mymax=s; }
  }
  if(mymax>0) atomicMax(&maxdS,mymax);
  __syncthreads();

  int* sp=sbase+(size_t)pidx*SSTRIDE_W;
  int4* g_pk=(int4*)(sp+PK_OFF);
  if(tid==0){
    g_pk[0]=make_int4(0,__float_as_int(0.0f),0,0);
    sp[D_OFF]=maxdS;
  }
  for(int t=tid;t<ESLOT;t+=TPR){
    unsigned int pos=Q[t];
    if(pos!=0xFFFFFFFFu){
      int u=t>>2, d=t&3;
      int v=(d==0)?u-1:(d==1)?u+1:(d==2)?u-WW:u+WW;
      unsigned int rpos=Q[(v<<2)|(d^1)];
      if(pos<rpos){                       // down edge: u = parent(v)
        float4 w4=adjwS[u];
        float w=(d==0)?w4.x:(d==1)?w4.y:(d==2)?w4.z:w4.w;
        g_pk[v]=make_int4(u,__float_as_int(w),scanA[pos],0);
      }
    }
  }
}

// ---------------------------------------------------------------------------
// Precompute pointer-doubling levels per problem (value-independent).
__global__ __launch_bounds__(TPF) void k_tables(
  const int* __restrict__ sbase, int* __restrict__ ancT,
  float* __restrict__ prodT)
{
  __shared__ int   ancA[NN], ancB[NN];
  __shared__ float prmA[NN], prmB[NN];
  const int tid=threadIdx.x;
  const int pidx=blockIdx.x;
  const int* sp=sbase+(size_t)pidx*SSTRIDE_W;
  const int4* g_pk=(const int4*)(sp+PK_OFF);
  const int maxD=sp[D_OFF];
  int T=1; while((1<<T)<=maxD) T++;
  int* gA=ancT+(size_t)pidx*MAXT*NN;
  float* gP=prodT+(size_t)pidx*MAXT*NN;
  int* aP=ancA; int* aQ=ancB; float* pP=prmA; float* pQ=prmB;
  for(int i=tid;i<NN;i+=TPF){
    int4 rec=g_pk[i];
    aP[i]=rec.x; pP[i]=__int_as_float(rec.y);
    gA[i]=rec.x; gP[i]=pP[i];
  }
  __syncthreads();
  for(int t=1;t<T;t++){
    for(int i=tid;i<NN;i+=TPF){
      int a=aP[i];
      int a2=aP[a]; float pr=pP[i]*pP[a];
      aQ[i]=a2; pQ[i]=pr;
      gA[(size_t)t*NN+i]=a2; gP[(size_t)t*NN+i]=pr;
    }
    __syncthreads();
    { int* t1=aP; aP=aQ; aQ=t1; float* t2=pP; pP=pQ; pQ=t2; }
  }
}

// ---------------------------------------------------------------------------
// Value-only tree filter, ONE (problem, channel) per block.
__global__ __launch_bounds__(TPF) void k_fchan(
  const float* __restrict__ X, float* __restrict__ Fout,
  const int* __restrict__ sbase, const int* __restrict__ ancT,
  const float* __restrict__ prodT, int pidx0)
{
  __shared__ float S[NN];    // 9216 B
  __shared__ float Sb[NN];   // 9216 B
  const int tid=threadIdx.x;
  const int pg=blockIdx.x/5, c=blockIdx.x%5;
  const int pidx=pidx0+pg;
  const int xb=pg&7;
  const int* sp=sbase+(size_t)pidx*SSTRIDE_W;
  const int4* g_pk=(const int4*)(sp+PK_OFF);
  const int maxD=sp[D_OFF];
  int T=1; while((1<<T)<=maxD) T++;
  const int* ancP=ancT+(size_t)pidx*MAXT*NN;
  const float* prmP=prodT+(size_t)pidx*MAXT*NN;

  int dep[NPL]; float wv[NPL];
  #pragma unroll
  for(int j=0;j<NPL;j++){
    int i=tid+j*TPF;
    if(i<NN){
      int4 rec=g_pk[i];
      dep[j]=rec.z; wv[j]=__int_as_float(rec.y);
      S[i]=(c<4)? X[((size_t)xb*KK+c)*NN+i] : 1.0f;
    } else { dep[j]=-1; wv[j]=0.0f; }
  }
  __syncthreads();

  // ---- upward ----
  for(int t=0;t<T;t++){
    float sn[NPL]; int aj[NPL]; float pj[NPL];
    #pragma unroll
    for(int j=0;j<NPL;j++){
      int i=tid+j*TPF;
      if(i<NN){ sn[j]=S[i]; aj[j]=ancP[(size_t)t*NN+i]; pj[j]=prmP[(size_t)t*NN+i]; }
      else { sn[j]=0.0f; aj[j]=0; pj[j]=0.0f; }
    }
    __syncthreads();
    int bit=1<<t;
    #pragma unroll
    for(int j=0;j<NPL;j++){
      if(dep[j]>=bit) atomicAdd(&S[aj[j]], pj[j]*sn[j]);
    }
    __syncthreads();
  }

  // ---- downward init: b = (1-w^2)*A_up (root w=0 -> b=A_up) ----
  #pragma unroll
  for(int j=0;j<NPL;j++){
    int i=tid+j*TPF;
    if(i<NN){ float fq=1.0f-wv[j]*wv[j]; Sb[i]=fq*S[i]; }
  }
  __syncthreads();

  // ---- downward rounds (copy-free ping-pong) ----
  float* Sp=Sb; float* Sq=S;
  for(int t=0;t<T;t++){
    float bn[NPL];
    #pragma unroll
    for(int j=0;j<NPL;j++){
      int i=tid+j*TPF;
      if(i<NN){
        int a=ancP[(size_t)t*NN+i]; float ai=prmP[(size_t)t*NN+i];
        bn[j]=fmaf(ai,Sp[a],Sp[i]);
      } else bn[j]=0.0f;
    }
    __syncthreads();
    #pragma unroll
    for(int j=0;j<NPL;j++){
      int i=tid+j*TPF;
      if(i<NN) Sq[i]=bn[j];
    }
    __syncthreads();
    { float* tmp=Sp; Sp=Sq; Sq=tmp; }
  }
  // a == 0 for all nodes after T rounds (2^T > maxD) -> F = b
  float* o=Fout+(size_t)blockIdx.x*NN;
  for(int i=tid;i<NN;i+=TPF) o[i]=Sp[i];
}

// ---------------------------------------------------------------------------
__global__ __launch_bounds__(TPB) void k_div0(const float* __restrict__ FA,
                                              float* __restrict__ AS){
  int t=blockIdx.x*TPB+threadIdx.x;
  if(t>=BB*KK*NN) return;
  int b=t/(KK*NN), rem=t-b*(KK*NN), c=rem/NN, i=rem-c*NN;
  float inv=1.0f/FA[((size_t)b*5+4)*NN+i];
  AS[t]=FA[((size_t)b*5+c)*NN+i]*inv;
}

// ---------------------------------------------------------------------------
__global__ __launch_bounds__(TPB) void k_loss(
  const float* __restrict__ FB, const float* __restrict__ probf,
  const float* __restrict__ rois, float* __restrict__ partials)
{
  __shared__ float red[TPB];
  const int tid=threadIdx.x;
  const int fb=blockIdx.x;          // 0..23
  const int b=fb&7;
  const float* pb=probf+(size_t)b*KK*NN;
  float part=0.0f;
  for(int i=tid;i<NN;i+=TPB){
    int r=i/WW, c2=i-r*WW;
    float roi=rois[(size_t)b*(192*192)+(4*r)*192+(4*c2)];
    float inv=1.0f/FB[((size_t)fb*5+4)*NN+i];
    float s=fabsf(pb[i]      -FB[((size_t)fb*5+0)*NN+i]*inv)
          + fabsf(pb[NN+i]   -FB[((size_t)fb*5+1)*NN+i]*inv)
          + fabsf(pb[2*NN+i] -FB[((size_t)fb*5+2)*NN+i]*inv)
          + fabsf(pb[3*NN+i] -FB[((size_t)fb*5+3)*NN+i]*inv);
    part+=roi*s;
  }
  red[tid]=part; __syncthreads();
  for(int s2=TPB/2;s2>0;s2>>=1){ if(tid<s2) red[tid]+=red[tid+s2]; __syncthreads(); }
  if(tid==0) partials[fb]=red[0];
}

// ---------------------------------------------------------------------------
__global__ __launch_bounds__(TPB) void k_final(const float* __restrict__ rois,
    const float* __restrict__ partials, const float* __restrict__ wt,
    float* __restrict__ out)
{
  __shared__ float red[TPB];
  const int tid=threadIdx.x;
  float n=0.0f;
  for(int t=tid;t<BB*NN;t+=TPB){
    int b=t/NN, i=t-b*NN; int r=i/WW, c=i-r*WW;
    n += rois[(size_t)b*(192*192)+(4*r)*192+(4*c)];
  }
  red[tid]=n; __syncthreads();
  for(int s=TPB/2;s>0;s>>=1){ if(tid<s) red[tid]+=red[tid+s]; __syncthreads(); }
  if(tid==0){
    float loss=0.0f;
    for(int j=0;j<3*BB;j++) loss+=partials[j];
    float N=red[0];
    out[0]=wt[0]*((N>0.0f)?(loss/N):loss);
  }
}

// ---------------------------------------------------------------------------
extern "C" void kernel_launch(void* const* d_in, const int* in_sizes, int n_in,
                              void* d_out, int out_size, void* d_ws, size_t ws_size,
                              hipStream_t stream) {
  (void)in_sizes; (void)n_in; (void)out_size;
  const float* preds=(const float*)d_in[0];
  const float* lowf =(const float*)d_in[1];
  const float* hf1  =(const float*)d_in[2];
  const float* hf2  =(const float*)d_in[3];
  const float* hf3  =(const float*)d_in[4];
  const float* rois =(const float*)d_in[5];
  const float* wt   =(const float*)d_in[6];
  float* out=(float*)d_out;

  char* ws=(char*)d_ws;
  float* partials=(float*)ws;                                  // 24 floats @0
  float* probf=(float*)(ws+256);                               // 294,912 B
  float* AS   =(float*)(ws+256+(size_t)BB*KK*NN*4);            // 294,912 B
  size_t sb_off=256+(size_t)2*BB*KK*NN*4;                      // 590,080
  int*   sbase=(int*)(ws+sb_off);                              // 1,180,672 B
  size_t aw_off=sb_off+(size_t)32*SSTRIDE_W*4;                 // 1,770,752
  float4* adjwG=(float4*)(ws+aw_off);                          // 1,179,648 B
  size_t aj_off=aw_off+(size_t)32*NN*16;                       // 2,950,400
  unsigned char* adjG=(unsigned char*)(ws+aj_off);             // 73,728 B
  size_t dk_off=aj_off+(size_t)32*NN;                          // 3,024,128 (8-mult)
  double* dkeyG=(double*)(ws+dk_off);                          // 32*EEE*8 = 1,155,072 B
  size_t pl_off=dk_off+(size_t)32*EEE*8;                       // 4,179,200
  double* pd_low=(double*)(ws+pl_off);                         // 288,768 B
  size_t ph_off=pl_off+(size_t)8*EEE*8;                        // 4,467,968
  double* pd_hf=(double*)(ws+ph_off);                          // 24*nchunk*EEE*8

  // table/F buffers ALIAS pd_hf (dead after k_redux); 8.56 MB <= 13.86 MB floor.
  int*   ancT =(int*)  (ws+ph_off);                            // 3,538,944 B
  float* prodT=(float*)(ws+ph_off+(size_t)32*MAXT*NN*4);       // 3,538,944 B
  float* FA   =(float*)(ws+ph_off+(size_t)2*32*MAXT*NN*4);     // 40*NN*4
  float* FB   =(float*)(ws+ph_off+(size_t)2*32*MAXT*NN*4+(size_t)40*NN*4); // 120*NN*4

  int nchunk=32;
  if(ph_off+(size_t)24*32*EEE*8>ws_size) nchunk=16;

  k_prob<<<(BB*NN+TPB-1)/TPB,TPB,0,stream>>>(preds,probf);
  k_edges<<<8+24*nchunk,TPE,0,stream>>>(lowf,hf1,hf2,hf3,pd_low,pd_hf,nchunk);
  k_redux<<<(32*EEE+TPB-1)/TPB,TPB,0,stream>>>(pd_low,pd_hf,nchunk,dkeyG);
  k_boruvka<<<32,TPW,0,stream>>>(dkeyG,adjwG,adjG);
  k_root<<<32,TPR,0,stream>>>(adjwG,adjG,sbase);
  k_tables<<<32,TPF,0,stream>>>(sbase,ancT,prodT);
  k_fchan<<<40,TPF,0,stream>>>(probf,FA,sbase,ancT,prodT,0);
  k_div0<<<(BB*KK*NN+TPB-1)/TPB,TPB,0,stream>>>(FA,AS);
  k_fchan<<<120,TPF,0,stream>>>(AS,FB,sbase,ancT,prodT,8);
  k_loss<<<3*BB,TPB,0,stream>>>(FB,probf,rois,partials);
  k_final<<<1,TPB,0,stream>>>(rois,partials,wt,out);
}

// Round 13
// 226.961 us; speedup vs baseline: 3.2061x; 1.0247x over previous
//
#include <hip/hip_runtime.h>
#include <math.h>

// ---------------------------------------------------------------------------
// TreeEnergyLoss on MI355X.
// softmax -> k_edges (chunked f64 edge distances via LDS-upsampled embeddings;
// node-centric shared-read edge loops) -> k_redux (parallel fixed-order chunk
// sum -> dkeyG) -> k_struct (FUSED: 1024t Boruvka MST under strict
// (dist,edge-idx) order == reference's stable Kruskal + Euler-tour rooting
// via Wyllie list-ranking + pointer-doubling level tables; one 123.6KB LDS
// arena with phase-aliased regions) -> k_fchan (one block per
// (problem,channel) value-only doubling passes) -> k_div0 / k_loss / k_final.
// ---------------------------------------------------------------------------

#define HH 48
#define WW 48
#define NN (HH*WW)          // 2304 nodes
#define EHH (HH*(WW-1))     // 2256 horizontal edges
#define EEE (2*EHH)         // 4512 edges
#define BB 8
#define KK 4
#define TPB 256
#define TPE 512             // edges kernel
#define TPW 1024            // struct kernel
#define TPF 512             // fchan kernel
#define NPL 5               // nodes per lane in fchan (ceil 2304/512)
#define NPN 5               // nodes per thread in k_edges (ceil 2304/512)
#define ESLOT (4*NN)        // 9216 directed-edge slots
#define LVE (2*(NN-1))      // 4606 valid directed edges
#define RIPT ((LVE+TPW-1)/TPW)  // 5 scan items per thread
#define SENTN 0xFFFFu
#define MAXT 12             // 2^12 = 4096 > max possible depth (2303)

// per-problem structure record in ws (ints): node-indexed int4 (parent,w,depth,0) | maxdepth
#define SSTRIDE_W (4*NN+8)
#define PK_OFF 0
#define D_OFF (4*NN)

__device__ __forceinline__ void edge_uv(int e,int& u,int& v){
  if(e<EHH){ int r=e/(WW-1); int c=e-r*(WW-1); u=r*WW+c; v=u+1; }
  else     { int t=e-EHH; u=t; v=t+WW; }
}

__device__ __forceinline__ void pick_src(int f, const float* lowf, const float* hf1,
                                         const float* hf2, const float* hf3,
                                         const float*& src, int& sh, int& C){
  if(f==0){src=lowf; sh=192; C=3;}
  else if(f==1){src=hf1; sh=24; C=512;}
  else if(f==2){src=hf2; sh=12; C=512;}
  else        {src=hf3; sh=6;  C=512;}
}

// ---------------------------------------------------------------------------
__global__ __launch_bounds__(TPB) void k_prob(const float* __restrict__ preds,
                                              float* __restrict__ probf){
  int t=blockIdx.x*TPB+threadIdx.x;
  if(t>=BB*NN) return;
  int b=t/NN, i=t-b*NN;
  const float* p=preds+(size_t)b*KK*NN+i;
  float x0=p[0],x1=p[NN],x2=p[2*NN],x3=p[3*NN];
  float mx=fmaxf(fmaxf(x0,x1),fmaxf(x2,x3));
  float e0=expf(x0-mx),e1=expf(x1-mx),e2=expf(x2-mx),e3=expf(x3-mx);
  float s=((e0+e1)+(e2+e3));
  float* q=probf+(size_t)b*KK*NN+i;
  q[0]=e0/s; q[NN]=e1/s; q[2*NN]=e2/s; q[3*NN]=e3/s;
}

// ---------------------------------------------------------------------------
// Parallel edge-distance partials.  One block = (problem, channel-chunk).
// NODE-CENTRIC edge loops: per (node u, channel) read up[u], up[u+1],
// up[u+WW] once (u/u+1 adjacent -> ds_read2 fusion) and feed BOTH the H and
// V edge accumulators.  Per-edge channel accumulation order identical to
// prior rounds -> dkey bit-identical -> same MST.
__global__ __launch_bounds__(TPE) void k_edges(
  const float* __restrict__ lowf, const float* __restrict__ hf1,
  const float* __restrict__ hf2, const float* __restrict__ hf3,
  double* __restrict__ pd_low, double* __restrict__ pd_hf, int nchunk)
{
  __shared__ float up[4*NN+64];   // 37120 B (pad: guarded-unused over-reads)
  __shared__ int   y0t[48], y1t[48];
  __shared__ float wyt[48];
  const int tid=threadIdx.x;
  int pidx, chunk, hfidx=0;
  if(blockIdx.x<8){ pidx=blockIdx.x; chunk=0; }
  else { int t=blockIdx.x-8; hfidx=t/nchunk; chunk=t-hfidx*nchunk; pidx=8+hfidx; }
  const int f=pidx>>3, b=pidx&7;
  const float* src; int sh,C;
  pick_src(f,lowf,hf1,hf2,hf3,src,sh,C);
  const int shw=sh*sh;
  const float* srcb=src+(size_t)b*C*shw;
  const int cpc=(f==0)?3:(512/nchunk);
  const int c_begin=chunk*cpc;
  const int c_end=(c_begin+cpc<C)?(c_begin+cpc):C;

  if(tid<48){
    float sy=(float)sh/48.0f;
    float ys=fmaxf(((float)tid+0.5f)*sy-0.5f,0.0f);
    int y0=(int)ys; if(y0>sh-1) y0=sh-1;
    int y1=y0+1; if(y1>sh-1) y1=sh-1;
    y0t[tid]=y0; y1t[tid]=y1; wyt[tid]=ys-(float)y0;
  }

  double accH[NPN], accV[NPN];
  #pragma unroll
  for(int j=0;j<NPN;j++){ accH[j]=0.0; accV[j]=0.0; }

  for(int c0=c_begin;c0<c_end;c0+=4){
    const int nc=(c_end-c0<4)?(c_end-c0):4;
    __syncthreads();               // protect previous sub-stage reads (and table init)
    for(int i=tid;i<NN;i+=TPE){
      int r=i/WW, c=i-r*WW;
      int y0=y0t[r], y1=y1t[r]; float wy=wyt[r];
      int x0=y0t[c], x1=y1t[c]; float wx=wyt[c];
      float w00=(1.0f-wy)*(1.0f-wx), w01=(1.0f-wy)*wx;
      float w10=wy*(1.0f-wx),        w11=wy*wx;
      int o00=y0*sh+x0, o01=y0*sh+x1, o10=y1*sh+x0, o11=y1*sh+x1;
      const float* pl=srcb+(size_t)c0*shw;
      for(int cc=0;cc<nc;cc++){
        const float* p=pl+(size_t)cc*shw;
        up[cc*NN+i]=w00*p[o00]+w01*p[o01]+w10*p[o10]+w11*p[o11];
      }
    }
    __syncthreads();
    #pragma unroll
    for(int j=0;j<NPN;j++){
      int u=tid+j*TPE;
      if(u<NN){
        int r=u/WW, c=u-r*WW;
        bool hOK=(c<WW-1), vOK=(r<HH-1);
        for(int cc=0;cc<nc;cc++){
          const float* pu=up+cc*NN+u;
          float a=pu[0], b1=pu[1], c1=pu[WW];
          if(hOK){ double d=(double)a-(double)b1; accH[j]=fma(d,d,accH[j]); }
          if(vOK){ double d=(double)a-(double)c1; accV[j]=fma(d,d,accV[j]); }
        }
      }
    }
  }
  double* outp=(f==0)? pd_low+(size_t)pidx*EEE
                     : pd_hf+((size_t)hfidx*nchunk+chunk)*EEE;
  #pragma unroll
  for(int j=0;j<NPN;j++){
    int u=tid+j*TPE;
    if(u<NN){
      int r=u/WW, c=u-r*WW;
      if(c<WW-1) outp[r*(WW-1)+c]=accH[j];
      if(r<HH-1) outp[EHH+u]=accV[j];
    }
  }
}

// ---------------------------------------------------------------------------
// Parallel fixed-order chunk reduction: dkeyG[pidx][e].
__global__ __launch_bounds__(TPB) void k_redux(
  const double* __restrict__ pd_low, const double* __restrict__ pd_hf,
  int nchunk, double* __restrict__ dkeyG)
{
  int t=blockIdx.x*TPB+threadIdx.x;
  if(t>=32*EEE) return;
  int pidx=t/EEE, e=t-pidx*EEE;
  double s;
  if(pidx<8) s=pd_low[(size_t)pidx*EEE+e];
  else {
    const double* p0=pd_hf+((size_t)(pidx-8)*nchunk)*EEE+e;
    s=0.0;
    for(int k=0;k<nchunk;k++) s+=p0[(size_t)k*EEE];
  }
  dkeyG[t]=s;
}

// ---------------------------------------------------------------------------
// FUSED structure kernel: Boruvka MST -> Euler-tour rooting (Wyllie) ->
// pointer-doubling level tables.  One 1024-thread block per (forest,batch).
// Single LDS arena with phase-aliased regions (see offsets).
__global__ __launch_bounds__(TPW) void k_struct(
  const double* __restrict__ dkeyG, int* __restrict__ sbase,
  int* __restrict__ ancT, float* __restrict__ prodT)
{
  __shared__ __align__(16) char smem[123600];
  // phase A (Boruvka):
  double*             dkey =(double*)(smem+0);                 // [0,36096)
  unsigned char*      mstf =(unsigned char*)(smem+36096);      // [36096,40608)
  unsigned long long* bestd=(unsigned long long*)(smem+40608); // [40608,59040)
  int*                comp =(int*)(smem+59040);                // [59040,68256)
  int*                beste=(int*)(smem+68256);                // [68256,77472)
  int*                lnk  =(int*)(smem+77472);                // [77472,86688)
  // transition (over dead bestd/comp/beste and lnk):
  float4*             adjw =(float4*)(smem+40608);             // [40608,77472)
  unsigned char*      adjS =(unsigned char*)(smem+77472);      // [77472,79776)
  int*                chunkS=(int*)(smem+79776);               // [79776,83872)
  // phase B (root; over dead dkey/mstf):
  unsigned int*       eA   =(unsigned int*)(smem+0);           // [0,36864)
  unsigned int*       eB   =(unsigned int*)(smem+86688);       // [86688,123552)
  int*                flags=(int*)(smem+123552);               // [123552,123568)
  // phase C (tables; over dead pos buffers):
  int*                ancA =(int*)(smem+0);
  float*              prmA =(float*)(smem+9216);
  int*                ancB =(int*)(smem+18432);
  float*              prmB =(float*)(smem+27648);

  const int tid=threadIdx.x;
  const int pidx=blockIdx.x;
  const int f=pidx>>3;
  const float sigma=(f==0)?0.02f:1.0f;

  // ================= phase A: Boruvka =================
  {
    const double* p0=dkeyG+(size_t)pidx*EEE;
    for(int e=tid;e<EEE;e+=TPW) dkey[e]=p0[e];
    for(int i=tid;i<NN;i+=TPW) comp[i]=i;
    for(int e=tid;e<EEE;e+=TPW) mstf[e]=0;
    __syncthreads();

    for(int round=0;round<20;++round){
      for(int i=tid;i<NN;i+=TPW){ bestd[i]=~0ull; beste[i]=0x7fffffff; lnk[i]=i; }
      if(tid==0) flags[1]=0;
      __syncthreads();
      for(int e=tid;e<EEE;e+=TPW){
        int u,v; edge_uv(e,u,v);
        int cu=comp[u], cv=comp[v];
        if(cu!=cv){
          unsigned long long db=(unsigned long long)__double_as_longlong(dkey[e]);
          atomicMin(&bestd[cu],db);
          atomicMin(&bestd[cv],db);
        }
      }
      __syncthreads();
      for(int e=tid;e<EEE;e+=TPW){
        int u,v; edge_uv(e,u,v);
        int cu=comp[u], cv=comp[v];
        if(cu!=cv){
          unsigned long long db=(unsigned long long)__double_as_longlong(dkey[e]);
          if(db==bestd[cu]) atomicMin(&beste[cu],e);
          if(db==bestd[cv]) atomicMin(&beste[cv],e);
        }
      }
      __syncthreads();
      // hook (mutual pair resolved toward smaller id; mutual => SAME edge, order strict)
      for(int i=tid;i<NN;i+=TPW){
        if(comp[i]==i && beste[i]!=0x7fffffff){
          int e=beste[i]; int u,v; edge_uv(e,u,v);
          int cu=comp[u], cv=comp[v];
          int other=(cu==i)?cv:cu;
          bool mutual=(beste[other]==e);
          if(!mutual || other<i){ lnk[i]=other; mstf[e]=1; flags[1]=1; }
        }
      }
      __syncthreads();
      if(flags[1]==0) break;
      // lock-free path-halving find
      {
        volatile int* vl=lnk;
        for(int i=tid;i<NN;i+=TPW){
          int x=comp[i];
          int p=vl[x];
          int gp=vl[p];
          while(p!=gp){
            vl[x]=gp;
            x=p; p=gp; gp=vl[p];
          }
          comp[i]=p;
        }
      }
      __syncthreads();
    }
    __syncthreads();

    // ---- transition: adjS (mask) + adjw (weights) from mstf + dkey ----
    for(int i=tid;i<NN;i+=TPW){
      int r=i/WW, c=i-r*WW;
      int mask=0; float4 w; w.x=0.0f; w.y=0.0f; w.z=0.0f; w.w=0.0f;
      if(c>0    && mstf[r*(WW-1)+c-1]){ mask|=1; w.x=expf(-(float)dkey[r*(WW-1)+c-1]/sigma); }
      if(c<WW-1 && mstf[r*(WW-1)+c])  { mask|=2; w.y=expf(-(float)dkey[r*(WW-1)+c]/sigma); }
      if(r>0    && mstf[EHH+i-WW])    { mask|=4; w.z=expf(-(float)dkey[EHH+i-WW]/sigma); }
      if(r<HH-1 && mstf[EHH+i])       { mask|=8; w.w=expf(-(float)dkey[EHH+i]/sigma); }
      adjw[i]=w;
      adjS[i]=(unsigned char)mask;
    }
    if(tid==0) flags[2]=0;   // maxdepth accumulator
    __syncthreads();
  }

  // ================= phase B: Euler-tour rooting =================
  {
    const int m0=adjS[0];
    const int d0=(m0&1)?0:((m0&2)?1:((m0&4)?2:3));
    const int e0=d0;   // node 0 * 4 + d0

    for(int t=tid;t<ESLOT;t+=TPW){
      int u=t>>2, d=t&3;
      unsigned int pk=0;
      if(adjS[u]&(1<<d)){
        int v=(d==0)?u-1:(d==1)?u+1:(d==2)?u-WW:u+WW;
        int rd=d^1;
        int mv=adjS[v];
        int nd=rd;
        #pragma unroll
        for(int k2=4;k2>=1;k2--){ int dd=(rd+k2)&3; if(mv&(1<<dd)) nd=dd; }
        int ne=(v<<2)|nd;
        unsigned int nxt=(ne==e0)?SENTN:(unsigned int)ne;
        pk=(nxt<<16)|1u;
      }
      eA[t]=pk;
    }
    __syncthreads();

    unsigned int* P=eA; unsigned int* Q=eB;
    for(int r2=0;r2<13;r2++){
      for(int t=tid;t<ESLOT;t+=TPW){
        unsigned int pk=P[t];
        unsigned int dist=pk&0xFFFFu, nxt=pk>>16;
        if(dist && nxt!=SENTN){
          unsigned int pk2=P[nxt];
          dist+=pk2&0xFFFFu;
          nxt=pk2>>16;
          pk=(nxt<<16)|dist;
        }
        Q[t]=pk;
      }
      __syncthreads();
      unsigned int* tmp=P; P=Q; Q=tmp;
    }
    for(int t=tid;t<ESLOT;t+=TPW){
      unsigned int dist=P[t]&0xFFFFu;
      Q[t]=dist?(unsigned int)(LVE-(int)dist):0xFFFFFFFFu;
    }
    __syncthreads();

    int* scanA=(int*)P;
    for(int t=tid;t<ESLOT;t+=TPW){
      unsigned int pos=Q[t];
      if(pos!=0xFFFFFFFFu){
        int u=t>>2, d=t&3;
        int v=(d==0)?u-1:(d==1)?u+1:(d==2)?u-WW:u+WW;
        unsigned int rpos=Q[(v<<2)|(d^1)];
        scanA[pos]=(pos<rpos)?1:-1;
      }
    }
    __syncthreads();

    const int base=tid*RIPT;
    int vals[RIPT]; int lsum=0;
    #pragma unroll
    for(int j=0;j<RIPT;j++){
      int p=base+j;
      int v=(p<LVE)?scanA[p]:0;
      lsum+=v; vals[j]=lsum;
    }
    chunkS[tid]=lsum;
    __syncthreads();
    for(int off=1;off<TPW;off<<=1){
      int v=chunkS[tid];
      int vv=(tid>=off)?chunkS[tid-off]:0;
      __syncthreads();
      chunkS[tid]=v+vv;
      __syncthreads();
    }
    const int myoff=(tid>0)?chunkS[tid-1]:0;
    int mymax=0;
    #pragma unroll
    for(int j=0;j<RIPT;j++){
      int p=base+j;
      if(p<LVE){ int s=vals[j]+myoff; scanA[p]=s; if(s>mymax) mymax=s; }
    }
    if(mymax>0) atomicMax(&flags[2],mymax);
    __syncthreads();

    int* sp=sbase+(size_t)pidx*SSTRIDE_W;
    int4* g_pk=(int4*)(sp+PK_OFF);
    if(tid==0){
      g_pk[0]=make_int4(0,__float_as_int(0.0f),0,0);
      sp[D_OFF]=flags[2];
    }
    for(int t=tid;t<ESLOT;t+=TPW){
      unsigned int pos=Q[t];
      if(pos!=0xFFFFFFFFu){
        int u=t>>2, d=t&3;
        int v=(d==0)?u-1:(d==1)?u+1:(d==2)?u-WW:u+WW;
        unsigned int rpos=Q[(v<<2)|(d^1)];
        if(pos<rpos){                       // down edge: u = parent(v)
          float4 w4=adjw[u];
          float w=(d==0)?w4.x:(d==1)?w4.y:(d==2)?w4.z:w4.w;
          g_pk[v]=make_int4(u,__float_as_int(w),scanA[pos],0);
        }
      }
    }
    __syncthreads();   // g_pk visible to whole block (global, same-block sync)
  }

  // ================= phase C: level tables =================
  {
    const int* sp=sbase+(size_t)pidx*SSTRIDE_W;
    const int4* g_pk=(const int4*)(sp+PK_OFF);
    const int maxD=flags[2];
    int T=1; while((1<<T)<=maxD) T++;
    int* gA=ancT+(size_t)pidx*MAXT*NN;
    float* gP=prodT+(size_t)pidx*MAXT*NN;
    int* aP=ancA; int* aQ=ancB; float* pP=prmA; float* pQ=prmB;
    for(int i=tid;i<NN;i+=TPW){
      int4 rec=g_pk[i];
      aP[i]=rec.x; pP[i]=__int_as_float(rec.y);
      gA[i]=rec.x; gP[i]=pP[i];
    }
    __syncthreads();
    for(int t=1;t<T;t++){
      for(int i=tid;i<NN;i+=TPW){
        int a=aP[i];
        int a2=aP[a]; float pr=pP[i]*pP[a];
        aQ[i]=a2; pQ[i]=pr;
        gA[(size_t)t*NN+i]=a2; gP[(size_t)t*NN+i]=pr;
      }
      __syncthreads();
      { int* t1=aP; aP=aQ; aQ=t1; float* t2=pP; pP=pQ; pQ=t2; }
    }
  }
}

// ---------------------------------------------------------------------------
// Value-only tree filter, ONE (problem, channel) per block.
__global__ __launch_bounds__(TPF) void k_fchan(
  const float* __restrict__ X, float* __restrict__ Fout,
  const int* __restrict__ sbase, const int* __restrict__ ancT,
  const float* __restrict__ prodT, int pidx0)
{
  __shared__ float S[NN];    // 9216 B
  __shared__ float Sb[NN];   // 9216 B
  const int tid=threadIdx.x;
  const int pg=blockIdx.x/5, c=blockIdx.x%5;
  const int pidx=pidx0+pg;
  const int xb=pg&7;
  const int* sp=sbase+(size_t)pidx*SSTRIDE_W;
  const int4* g_pk=(const int4*)(sp+PK_OFF);
  const int maxD=sp[D_OFF];
  int T=1; while((1<<T)<=maxD) T++;
  const int* ancP=ancT+(size_t)pidx*MAXT*NN;
  const float* prmP=prodT+(size_t)pidx*MAXT*NN;

  int dep[NPL]; float wv[NPL];
  #pragma unroll
  for(int j=0;j<NPL;j++){
    int i=tid+j*TPF;
    if(i<NN){
      int4 rec=g_pk[i];
      dep[j]=rec.z; wv[j]=__int_as_float(rec.y);
      S[i]=(c<4)? X[((size_t)xb*KK+c)*NN+i] : 1.0f;
    } else { dep[j]=-1; wv[j]=0.0f; }
  }
  __syncthreads();

  // ---- upward ----
  for(int t=0;t<T;t++){
    float sn[NPL]; int aj[NPL]; float pj[NPL];
    #pragma unroll
    for(int j=0;j<NPL;j++){
      int i=tid+j*TPF;
      if(i<NN){ sn[j]=S[i]; aj[j]=ancP[(size_t)t*NN+i]; pj[j]=prmP[(size_t)t*NN+i]; }
      else { sn[j]=0.0f; aj[j]=0; pj[j]=0.0f; }
    }
    __syncthreads();
    int bit=1<<t;
    #pragma unroll
    for(int j=0;j<NPL;j++){
      if(dep[j]>=bit) atomicAdd(&S[aj[j]], pj[j]*sn[j]);
    }
    __syncthreads();
  }

  // ---- downward init: b = (1-w^2)*A_up (root w=0 -> b=A_up) ----
  #pragma unroll
  for(int j=0;j<NPL;j++){
    int i=tid+j*TPF;
    if(i<NN){ float fq=1.0f-wv[j]*wv[j]; Sb[i]=fq*S[i]; }
  }
  __syncthreads();

  // ---- downward rounds (copy-free ping-pong) ----
  float* Sp=Sb; float* Sq=S;
  for(int t=0;t<T;t++){
    float bn[NPL];
    #pragma unroll
    for(int j=0;j<NPL;j++){
      int i=tid+j*TPF;
      if(i<NN){
        int a=ancP[(size_t)t*NN+i]; float ai=prmP[(size_t)t*NN+i];
        bn[j]=fmaf(ai,Sp[a],Sp[i]);
      } else bn[j]=0.0f;
    }
    __syncthreads();
    #pragma unroll
    for(int j=0;j<NPL;j++){
      int i=tid+j*TPF;
      if(i<NN) Sq[i]=bn[j];
    }
    __syncthreads();
    { float* tmp=Sp; Sp=Sq; Sq=tmp; }
  }
  // a == 0 for all nodes after T rounds (2^T > maxD) -> F = b
  float* o=Fout+(size_t)blockIdx.x*NN;
  for(int i=tid;i<NN;i+=TPF) o[i]=Sp[i];
}

// ---------------------------------------------------------------------------
__global__ __launch_bounds__(TPB) void k_div0(const float* __restrict__ FA,
                                              float* __restrict__ AS){
  int t=blockIdx.x*TPB+threadIdx.x;
  if(t>=BB*KK*NN) return;
  int b=t/(KK*NN), rem=t-b*(KK*NN), c=rem/NN, i=rem-c*NN;
  float inv=1.0f/FA[((size_t)b*5+4)*NN+i];
  AS[t]=FA[((size_t)b*5+c)*NN+i]*inv;
}

// ---------------------------------------------------------------------------
__global__ __launch_bounds__(TPB) void k_loss(
  const float* __restrict__ FB, const float* __restrict__ probf,
  const float* __restrict__ rois, float* __restrict__ partials)
{
  __shared__ float red[TPB];
  const int tid=threadIdx.x;
  const int fb=blockIdx.x;          // 0..23
  const int b=fb&7;
  const float* pb=probf+(size_t)b*KK*NN;
  float part=0.0f;
  for(int i=tid;i<NN;i+=TPB){
    int r=i/WW, c2=i-r*WW;
    float roi=rois[(size_t)b*(192*192)+(4*r)*192+(4*c2)];
    float inv=1.0f/FB[((size_t)fb*5+4)*NN+i];
    float s=fabsf(pb[i]      -FB[((size_t)fb*5+0)*NN+i]*inv)
          + fabsf(pb[NN+i]   -FB[((size_t)fb*5+1)*NN+i]*inv)
          + fabsf(pb[2*NN+i] -FB[((size_t)fb*5+2)*NN+i]*inv)
          + fabsf(pb[3*NN+i] -FB[((size_t)fb*5+3)*NN+i]*inv);
    part+=roi*s;
  }
  red[tid]=part; __syncthreads();
  for(int s2=TPB/2;s2>0;s2>>=1){ if(tid<s2) red[tid]+=red[tid+s2]; __syncthreads(); }
  if(tid==0) partials[fb]=red[0];
}

// ---------------------------------------------------------------------------
__global__ __launch_bounds__(TPB) void k_final(const float* __restrict__ rois,
    const float* __restrict__ partials, const float* __restrict__ wt,
    float* __restrict__ out)
{
  __shared__ float red[TPB];
  const int tid=threadIdx.x;
  float n=0.0f;
  for(int t=tid;t<BB*NN;t+=TPB){
    int b=t/NN, i=t-b*NN; int r=i/WW, c=i-r*WW;
    n += rois[(size_t)b*(192*192)+(4*r)*192+(4*c)];
  }
  red[tid]=n; __syncthreads();
  for(int s=TPB/2;s>0;s>>=1){ if(tid<s) red[tid]+=red[tid+s]; __syncthreads(); }
  if(tid==0){
    float loss=0.0f;
    for(int j=0;j<3*BB;j++) loss+=partials[j];
    float N=red[0];
    out[0]=wt[0]*((N>0.0f)?(loss/N):loss);
  }
}

// ---------------------------------------------------------------------------
extern "C" void kernel_launch(void* const* d_in, const int* in_sizes, int n_in,
                              void* d_out, int out_size, void* d_ws, size_t ws_size,
                              hipStream_t stream) {
  (void)in_sizes; (void)n_in; (void)out_size;
  const float* preds=(const float*)d_in[0];
  const float* lowf =(const float*)d_in[1];
  const float* hf1  =(const float*)d_in[2];
  const float* hf2  =(const float*)d_in[3];
  const float* hf3  =(const float*)d_in[4];
  const float* rois =(const float*)d_in[5];
  const float* wt   =(const float*)d_in[6];
  float* out=(float*)d_out;

  char* ws=(char*)d_ws;
  float* partials=(float*)ws;                                  // 24 floats @0
  float* probf=(float*)(ws+256);                               // 294,912 B
  float* AS   =(float*)(ws+256+(size_t)BB*KK*NN*4);            // 294,912 B
  size_t sb_off=256+(size_t)2*BB*KK*NN*4;                      // 590,080
  int*   sbase=(int*)(ws+sb_off);                              // 1,180,672 B
  size_t dk_off=sb_off+(size_t)32*SSTRIDE_W*4;                 // 1,770,752 (8-mult)
  double* dkeyG=(double*)(ws+dk_off);                          // 1,155,072 B
  size_t pl_off=dk_off+(size_t)32*EEE*8;                       // 2,925,824
  double* pd_low=(double*)(ws+pl_off);                         // 288,768 B
  size_t ph_off=pl_off+(size_t)8*EEE*8;                        // 3,214,592
  double* pd_hf=(double*)(ws+ph_off);                          // 24*nchunk*EEE*8

  // table/F buffers ALIAS pd_hf (dead after k_redux); 8.56 MB <= 13.86 MB floor.
  int*   ancT =(int*)  (ws+ph_off);                            // 3,538,944 B
  float* prodT=(float*)(ws+ph_off+(size_t)32*MAXT*NN*4);       // 3,538,944 B
  float* FA   =(float*)(ws+ph_off+(size_t)2*32*MAXT*NN*4);     // 40*NN*4
  float* FB   =(float*)(ws+ph_off+(size_t)2*32*MAXT*NN*4+(size_t)40*NN*4); // 120*NN*4

  int nchunk=32;
  if(ph_off+(size_t)24*32*EEE*8>ws_size) nchunk=16;

  k_prob<<<(BB*NN+TPB-1)/TPB,TPB,0,stream>>>(preds,probf);
  k_edges<<<8+24*nchunk,TPE,0,stream>>>(lowf,hf1,hf2,hf3,pd_low,pd_hf,nchunk);
  k_redux<<<(32*EEE+TPB-1)/TPB,TPB,0,stream>>>(pd_low,pd_hf,nchunk,dkeyG);
  k_struct<<<32,TPW,0,stream>>>(dkeyG,sbase,ancT,prodT);
  k_fchan<<<40,TPF,0,stream>>>(probf,FA,sbase,ancT,prodT,0);
  k_div0<<<(BB*KK*NN+TPB-1)/TPB,TPB,0,stream>>>(FA,AS);
  k_fchan<<<120,TPF,0,stream>>>(AS,FB,sbase,ancT,prodT,8);
  k_loss<<<3*BB,TPB,0,stream>>>(FB,probf,rois,partials);
  k_final<<<1,TPB,0,stream>>>(rois,partials,wt,out);
}

// Round 14
// 221.443 us; speedup vs baseline: 3.2860x; 1.0249x over previous
//
#include <hip/hip_runtime.h>
#include <math.h>

// ---------------------------------------------------------------------------
// TreeEnergyLoss on MI355X.
// k_edges (softmax blocks merged in; chunked f64 edge distances via
// LDS-upsampled embeddings; node-centric shared-read edge loops) -> k_redux
// (parallel fixed-order chunk sum -> dkeyG) -> k_struct (FUSED: 1024t Boruvka
// MST under strict (dist,edge-idx) order == reference's stable Kruskal +
// Euler-tour rooting via Wyllie + pointer-doubling level tables; barrier-diet:
// 4-barrier Boruvka rounds, 2-barrier shfl scan) -> k_fchan (one block per
// (problem,channel) value-only doubling passes) -> k_div0 / k_loss / k_final.
// ---------------------------------------------------------------------------

#define HH 48
#define WW 48
#define NN (HH*WW)          // 2304 nodes
#define EHH (HH*(WW-1))     // 2256 horizontal edges
#define EEE (2*EHH)         // 4512 edges
#define BB 8
#define KK 4
#define TPB 256
#define TPE 512             // edges kernel
#define TPW 1024            // struct kernel
#define TPF 512             // fchan kernel
#define NPL 5               // nodes per lane in fchan (ceil 2304/512)
#define NPN 5               // nodes per thread in k_edges (ceil 2304/512)
#define ESLOT (4*NN)        // 9216 directed-edge slots
#define LVE (2*(NN-1))      // 4606 valid directed edges
#define RIPT ((LVE+TPW-1)/TPW)  // 5 scan items per thread
#define SENTN 0xFFFFu
#define MAXT 12             // 2^12 = 4096 > max possible depth (2303)

// per-problem structure record in ws (ints): node-indexed int4 (parent,w,depth,0) | maxdepth
#define SSTRIDE_W (4*NN+8)
#define PK_OFF 0
#define D_OFF (4*NN)

__device__ __forceinline__ void edge_uv(int e,int& u,int& v){
  if(e<EHH){ int r=e/(WW-1); int c=e-r*(WW-1); u=r*WW+c; v=u+1; }
  else     { int t=e-EHH; u=t; v=t+WW; }
}

__device__ __forceinline__ void pick_src(int f, const float* lowf, const float* hf1,
                                         const float* hf2, const float* hf3,
                                         const float*& src, int& sh, int& C){
  if(f==0){src=lowf; sh=192; C=3;}
  else if(f==1){src=hf1; sh=24; C=512;}
  else if(f==2){src=hf2; sh=12; C=512;}
  else        {src=hf3; sh=6;  C=512;}
}

// ---------------------------------------------------------------------------
// Edge-distance partials, with softmax blocks appended at the end of the grid.
// One block = (problem, channel-chunk); blocks >= nEB do the softmax.
__global__ __launch_bounds__(TPE) void k_edges(
  const float* __restrict__ lowf, const float* __restrict__ hf1,
  const float* __restrict__ hf2, const float* __restrict__ hf3,
  const float* __restrict__ preds, float* __restrict__ probf,
  double* __restrict__ pd_low, double* __restrict__ pd_hf, int nchunk)
{
  __shared__ float up[4*NN+64];   // 37120 B (pad: guarded-unused over-reads)
  __shared__ int   y0t[48], y1t[48];
  __shared__ float wyt[48];
  const int tid=threadIdx.x;
  const int nEB=8+24*nchunk;

  if(blockIdx.x>=nEB){            // ---- softmax blocks ----
    int t=(blockIdx.x-nEB)*TPE+tid;
    if(t<BB*NN){
      int b=t/NN, i=t-b*NN;
      const float* p=preds+(size_t)b*KK*NN+i;
      float x0=p[0],x1=p[NN],x2=p[2*NN],x3=p[3*NN];
      float mx=fmaxf(fmaxf(x0,x1),fmaxf(x2,x3));
      float e0=expf(x0-mx),e1=expf(x1-mx),e2=expf(x2-mx),e3=expf(x3-mx);
      float s=((e0+e1)+(e2+e3));
      float* q=probf+(size_t)b*KK*NN+i;
      q[0]=e0/s; q[NN]=e1/s; q[2*NN]=e2/s; q[3*NN]=e3/s;
    }
    return;
  }

  int pidx, chunk, hfidx=0;
  if(blockIdx.x<8){ pidx=blockIdx.x; chunk=0; }
  else { int t=blockIdx.x-8; hfidx=t/nchunk; chunk=t-hfidx*nchunk; pidx=8+hfidx; }
  const int f=pidx>>3, b=pidx&7;
  const float* src; int sh,C;
  pick_src(f,lowf,hf1,hf2,hf3,src,sh,C);
  const int shw=sh*sh;
  const float* srcb=src+(size_t)b*C*shw;
  const int cpc=(f==0)?3:(512/nchunk);
  const int c_begin=chunk*cpc;
  const int c_end=(c_begin+cpc<C)?(c_begin+cpc):C;

  if(tid<48){
    float sy=(float)sh/48.0f;
    float ys=fmaxf(((float)tid+0.5f)*sy-0.5f,0.0f);
    int y0=(int)ys; if(y0>sh-1) y0=sh-1;
    int y1=y0+1; if(y1>sh-1) y1=sh-1;
    y0t[tid]=y0; y1t[tid]=y1; wyt[tid]=ys-(float)y0;
  }

  double accH[NPN], accV[NPN];
  #pragma unroll
  for(int j=0;j<NPN;j++){ accH[j]=0.0; accV[j]=0.0; }

  for(int c0=c_begin;c0<c_end;c0+=4){
    const int nc=(c_end-c0<4)?(c_end-c0):4;
    __syncthreads();               // protect previous sub-stage reads (and table init)
    for(int i=tid;i<NN;i+=TPE){
      int r=i/WW, c=i-r*WW;
      int y0=y0t[r], y1=y1t[r]; float wy=wyt[r];
      int x0=y0t[c], x1=y1t[c]; float wx=wyt[c];
      float w00=(1.0f-wy)*(1.0f-wx), w01=(1.0f-wy)*wx;
      float w10=wy*(1.0f-wx),        w11=wy*wx;
      int o00=y0*sh+x0, o01=y0*sh+x1, o10=y1*sh+x0, o11=y1*sh+x1;
      const float* pl=srcb+(size_t)c0*shw;
      for(int cc=0;cc<nc;cc++){
        const float* p=pl+(size_t)cc*shw;
        up[cc*NN+i]=w00*p[o00]+w01*p[o01]+w10*p[o10]+w11*p[o11];
      }
    }
    __syncthreads();
    #pragma unroll
    for(int j=0;j<NPN;j++){
      int u=tid+j*TPE;
      if(u<NN){
        int r=u/WW, c=u-r*WW;
        bool hOK=(c<WW-1), vOK=(r<HH-1);
        for(int cc=0;cc<nc;cc++){
          const float* pu=up+cc*NN+u;
          float a=pu[0], b1=pu[1], c1=pu[WW];
          if(hOK){ double d=(double)a-(double)b1; accH[j]=fma(d,d,accH[j]); }
          if(vOK){ double d=(double)a-(double)c1; accV[j]=fma(d,d,accV[j]); }
        }
      }
    }
  }
  double* outp=(f==0)? pd_low+(size_t)pidx*EEE
                     : pd_hf+((size_t)hfidx*nchunk+chunk)*EEE;
  #pragma unroll
  for(int j=0;j<NPN;j++){
    int u=tid+j*TPE;
    if(u<NN){
      int r=u/WW, c=u-r*WW;
      if(c<WW-1) outp[r*(WW-1)+c]=accH[j];
      if(r<HH-1) outp[EHH+u]=accV[j];
    }
  }
}

// ---------------------------------------------------------------------------
// Parallel fixed-order chunk reduction: dkeyG[pidx][e].
__global__ __launch_bounds__(TPB) void k_redux(
  const double* __restrict__ pd_low, const double* __restrict__ pd_hf,
  int nchunk, double* __restrict__ dkeyG)
{
  int t=blockIdx.x*TPB+threadIdx.x;
  if(t>=32*EEE) return;
  int pidx=t/EEE, e=t-pidx*EEE;
  double s;
  if(pidx<8) s=pd_low[(size_t)pidx*EEE+e];
  else {
    const double* p0=pd_hf+((size_t)(pidx-8)*nchunk)*EEE+e;
    s=0.0;
    for(int k=0;k<nchunk;k++) s+=p0[(size_t)k*EEE];
  }
  dkeyG[t]=s;
}

// ---------------------------------------------------------------------------
// FUSED structure kernel: Boruvka MST -> Euler-tour rooting (Wyllie) ->
// pointer-doubling level tables.  One 1024-thread block per (forest,batch).
// Barrier diet: 4 barriers/Boruvka round (init folded into sweeps), 2-barrier
// shfl-based scan.
__global__ __launch_bounds__(TPW) void k_struct(
  const double* __restrict__ dkeyG, int* __restrict__ sbase,
  int* __restrict__ ancT, float* __restrict__ prodT)
{
  __shared__ __align__(16) char smem[123600];
  // phase A (Boruvka):
  double*             dkey =(double*)(smem+0);                 // [0,36096)
  unsigned char*      mstf =(unsigned char*)(smem+36096);      // [36096,40608)
  unsigned long long* bestd=(unsigned long long*)(smem+40608); // [40608,59040)
  int*                comp =(int*)(smem+59040);                // [59040,68256)
  int*                beste=(int*)(smem+68256);                // [68256,77472)
  int*                lnk  =(int*)(smem+77472);                // [77472,86688)
  // transition (over dead bestd/comp/beste and lnk):
  float4*             adjw =(float4*)(smem+40608);             // [40608,77472)
  unsigned char*      adjS =(unsigned char*)(smem+77472);      // [77472,79776)
  int*                chunkS=(int*)(smem+79776);               // [79776,83872)
  // phase B (root; over dead dkey/mstf):
  unsigned int*       eA   =(unsigned int*)(smem+0);           // [0,36864)
  unsigned int*       eB   =(unsigned int*)(smem+86688);       // [86688,123552)
  int*                flags=(int*)(smem+123552);               // [123552,123568)
  // phase C (tables; over dead pos buffers):
  int*                ancA =(int*)(smem+0);
  float*              prmA =(float*)(smem+9216);
  int*                ancB =(int*)(smem+18432);
  float*              prmB =(float*)(smem+27648);

  const int tid=threadIdx.x;
  const int pidx=blockIdx.x;
  const int f=pidx>>3;
  const float sigma=(f==0)?0.02f:1.0f;

  // ================= phase A: Boruvka =================
  {
    const double* p0=dkeyG+(size_t)pidx*EEE;
    for(int e=tid;e<EEE;e+=TPW) dkey[e]=p0[e];
    for(int i=tid;i<NN;i+=TPW) comp[i]=i;
    for(int e=tid;e<EEE;e+=TPW) mstf[e]=0;
    // pre-loop init (round 0)
    for(int i=tid;i<NN;i+=TPW){ bestd[i]=~0ull; beste[i]=0x7fffffff; lnk[i]=i; }
    if(tid==0) flags[1]=0;
    __syncthreads();

    for(int round=0;round<20;++round){
      // sweep1 (+ lnk re-init; safe: lnk untouched until hook, 2 barriers away)
      for(int i=tid;i<NN;i+=TPW) lnk[i]=i;
      for(int e=tid;e<EEE;e+=TPW){
        int u,v; edge_uv(e,u,v);
        int cu=comp[u], cv=comp[v];
        if(cu!=cv){
          unsigned long long db=(unsigned long long)__double_as_longlong(dkey[e]);
          atomicMin(&bestd[cu],db);
          atomicMin(&bestd[cv],db);
        }
      }
      __syncthreads();
      for(int e=tid;e<EEE;e+=TPW){
        int u,v; edge_uv(e,u,v);
        int cu=comp[u], cv=comp[v];
        if(cu!=cv){
          unsigned long long db=(unsigned long long)__double_as_longlong(dkey[e]);
          if(db==bestd[cu]) atomicMin(&beste[cu],e);
          if(db==bestd[cv]) atomicMin(&beste[cv],e);
        }
      }
      __syncthreads();
      // hook (mutual pair resolved toward smaller id; mutual => SAME edge, order strict)
      for(int i=tid;i<NN;i+=TPW){
        if(comp[i]==i && beste[i]!=0x7fffffff){
          int e=beste[i]; int u,v; edge_uv(e,u,v);
          int cu=comp[u], cv=comp[v];
          int other=(cu==i)?cv:cu;
          bool mutual=(beste[other]==e);
          if(!mutual || other<i){ lnk[i]=other; mstf[e]=1; flags[1]=1; }
        }
      }
      __syncthreads();
      if(flags[1]==0) break;
      // find (lock-free path-halving) + next-round init (disjoint arrays)
      {
        volatile int* vl=lnk;
        for(int i=tid;i<NN;i+=TPW){
          int x=comp[i];
          int p=vl[x];
          int gp=vl[p];
          while(p!=gp){
            vl[x]=gp;
            x=p; p=gp; gp=vl[p];
          }
          comp[i]=p;
        }
      }
      for(int i=tid;i<NN;i+=TPW){ bestd[i]=~0ull; beste[i]=0x7fffffff; }
      if(tid==0) flags[1]=0;
      __syncthreads();
    }
    __syncthreads();

    // ---- transition: adjS (mask) + adjw (weights) from mstf + dkey ----
    for(int i=tid;i<NN;i+=TPW){
      int r=i/WW, c=i-r*WW;
      int mask=0; float4 w; w.x=0.0f; w.y=0.0f; w.z=0.0f; w.w=0.0f;
      if(c>0    && mstf[r*(WW-1)+c-1]){ mask|=1; w.x=expf(-(float)dkey[r*(WW-1)+c-1]/sigma); }
      if(c<WW-1 && mstf[r*(WW-1)+c])  { mask|=2; w.y=expf(-(float)dkey[r*(WW-1)+c]/sigma); }
      if(r>0    && mstf[EHH+i-WW])    { mask|=4; w.z=expf(-(float)dkey[EHH+i-WW]/sigma); }
      if(r<HH-1 && mstf[EHH+i])       { mask|=8; w.w=expf(-(float)dkey[EHH+i]/sigma); }
      adjw[i]=w;
      adjS[i]=(unsigned char)mask;
    }
    if(tid==0) flags[2]=0;   // maxdepth accumulator
    __syncthreads();
  }

  // ================= phase B: Euler-tour rooting =================
  {
    const int m0=adjS[0];
    const int d0=(m0&1)?0:((m0&2)?1:((m0&4)?2:3));
    const int e0=d0;   // node 0 * 4 + d0

    for(int t=tid;t<ESLOT;t+=TPW){
      int u=t>>2, d=t&3;
      unsigned int pk=0;
      if(adjS[u]&(1<<d)){
        int v=(d==0)?u-1:(d==1)?u+1:(d==2)?u-WW:u+WW;
        int rd=d^1;
        int mv=adjS[v];
        int nd=rd;
        #pragma unroll
        for(int k2=4;k2>=1;k2--){ int dd=(rd+k2)&3; if(mv&(1<<dd)) nd=dd; }
        int ne=(v<<2)|nd;
        unsigned int nxt=(ne==e0)?SENTN:(unsigned int)ne;
        pk=(nxt<<16)|1u;
      }
      eA[t]=pk;
    }
    __syncthreads();

    unsigned int* P=eA; unsigned int* Q=eB;
    for(int r2=0;r2<13;r2++){
      for(int t=tid;t<ESLOT;t+=TPW){
        unsigned int pk=P[t];
        unsigned int dist=pk&0xFFFFu, nxt=pk>>16;
        if(dist && nxt!=SENTN){
          unsigned int pk2=P[nxt];
          dist+=pk2&0xFFFFu;
          nxt=pk2>>16;
          pk=(nxt<<16)|dist;
        }
        Q[t]=pk;
      }
      __syncthreads();
      unsigned int* tmp=P; P=Q; Q=tmp;
    }
    for(int t=tid;t<ESLOT;t+=TPW){
      unsigned int dist=P[t]&0xFFFFu;
      Q[t]=dist?(unsigned int)(LVE-(int)dist):0xFFFFFFFFu;
    }
    __syncthreads();

    int* scanA=(int*)P;
    for(int t=tid;t<ESLOT;t+=TPW){
      unsigned int pos=Q[t];
      if(pos!=0xFFFFFFFFu){
        int u=t>>2, d=t&3;
        int v=(d==0)?u-1:(d==1)?u+1:(d==2)?u-WW:u+WW;
        unsigned int rpos=Q[(v<<2)|(d^1)];
        scanA[pos]=(pos<rpos)?1:-1;
      }
    }
    __syncthreads();

    // ---- blocked inclusive scan (wave-shfl; 2 barriers) ----
    const int base=tid*RIPT;
    int vals[RIPT]; int lsum=0;
    #pragma unroll
    for(int j=0;j<RIPT;j++){
      int p=base+j;
      int v=(p<LVE)?scanA[p]:0;
      lsum+=v; vals[j]=lsum;
    }
    const int lane=tid&63, wid=tid>>6;   // 16 waves
    int x=lsum;
    #pragma unroll
    for(int off=1;off<64;off<<=1){
      int y=__shfl_up(x,off,64);
      if(lane>=off) x+=y;
    }
    if(lane==63) chunkS[wid]=x;          // wave totals
    __syncthreads();
    if(wid==0 && lane<16){
      int w=chunkS[lane];
      #pragma unroll
      for(int off=1;off<16;off<<=1){
        int y=__shfl_up(w,off,64);
        if(lane>=off) w+=y;
      }
      chunkS[lane]=w;
    }
    __syncthreads();
    const int waveoff=(wid>0)?chunkS[wid-1]:0;
    const int myoff=x+waveoff-lsum;      // == sum of lsum for tid' < tid
    int mymax=0;
    #pragma unroll
    for(int j=0;j<RIPT;j++){
      int p=base+j;
      if(p<LVE){ int s=vals[j]+myoff; scanA[p]=s; if(s>mymax) mymax=s; }
    }
    if(mymax>0) atomicMax(&flags[2],mymax);
    __syncthreads();

    int* sp=sbase+(size_t)pidx*SSTRIDE_W;
    int4* g_pk=(int4*)(sp+PK_OFF);
    if(tid==0){
      g_pk[0]=make_int4(0,__float_as_int(0.0f),0,0);
      sp[D_OFF]=flags[2];
    }
    for(int t=tid;t<ESLOT;t+=TPW){
      unsigned int pos=Q[t];
      if(pos!=0xFFFFFFFFu){
        int u=t>>2, d=t&3;
        int v=(d==0)?u-1:(d==1)?u+1:(d==2)?u-WW:u+WW;
        unsigned int rpos=Q[(v<<2)|(d^1)];
        if(pos<rpos){                       // down edge: u = parent(v)
          float4 w4=adjw[u];
          float w=(d==0)?w4.x:(d==1)?w4.y:(d==2)?w4.z:w4.w;
          g_pk[v]=make_int4(u,__float_as_int(w),scanA[pos],0);
        }
      }
    }
    __syncthreads();   // g_pk visible to whole block (global, same-block sync)
  }

  // ================= phase C: level tables =================
  {
    const int* sp=sbase+(size_t)pidx*SSTRIDE_W;
    const int4* g_pk=(const int4*)(sp+PK_OFF);
    const int maxD=flags[2];
    int T=1; while((1<<T)<=maxD) T++;
    int* gA=ancT+(size_t)pidx*MAXT*NN;
    float* gP=prodT+(size_t)pidx*MAXT*NN;
    int* aP=ancA; int* aQ=ancB; float* pP=prmA; float* pQ=prmB;
    for(int i=tid;i<NN;i+=TPW){
      int4 rec=g_pk[i];
      aP[i]=rec.x; pP[i]=__int_as_float(rec.y);
      gA[i]=rec.x; gP[i]=pP[i];
    }
    __syncthreads();
    for(int t=1;t<T;t++){
      for(int i=tid;i<NN;i+=TPW){
        int a=aP[i];
        int a2=aP[a]; float pr=pP[i]*pP[a];
        aQ[i]=a2; pQ[i]=pr;
        gA[(size_t)t*NN+i]=a2; gP[(size_t)t*NN+i]=pr;
      }
      __syncthreads();
      { int* t1=aP; aP=aQ; aQ=t1; float* t2=pP; pP=pQ; pQ=t2; }
    }
  }
}

// ---------------------------------------------------------------------------
// Value-only tree filter, ONE (problem, channel) per block.
__global__ __launch_bounds__(TPF) void k_fchan(
  const float* __restrict__ X, float* __restrict__ Fout,
  const int* __restrict__ sbase, const int* __restrict__ ancT,
  const float* __restrict__ prodT, int pidx0)
{
  __shared__ float S[NN];    // 9216 B
  __shared__ float Sb[NN];   // 9216 B
  const int tid=threadIdx.x;
  const int pg=blockIdx.x/5, c=blockIdx.x%5;
  const int pidx=pidx0+pg;
  const int xb=pg&7;
  const int* sp=sbase+(size_t)pidx*SSTRIDE_W;
  const int4* g_pk=(const int4*)(sp+PK_OFF);
  const int maxD=sp[D_OFF];
  int T=1; while((1<<T)<=maxD) T++;
  const int* ancP=ancT+(size_t)pidx*MAXT*NN;
  const float* prmP=prodT+(size_t)pidx*MAXT*NN;

  int dep[NPL]; float wv[NPL];
  #pragma unroll
  for(int j=0;j<NPL;j++){
    int i=tid+j*TPF;
    if(i<NN){
      int4 rec=g_pk[i];
      dep[j]=rec.z; wv[j]=__int_as_float(rec.y);
      S[i]=(c<4)? X[((size_t)xb*KK+c)*NN+i] : 1.0f;
    } else { dep[j]=-1; wv[j]=0.0f; }
  }
  __syncthreads();

  // ---- upward ----
  for(int t=0;t<T;t++){
    float sn[NPL]; int aj[NPL]; float pj[NPL];
    #pragma unroll
    for(int j=0;j<NPL;j++){
      int i=tid+j*TPF;
      if(i<NN){ sn[j]=S[i]; aj[j]=ancP[(size_t)t*NN+i]; pj[j]=prmP[(size_t)t*NN+i]; }
      else { sn[j]=0.0f; aj[j]=0; pj[j]=0.0f; }
    }
    __syncthreads();
    int bit=1<<t;
    #pragma unroll
    for(int j=0;j<NPL;j++){
      if(dep[j]>=bit) atomicAdd(&S[aj[j]], pj[j]*sn[j]);
    }
    __syncthreads();
  }

  // ---- downward init: b = (1-w^2)*A_up (root w=0 -> b=A_up) ----
  #pragma unroll
  for(int j=0;j<NPL;j++){
    int i=tid+j*TPF;
    if(i<NN){ float fq=1.0f-wv[j]*wv[j]; Sb[i]=fq*S[i]; }
  }
  __syncthreads();

  // ---- downward rounds (copy-free ping-pong) ----
  float* Sp=Sb; float* Sq=S;
  for(int t=0;t<T;t++){
    float bn[NPL];
    #pragma unroll
    for(int j=0;j<NPL;j++){
      int i=tid+j*TPF;
      if(i<NN){
        int a=ancP[(size_t)t*NN+i]; float ai=prmP[(size_t)t*NN+i];
        bn[j]=fmaf(ai,Sp[a],Sp[i]);
      } else bn[j]=0.0f;
    }
    __syncthreads();
    #pragma unroll
    for(int j=0;j<NPL;j++){
      int i=tid+j*TPF;
      if(i<NN) Sq[i]=bn[j];
    }
    __syncthreads();
    { float* tmp=Sp; Sp=Sq; Sq=tmp; }
  }
  // a == 0 for all nodes after T rounds (2^T > maxD) -> F = b
  float* o=Fout+(size_t)blockIdx.x*NN;
  for(int i=tid;i<NN;i+=TPF) o[i]=Sp[i];
}

// ---------------------------------------------------------------------------
__global__ __launch_bounds__(TPB) void k_div0(const float* __restrict__ FA,
                                              float* __restrict__ AS){
  int t=blockIdx.x*TPB+threadIdx.x;
  if(t>=BB*KK*NN) return;
  int b=t/(KK*NN), rem=t-b*(KK*NN), c=rem/NN, i=rem-c*NN;
  float inv=1.0f/FA[((size_t)b*5+4)*NN+i];
  AS[t]=FA[((size_t)b*5+c)*NN+i]*inv;
}

// ---------------------------------------------------------------------------
__global__ __launch_bounds__(TPB) void k_loss(
  const float* __restrict__ FB, const float* __restrict__ probf,
  const float* __restrict__ rois, float* __restrict__ partials)
{
  __shared__ float red[TPB];
  const int tid=threadIdx.x;
  const int fb=blockIdx.x;          // 0..23
  const int b=fb&7;
  const float* pb=probf+(size_t)b*KK*NN;
  float part=0.0f;
  for(int i=tid;i<NN;i+=TPB){
    int r=i/WW, c2=i-r*WW;
    float roi=rois[(size_t)b*(192*192)+(4*r)*192+(4*c2)];
    float inv=1.0f/FB[((size_t)fb*5+4)*NN+i];
    float s=fabsf(pb[i]      -FB[((size_t)fb*5+0)*NN+i]*inv)
          + fabsf(pb[NN+i]   -FB[((size_t)fb*5+1)*NN+i]*inv)
          + fabsf(pb[2*NN+i] -FB[((size_t)fb*5+2)*NN+i]*inv)
          + fabsf(pb[3*NN+i] -FB[((size_t)fb*5+3)*NN+i]*inv);
    part+=roi*s;
  }
  red[tid]=part; __syncthreads();
  for(int s2=TPB/2;s2>0;s2>>=1){ if(tid<s2) red[tid]+=red[tid+s2]; __syncthreads(); }
  if(tid==0) partials[fb]=red[0];
}

// ---------------------------------------------------------------------------
__global__ __launch_bounds__(TPB) void k_final(const float* __restrict__ rois,
    const float* __restrict__ partials, const float* __restrict__ wt,
    float* __restrict__ out)
{
  __shared__ float red[TPB];
  const int tid=threadIdx.x;
  float n=0.0f;
  for(int t=tid;t<BB*NN;t+=TPB){
    int b=t/NN, i=t-b*NN; int r=i/WW, c=i-r*WW;
    n += rois[(size_t)b*(192*192)+(4*r)*192+(4*c)];
  }
  red[tid]=n; __syncthreads();
  for(int s=TPB/2;s>0;s>>=1){ if(tid<s) red[tid]+=red[tid+s]; __syncthreads(); }
  if(tid==0){
    float loss=0.0f;
    for(int j=0;j<3*BB;j++) loss+=partials[j];
    float N=red[0];
    out[0]=wt[0]*((N>0.0f)?(loss/N):loss);
  }
}

// ---------------------------------------------------------------------------
extern "C" void kernel_launch(void* const* d_in, const int* in_sizes, int n_in,
                              void* d_out, int out_size, void* d_ws, size_t ws_size,
                              hipStream_t stream) {
  (void)in_sizes; (void)n_in; (void)out_size;
  const float* preds=(const float*)d_in[0];
  const float* lowf =(const float*)d_in[1];
  const float* hf1  =(const float*)d_in[2];
  const float* hf2  =(const float*)d_in[3];
  const float* hf3  =(const float*)d_in[4];
  const float* rois =(const float*)d_in[5];
  const float* wt   =(const float*)d_in[6];
  float* out=(float*)d_out;

  char* ws=(char*)d_ws;
  float* partials=(float*)ws;                                  // 24 floats @0
  float* probf=(float*)(ws+256);                               // 294,912 B
  float* AS   =(float*)(ws+256+(size_t)BB*KK*NN*4);            // 294,912 B
  size_t sb_off=256+(size_t)2*BB*KK*NN*4;                      // 590,080
  int*   sbase=(int*)(ws+sb_off);                              // 1,180,672 B
  size_t dk_off=sb_off+(size_t)32*SSTRIDE_W*4;                 // 1,770,752 (8-mult)
  double* dkeyG=(double*)(ws+dk_off);                          // 1,155,072 B
  size_t pl_off=dk_off+(size_t)32*EEE*8;                       // 2,925,824
  double* pd_low=(double*)(ws+pl_off);                         // 288,768 B
  size_t ph_off=pl_off+(size_t)8*EEE*8;                        // 3,214,592
  double* pd_hf=(double*)(ws+ph_off);                          // 24*nchunk*EEE*8

  // table/F buffers ALIAS pd_hf (dead after k_redux); 8.56 MB <= 13.86 MB floor.
  int*   ancT =(int*)  (ws+ph_off);                            // 3,538,944 B
  float* prodT=(float*)(ws+ph_off+(size_t)32*MAXT*NN*4);       // 3,538,944 B
  float* FA   =(float*)(ws+ph_off+(size_t)2*32*MAXT*NN*4);     // 40*NN*4
  float* FB   =(float*)(ws+ph_off+(size_t)2*32*MAXT*NN*4+(size_t)40*NN*4); // 120*NN*4

  int nchunk=32;
  if(ph_off+(size_t)24*32*EEE*8>ws_size) nchunk=16;

  const int nEB=8+24*nchunk;
  const int nSM=(BB*NN+TPE-1)/TPE;    // softmax blocks appended to k_edges
  k_edges<<<nEB+nSM,TPE,0,stream>>>(lowf,hf1,hf2,hf3,preds,probf,pd_low,pd_hf,nchunk);
  k_redux<<<(32*EEE+TPB-1)/TPB,TPB,0,stream>>>(pd_low,pd_hf,nchunk,dkeyG);
  k_struct<<<32,TPW,0,stream>>>(dkeyG,sbase,ancT,prodT);
  k_fchan<<<40,TPF,0,stream>>>(probf,FA,sbase,ancT,prodT,0);
  k_div0<<<(BB*KK*NN+TPB-1)/TPB,TPB,0,stream>>>(FA,AS);
  k_fchan<<<120,TPF,0,stream>>>(AS,FB,sbase,ancT,prodT,8);
  k_loss<<<3*BB,TPB,0,stream>>>(FB,probf,rois,partials);
  k_final<<<1,TPB,0,stream>>>(rois,partials,wt,out);
}

// Round 15
// 212.189 us; speedup vs baseline: 3.4293x; 1.0436x over previous
//
#include <hip/hip_runtime.h>
#include <math.h>

// ---------------------------------------------------------------------------
// TreeEnergyLoss on MI355X.
// k_edges (softmax blocks merged in; chunked f64 edge distances via
// LDS-upsampled embeddings) -> k_redux (parallel fixed-order chunk sum ->
// dkeyG) -> k_struct (FUSED: 1024t Boruvka MST with SINGLE-SWEEP packed-key
// argmin ((dist_hi,edge) lexicographic == reference's stable Kruskal order)
// + Euler-tour rooting via Wyllie + pointer-doubling level tables) ->
// k_fchan (one block per (problem,channel) value-only doubling passes;
// forest-123 variant divides FA on load, absorbing old k_div0) ->
// k_loss / k_final.
// ---------------------------------------------------------------------------

#define HH 48
#define WW 48
#define NN (HH*WW)          // 2304 nodes
#define EHH (HH*(WW-1))     // 2256 horizontal edges
#define EEE (2*EHH)         // 4512 edges
#define BB 8
#define KK 4
#define TPB 256
#define TPE 512             // edges kernel
#define TPW 1024            // struct kernel
#define TPF 512             // fchan kernel
#define NPL 5               // nodes per lane in fchan (ceil 2304/512)
#define NPN 5               // nodes per thread in k_edges (ceil 2304/512)
#define ESLOT (4*NN)        // 9216 directed-edge slots
#define LVE (2*(NN-1))      // 4606 valid directed edges
#define RIPT ((LVE+TPW-1)/TPW)  // 5 scan items per thread
#define SENTN 0xFFFFu
#define MAXT 12             // 2^12 = 4096 > max possible depth (2303)

// per-problem structure record in ws (ints): node-indexed int4 (parent,w,depth,0) | maxdepth
#define SSTRIDE_W (4*NN+8)
#define PK_OFF 0
#define D_OFF (4*NN)

__device__ __forceinline__ void edge_uv(int e,int& u,int& v){
  if(e<EHH){ int r=e/(WW-1); int c=e-r*(WW-1); u=r*WW+c; v=u+1; }
  else     { int t=e-EHH; u=t; v=t+WW; }
}

__device__ __forceinline__ void pick_src(int f, const float* lowf, const float* hf1,
                                         const float* hf2, const float* hf3,
                                         const float*& src, int& sh, int& C){
  if(f==0){src=lowf; sh=192; C=3;}
  else if(f==1){src=hf1; sh=24; C=512;}
  else if(f==2){src=hf2; sh=12; C=512;}
  else        {src=hf3; sh=6;  C=512;}
}

// ---------------------------------------------------------------------------
// Edge-distance partials, with softmax blocks appended at the end of the grid.
__global__ __launch_bounds__(TPE) void k_edges(
  const float* __restrict__ lowf, const float* __restrict__ hf1,
  const float* __restrict__ hf2, const float* __restrict__ hf3,
  const float* __restrict__ preds, float* __restrict__ probf,
  double* __restrict__ pd_low, double* __restrict__ pd_hf, int nchunk)
{
  __shared__ float up[4*NN+64];   // 37120 B (pad: guarded-unused over-reads)
  __shared__ int   y0t[48], y1t[48];
  __shared__ float wyt[48];
  const int tid=threadIdx.x;
  const int nEB=8+24*nchunk;

  if(blockIdx.x>=nEB){            // ---- softmax blocks ----
    int t=(blockIdx.x-nEB)*TPE+tid;
    if(t<BB*NN){
      int b=t/NN, i=t-b*NN;
      const float* p=preds+(size_t)b*KK*NN+i;
      float x0=p[0],x1=p[NN],x2=p[2*NN],x3=p[3*NN];
      float mx=fmaxf(fmaxf(x0,x1),fmaxf(x2,x3));
      float e0=expf(x0-mx),e1=expf(x1-mx),e2=expf(x2-mx),e3=expf(x3-mx);
      float s=((e0+e1)+(e2+e3));
      float* q=probf+(size_t)b*KK*NN+i;
      q[0]=e0/s; q[NN]=e1/s; q[2*NN]=e2/s; q[3*NN]=e3/s;
    }
    return;
  }

  int pidx, chunk, hfidx=0;
  if(blockIdx.x<8){ pidx=blockIdx.x; chunk=0; }
  else { int t=blockIdx.x-8; hfidx=t/nchunk; chunk=t-hfidx*nchunk; pidx=8+hfidx; }
  const int f=pidx>>3, b=pidx&7;
  const float* src; int sh,C;
  pick_src(f,lowf,hf1,hf2,hf3,src,sh,C);
  const int shw=sh*sh;
  const float* srcb=src+(size_t)b*C*shw;
  const int cpc=(f==0)?3:(512/nchunk);
  const int c_begin=chunk*cpc;
  const int c_end=(c_begin+cpc<C)?(c_begin+cpc):C;

  if(tid<48){
    float sy=(float)sh/48.0f;
    float ys=fmaxf(((float)tid+0.5f)*sy-0.5f,0.0f);
    int y0=(int)ys; if(y0>sh-1) y0=sh-1;
    int y1=y0+1; if(y1>sh-1) y1=sh-1;
    y0t[tid]=y0; y1t[tid]=y1; wyt[tid]=ys-(float)y0;
  }

  double accH[NPN], accV[NPN];
  #pragma unroll
  for(int j=0;j<NPN;j++){ accH[j]=0.0; accV[j]=0.0; }

  for(int c0=c_begin;c0<c_end;c0+=4){
    const int nc=(c_end-c0<4)?(c_end-c0):4;
    __syncthreads();               // protect previous sub-stage reads (and table init)
    for(int i=tid;i<NN;i+=TPE){
      int r=i/WW, c=i-r*WW;
      int y0=y0t[r], y1=y1t[r]; float wy=wyt[r];
      int x0=y0t[c], x1=y1t[c]; float wx=wyt[c];
      float w00=(1.0f-wy)*(1.0f-wx), w01=(1.0f-wy)*wx;
      float w10=wy*(1.0f-wx),        w11=wy*wx;
      int o00=y0*sh+x0, o01=y0*sh+x1, o10=y1*sh+x0, o11=y1*sh+x1;
      const float* pl=srcb+(size_t)c0*shw;
      for(int cc=0;cc<nc;cc++){
        const float* p=pl+(size_t)cc*shw;
        up[cc*NN+i]=w00*p[o00]+w01*p[o01]+w10*p[o10]+w11*p[o11];
      }
    }
    __syncthreads();
    #pragma unroll
    for(int j=0;j<NPN;j++){
      int u=tid+j*TPE;
      if(u<NN){
        int r=u/WW, c=u-r*WW;
        bool hOK=(c<WW-1), vOK=(r<HH-1);
        for(int cc=0;cc<nc;cc++){
          const float* pu=up+cc*NN+u;
          float a=pu[0], b1=pu[1], c1=pu[WW];
          if(hOK){ double d=(double)a-(double)b1; accH[j]=fma(d,d,accH[j]); }
          if(vOK){ double d=(double)a-(double)c1; accV[j]=fma(d,d,accV[j]); }
        }
      }
    }
  }
  double* outp=(f==0)? pd_low+(size_t)pidx*EEE
                     : pd_hf+((size_t)hfidx*nchunk+chunk)*EEE;
  #pragma unroll
  for(int j=0;j<NPN;j++){
    int u=tid+j*TPE;
    if(u<NN){
      int r=u/WW, c=u-r*WW;
      if(c<WW-1) outp[r*(WW-1)+c]=accH[j];
      if(r<HH-1) outp[EHH+u]=accV[j];
    }
  }
}

// ---------------------------------------------------------------------------
// Parallel fixed-order chunk reduction: dkeyG[pidx][e].
__global__ __launch_bounds__(TPB) void k_redux(
  const double* __restrict__ pd_low, const double* __restrict__ pd_hf,
  int nchunk, double* __restrict__ dkeyG)
{
  int t=blockIdx.x*TPB+threadIdx.x;
  if(t>=32*EEE) return;
  int pidx=t/EEE, e=t-pidx*EEE;
  double s;
  if(pidx<8) s=pd_low[(size_t)pidx*EEE+e];
  else {
    const double* p0=pd_hf+((size_t)(pidx-8)*nchunk)*EEE+e;
    s=0.0;
    for(int k=0;k<nchunk;k++) s+=p0[(size_t)k*EEE];
  }
  dkeyG[t]=s;
}

// ---------------------------------------------------------------------------
// FUSED structure kernel: Boruvka MST (single-sweep packed-key argmin) ->
// Euler-tour rooting (Wyllie) -> pointer-doubling level tables.
// key(e) = (dist_bits & ~0x1FFF) | e : strict lexicographic (dist_hi, edge)
// order; identical-dist structural ties resolve to min edge index == the
// reference's stable-Kruskal tie-break.  True f64 dist for weights is
// re-read from global dkeyG at emission.
__global__ __launch_bounds__(TPW) void k_struct(
  const double* __restrict__ dkeyG, int* __restrict__ sbase,
  int* __restrict__ ancT, float* __restrict__ prodT)
{
  __shared__ __align__(16) char smem[123600];
  // phase A (Boruvka):
  unsigned long long* keyE =(unsigned long long*)(smem+0);     // [0,36096)
  unsigned char*      mstf =(unsigned char*)(smem+36096);      // [36096,40608)
  unsigned long long* best =(unsigned long long*)(smem+40608); // [40608,59040)
  int*                comp =(int*)(smem+59040);                // [59040,68256)
  unsigned short*     uE   =(unsigned short*)(smem+68256);     // [68256,77280)
  int*                lnk  =(int*)(smem+77472);                // [77472,86688)
  // transition (over dead best/uE and lnk):
  float4*             adjw =(float4*)(smem+40608);             // [40608,77472)
  unsigned char*      adjS =(unsigned char*)(smem+77472);      // [77472,79776)
  int*                chunkS=(int*)(smem+79776);               // [79776,83872)
  // phase B (root; over dead keyE/mstf):
  unsigned int*       eA   =(unsigned int*)(smem+0);           // [0,36864)
  unsigned int*       eB   =(unsigned int*)(smem+86688);       // [86688,123552)
  int*                flags=(int*)(smem+123552);               // [123552,123568)
  // phase C (tables; over dead pos buffers):
  int*                ancA =(int*)(smem+0);
  float*              prmA =(float*)(smem+9216);
  int*                ancB =(int*)(smem+18432);
  float*              prmB =(float*)(smem+27648);

  const int tid=threadIdx.x;
  const int pidx=blockIdx.x;
  const int f=pidx>>3;
  const float sigma=(f==0)?0.02f:1.0f;
  const double* p0=dkeyG+(size_t)pidx*EEE;

  // ================= phase A: Boruvka (single-sweep packed keys) ==========
  {
    for(int e=tid;e<EEE;e+=TPW){
      int u,v; edge_uv(e,u,v);
      uE[e]=(unsigned short)u;
      keyE[e]=(((unsigned long long)__double_as_longlong(p0[e]))&~0x1FFFull)
              |(unsigned long long)e;
      mstf[e]=0;
    }
    for(int i=tid;i<NN;i+=TPW){ comp[i]=i; best[i]=~0ull; lnk[i]=i; }
    if(tid==0) flags[1]=0;
    __syncthreads();

    for(int round=0;round<20;++round){
      // single sweep: packed-key argmin per component (+ lnk re-init;
      // safe: lnk untouched until hook, one barrier away)
      for(int i=tid;i<NN;i+=TPW) lnk[i]=i;
      for(int e=tid;e<EEE;e+=TPW){
        int u=uE[e]; int v=(e<EHH)?u+1:u+WW;
        int cu=comp[u], cv=comp[v];
        if(cu!=cv){
          unsigned long long k=keyE[e];
          atomicMin(&best[cu],k);
          atomicMin(&best[cv],k);
        }
      }
      __syncthreads();
      // hook (mutual pair resolved toward smaller id; mutual => SAME edge, order strict)
      for(int i=tid;i<NN;i+=TPW){
        if(comp[i]==i && best[i]!=~0ull){
          int e=(int)(best[i]&0x1FFFull);
          int u=uE[e]; int v=(e<EHH)?u+1:u+WW;
          int cu=comp[u], cv=comp[v];
          int other=(cu==i)?cv:cu;
          bool mutual=((best[other]&0x1FFFull)==(unsigned long long)e);
          if(!mutual || other<i){ lnk[i]=other; mstf[e]=1; flags[1]=1; }
        }
      }
      __syncthreads();
      if(flags[1]==0) break;
      // find (lock-free path-halving) + next-round init (disjoint arrays)
      {
        volatile int* vl=lnk;
        for(int i=tid;i<NN;i+=TPW){
          int x=comp[i];
          int p=vl[x];
          int gp=vl[p];
          while(p!=gp){
            vl[x]=gp;
            x=p; p=gp; gp=vl[p];
          }
          comp[i]=p;
        }
      }
      for(int i=tid;i<NN;i+=TPW) best[i]=~0ull;
      if(tid==0) flags[1]=0;
      __syncthreads();
    }
    __syncthreads();

    // ---- transition: adjS (mask) + adjw (weights; true dist from global) --
    for(int i=tid;i<NN;i+=TPW){
      int r=i/WW, c=i-r*WW;
      int mask=0; float4 w; w.x=0.0f; w.y=0.0f; w.z=0.0f; w.w=0.0f;
      if(c>0    && mstf[r*(WW-1)+c-1]){ mask|=1; w.x=expf(-(float)p0[r*(WW-1)+c-1]/sigma); }
      if(c<WW-1 && mstf[r*(WW-1)+c])  { mask|=2; w.y=expf(-(float)p0[r*(WW-1)+c]/sigma); }
      if(r>0    && mstf[EHH+i-WW])    { mask|=4; w.z=expf(-(float)p0[EHH+i-WW]/sigma); }
      if(r<HH-1 && mstf[EHH+i])       { mask|=8; w.w=expf(-(float)p0[EHH+i]/sigma); }
      adjw[i]=w;
      adjS[i]=(unsigned char)mask;
    }
    if(tid==0) flags[2]=0;   // maxdepth accumulator
    __syncthreads();
  }

  // ================= phase B: Euler-tour rooting =================
  {
    const int m0=adjS[0];
    const int d0=(m0&1)?0:((m0&2)?1:((m0&4)?2:3));
    const int e0=d0;   // node 0 * 4 + d0

    for(int t=tid;t<ESLOT;t+=TPW){
      int u=t>>2, d=t&3;
      unsigned int pk=0;
      if(adjS[u]&(1<<d)){
        int v=(d==0)?u-1:(d==1)?u+1:(d==2)?u-WW:u+WW;
        int rd=d^1;
        int mv=adjS[v];
        int nd=rd;
        #pragma unroll
        for(int k2=4;k2>=1;k2--){ int dd=(rd+k2)&3; if(mv&(1<<dd)) nd=dd; }
        int ne=(v<<2)|nd;
        unsigned int nxt=(ne==e0)?SENTN:(unsigned int)ne;
        pk=(nxt<<16)|1u;
      }
      eA[t]=pk;
    }
    __syncthreads();

    unsigned int* P=eA; unsigned int* Q=eB;
    for(int r2=0;r2<13;r2++){
      for(int t=tid;t<ESLOT;t+=TPW){
        unsigned int pk=P[t];
        unsigned int dist=pk&0xFFFFu, nxt=pk>>16;
        if(dist && nxt!=SENTN){
          unsigned int pk2=P[nxt];
          dist+=pk2&0xFFFFu;
          nxt=pk2>>16;
          pk=(nxt<<16)|dist;
        }
        Q[t]=pk;
      }
      __syncthreads();
      unsigned int* tmp=P; P=Q; Q=tmp;
    }
    for(int t=tid;t<ESLOT;t+=TPW){
      unsigned int dist=P[t]&0xFFFFu;
      Q[t]=dist?(unsigned int)(LVE-(int)dist):0xFFFFFFFFu;
    }
    __syncthreads();

    int* scanA=(int*)P;
    for(int t=tid;t<ESLOT;t+=TPW){
      unsigned int pos=Q[t];
      if(pos!=0xFFFFFFFFu){
        int u=t>>2, d=t&3;
        int v=(d==0)?u-1:(d==1)?u+1:(d==2)?u-WW:u+WW;
        unsigned int rpos=Q[(v<<2)|(d^1)];
        scanA[pos]=(pos<rpos)?1:-1;
      }
    }
    __syncthreads();

    // ---- blocked inclusive scan (wave-shfl; 2 barriers) ----
    const int base=tid*RIPT;
    int vals[RIPT]; int lsum=0;
    #pragma unroll
    for(int j=0;j<RIPT;j++){
      int p=base+j;
      int v=(p<LVE)?scanA[p]:0;
      lsum+=v; vals[j]=lsum;
    }
    const int lane=tid&63, wid=tid>>6;   // 16 waves
    int x=lsum;
    #pragma unroll
    for(int off=1;off<64;off<<=1){
      int y=__shfl_up(x,off,64);
      if(lane>=off) x+=y;
    }
    if(lane==63) chunkS[wid]=x;          // wave totals
    __syncthreads();
    if(wid==0 && lane<16){
      int w=chunkS[lane];
      #pragma unroll
      for(int off=1;off<16;off<<=1){
        int y=__shfl_up(w,off,64);
        if(lane>=off) w+=y;
      }
      chunkS[lane]=w;
    }
    __syncthreads();
    const int waveoff=(wid>0)?chunkS[wid-1]:0;
    const int myoff=x+waveoff-lsum;      // == sum of lsum for tid' < tid
    int mymax=0;
    #pragma unroll
    for(int j=0;j<RIPT;j++){
      int p=base+j;
      if(p<LVE){ int s=vals[j]+myoff; scanA[p]=s; if(s>mymax) mymax=s; }
    }
    if(mymax>0) atomicMax(&flags[2],mymax);
    __syncthreads();

    int* sp=sbase+(size_t)pidx*SSTRIDE_W;
    int4* g_pk=(int4*)(sp+PK_OFF);
    if(tid==0){
      g_pk[0]=make_int4(0,__float_as_int(0.0f),0,0);
      sp[D_OFF]=flags[2];
    }
    for(int t=tid;t<ESLOT;t+=TPW){
      unsigned int pos=Q[t];
      if(pos!=0xFFFFFFFFu){
        int u=t>>2, d=t&3;
        int v=(d==0)?u-1:(d==1)?u+1:(d==2)?u-WW:u+WW;
        unsigned int rpos=Q[(v<<2)|(d^1)];
        if(pos<rpos){                       // down edge: u = parent(v)
          float4 w4=adjw[u];
          float w=(d==0)?w4.x:(d==1)?w4.y:(d==2)?w4.z:w4.w;
          g_pk[v]=make_int4(u,__float_as_int(w),scanA[pos],0);
        }
      }
    }
    __syncthreads();   // g_pk visible to whole block (global, same-block sync)
  }

  // ================= phase C: level tables =================
  {
    const int* sp=sbase+(size_t)pidx*SSTRIDE_W;
    const int4* g_pk=(const int4*)(sp+PK_OFF);
    const int maxD=flags[2];
    int T=1; while((1<<T)<=maxD) T++;
    int* gA=ancT+(size_t)pidx*MAXT*NN;
    float* gP=prodT+(size_t)pidx*MAXT*NN;
    int* aP=ancA; int* aQ=ancB; float* pP=prmA; float* pQ=prmB;
    for(int i=tid;i<NN;i+=TPW){
      int4 rec=g_pk[i];
      aP[i]=rec.x; pP[i]=__int_as_float(rec.y);
      gA[i]=rec.x; gP[i]=pP[i];
    }
    __syncthreads();
    for(int t=1;t<T;t++){
      for(int i=tid;i<NN;i+=TPW){
        int a=aP[i];
        int a2=aP[a]; float pr=pP[i]*pP[a];
        aQ[i]=a2; pQ[i]=pr;
        gA[(size_t)t*NN+i]=a2; gP[(size_t)t*NN+i]=pr;
      }
      __syncthreads();
      { int* t1=aP; aP=aQ; aQ=t1; float* t2=pP; pP=pQ; pQ=t2; }
    }
  }
}

// ---------------------------------------------------------------------------
// Value-only tree filter, ONE (problem, channel) per block.
// dv=0: load X[(b*KK+c)*NN+i] directly.  dv=1: load FA 5-stride and divide by
// channel 4 on the fly (float-identical to the old k_div0 + load).
__global__ __launch_bounds__(TPF) void k_fchan(
  const float* __restrict__ X, float* __restrict__ Fout,
  const int* __restrict__ sbase, const int* __restrict__ ancT,
  const float* __restrict__ prodT, int pidx0, int dv)
{
  __shared__ float S[NN];    // 9216 B
  __shared__ float Sb[NN];   // 9216 B
  const int tid=threadIdx.x;
  const int pg=blockIdx.x/5, c=blockIdx.x%5;
  const int pidx=pidx0+pg;
  const int xb=pg&7;
  const int* sp=sbase+(size_t)pidx*SSTRIDE_W;
  const int4* g_pk=(const int4*)(sp+PK_OFF);
  const int maxD=sp[D_OFF];
  int T=1; while((1<<T)<=maxD) T++;
  const int* ancP=ancT+(size_t)pidx*MAXT*NN;
  const float* prmP=prodT+(size_t)pidx*MAXT*NN;

  int dep[NPL]; float wv[NPL];
  #pragma unroll
  for(int j=0;j<NPL;j++){
    int i=tid+j*TPF;
    if(i<NN){
      int4 rec=g_pk[i];
      dep[j]=rec.z; wv[j]=__int_as_float(rec.y);
      float val=1.0f;
      if(c<4){
        if(dv){
          float inv=1.0f/X[((size_t)xb*5+4)*NN+i];
          val=X[((size_t)xb*5+c)*NN+i]*inv;
        } else {
          val=X[((size_t)xb*KK+c)*NN+i];
        }
      }
      S[i]=val;
    } else { dep[j]=-1; wv[j]=0.0f; }
  }
  __syncthreads();

  // ---- upward ----
  for(int t=0;t<T;t++){
    float sn[NPL]; int aj[NPL]; float pj[NPL];
    #pragma unroll
    for(int j=0;j<NPL;j++){
      int i=tid+j*TPF;
      if(i<NN){ sn[j]=S[i]; aj[j]=ancP[(size_t)t*NN+i]; pj[j]=prmP[(size_t)t*NN+i]; }
      else { sn[j]=0.0f; aj[j]=0; pj[j]=0.0f; }
    }
    __syncthreads();
    int bit=1<<t;
    #pragma unroll
    for(int j=0;j<NPL;j++){
      if(dep[j]>=bit) atomicAdd(&S[aj[j]], pj[j]*sn[j]);
    }
    __syncthreads();
  }

  // ---- downward init: b = (1-w^2)*A_up (root w=0 -> b=A_up) ----
  #pragma unroll
  for(int j=0;j<NPL;j++){
    int i=tid+j*TPF;
    if(i<NN){ float fq=1.0f-wv[j]*wv[j]; Sb[i]=fq*S[i]; }
  }
  __syncthreads();

  // ---- downward rounds (copy-free ping-pong) ----
  float* Sp=Sb; float* Sq=S;
  for(int t=0;t<T;t++){
    float bn[NPL];
    #pragma unroll
    for(int j=0;j<NPL;j++){
      int i=tid+j*TPF;
      if(i<NN){
        int a=ancP[(size_t)t*NN+i]; float ai=prmP[(size_t)t*NN+i];
        bn[j]=fmaf(ai,Sp[a],Sp[i]);
      } else bn[j]=0.0f;
    }
    __syncthreads();
    #pragma unroll
    for(int j=0;j<NPL;j++){
      int i=tid+j*TPF;
      if(i<NN) Sq[i]=bn[j];
    }
    __syncthreads();
    { float* tmp=Sp; Sp=Sq; Sq=tmp; }
  }
  // a == 0 for all nodes after T rounds (2^T > maxD) -> F = b
  float* o=Fout+(size_t)blockIdx.x*NN;
  for(int i=tid;i<NN;i+=TPF) o[i]=Sp[i];
}

// ---------------------------------------------------------------------------
__global__ __launch_bounds__(TPB) void k_loss(
  const float* __restrict__ FB, const float* __restrict__ probf,
  const float* __restrict__ rois, float* __restrict__ partials)
{
  __shared__ float red[TPB];
  const int tid=threadIdx.x;
  const int fb=blockIdx.x;          // 0..23
  const int b=fb&7;
  const float* pb=probf+(size_t)b*KK*NN;
  float part=0.0f;
  for(int i=tid;i<NN;i+=TPB){
    int r=i/WW, c2=i-r*WW;
    float roi=rois[(size_t)b*(192*192)+(4*r)*192+(4*c2)];
    float inv=1.0f/FB[((size_t)fb*5+4)*NN+i];
    float s=fabsf(pb[i]      -FB[((size_t)fb*5+0)*NN+i]*inv)
          + fabsf(pb[NN+i]   -FB[((size_t)fb*5+1)*NN+i]*inv)
          + fabsf(pb[2*NN+i] -FB[((size_t)fb*5+2)*NN+i]*inv)
          + fabsf(pb[3*NN+i] -FB[((size_t)fb*5+3)*NN+i]*inv);
    part+=roi*s;
  }
  red[tid]=part; __syncthreads();
  for(int s2=TPB/2;s2>0;s2>>=1){ if(tid<s2) red[tid]+=red[tid+s2]; __syncthreads(); }
  if(tid==0) partials[fb]=red[0];
}

// ---------------------------------------------------------------------------
__global__ __launch_bounds__(TPB) void k_final(const float* __restrict__ rois,
    const float* __restrict__ partials, const float* __restrict__ wt,
    float* __restrict__ out)
{
  __shared__ float red[TPB];
  const int tid=threadIdx.x;
  float n=0.0f;
  for(int t=tid;t<BB*NN;t+=TPB){
    int b=t/NN, i=t-b*NN; int r=i/WW, c=i-r*WW;
    n += rois[(size_t)b*(192*192)+(4*r)*192+(4*c)];
  }
  red[tid]=n; __syncthreads();
  for(int s=TPB/2;s>0;s>>=1){ if(tid<s) red[tid]+=red[tid+s]; __syncthreads(); }
  if(tid==0){
    float loss=0.0f;
    for(int j=0;j<3*BB;j++) loss+=partials[j];
    float N=red[0];
    out[0]=wt[0]*((N>0.0f)?(loss/N):loss);
  }
}

// ---------------------------------------------------------------------------
extern "C" void kernel_launch(void* const* d_in, const int* in_sizes, int n_in,
                              void* d_out, int out_size, void* d_ws, size_t ws_size,
                              hipStream_t stream) {
  (void)in_sizes; (void)n_in; (void)out_size;
  const float* preds=(const float*)d_in[0];
  const float* lowf =(const float*)d_in[1];
  const float* hf1  =(const float*)d_in[2];
  const float* hf2  =(const float*)d_in[3];
  const float* hf3  =(const float*)d_in[4];
  const float* rois =(const float*)d_in[5];
  const float* wt   =(const float*)d_in[6];
  float* out=(float*)d_out;

  char* ws=(char*)d_ws;
  float* partials=(float*)ws;                                  // 24 floats @0
  float* probf=(float*)(ws+256);                               // 294,912 B
  size_t sb_off=256+(size_t)2*BB*KK*NN*4;                      // 590,080
  int*   sbase=(int*)(ws+sb_off);                              // 1,180,672 B
  size_t dk_off=sb_off+(size_t)32*SSTRIDE_W*4;                 // 1,770,752 (8-mult)
  double* dkeyG=(double*)(ws+dk_off);                          // 1,155,072 B
  size_t pl_off=dk_off+(size_t)32*EEE*8;                       // 2,925,824
  double* pd_low=(double*)(ws+pl_off);                         // 288,768 B
  size_t ph_off=pl_off+(size_t)8*EEE*8;                        // 3,214,592
  double* pd_hf=(double*)(ws+ph_off);                          // 24*nchunk*EEE*8

  // table/F buffers ALIAS pd_hf (dead after k_redux); 8.56 MB <= 13.86 MB floor.
  int*   ancT =(int*)  (ws+ph_off);                            // 3,538,944 B
  float* prodT=(float*)(ws+ph_off+(size_t)32*MAXT*NN*4);       // 3,538,944 B
  float* FA   =(float*)(ws+ph_off+(size_t)2*32*MAXT*NN*4);     // 40*NN*4
  float* FB   =(float*)(ws+ph_off+(size_t)2*32*MAXT*NN*4+(size_t)40*NN*4); // 120*NN*4

  int nchunk=32;
  if(ph_off+(size_t)24*32*EEE*8>ws_size) nchunk=16;

  const int nEB=8+24*nchunk;
  const int nSM=(BB*NN+TPE-1)/TPE;    // softmax blocks appended to k_edges
  k_edges<<<nEB+nSM,TPE,0,stream>>>(lowf,hf1,hf2,hf3,preds,probf,pd_low,pd_hf,nchunk);
  k_redux<<<(32*EEE+TPB-1)/TPB,TPB,0,stream>>>(pd_low,pd_hf,nchunk,dkeyG);
  k_struct<<<32,TPW,0,stream>>>(dkeyG,sbase,ancT,prodT);
  k_fchan<<<40,TPF,0,stream>>>(probf,FA,sbase,ancT,prodT,0,0);
  k_fchan<<<120,TPF,0,stream>>>(FA,FB,sbase,ancT,prodT,8,1);
  k_loss<<<3*BB,TPB,0,stream>>>(FB,probf,rois,partials);
  k_final<<<1,TPB,0,stream>>>(rois,partials,wt,out);
}

// Round 16
// 206.675 us; speedup vs baseline: 3.5208x; 1.0267x over previous
//
#include <hip/hip_runtime.h>
#include <math.h>

// ---------------------------------------------------------------------------
// TreeEnergyLoss on MI355X.
// k_edges (softmax merged; chunked f64 edge distances via LDS-upsampled
// embeddings) -> k_redux (parallel fixed-order chunk sum -> dkeyG; zeroes the
// loss completion counter) -> k_struct (FUSED: 1024t Boruvka MST, single-sweep
// packed-key argmin ((dist_hi,edge) lexicographic == reference's stable
// Kruskal order) + COMPACTED Euler-tour rooting via Wyllie over exactly
// 2(N-1) slots + packed int2 pointer-doubling level tables) -> k_fchan
// (one block per (problem,channel); forest-123 divides on load) -> k_loss
// (ROI-masked L1 partials + last-block final reduction, absorbing k_final).
// ---------------------------------------------------------------------------

#define HH 48
#define WW 48
#define NN (HH*WW)          // 2304 nodes
#define EHH (HH*(WW-1))     // 2256 horizontal edges
#define EEE (2*EHH)         // 4512 edges
#define BB 8
#define KK 4
#define TPB 256
#define TPE 512             // edges kernel
#define TPW 1024            // struct kernel
#define TPF 512             // fchan kernel
#define NPL 5               // nodes per lane in fchan (ceil 2304/512)
#define NPN 5               // nodes per thread in k_edges (ceil 2304/512)
#define LVE (2*(NN-1))      // 4606 directed tree edges
#define RIPT ((LVE+TPW-1)/TPW)  // 5 scan items per thread
#define NIPT ((NN+TPW-1)/TPW)   // 3 node items per thread
#define SENTN 0xFFFFu
#define MAXT 12             // 2^12 = 4096 > max possible depth (2303)

// per-problem structure record in ws (ints): node-indexed int4 (parent,w,depth,0) | maxdepth
#define SSTRIDE_W (4*NN+8)
#define PK_OFF 0
#define D_OFF (4*NN)

__device__ __forceinline__ void edge_uv(int e,int& u,int& v){
  if(e<EHH){ int r=e/(WW-1); int c=e-r*(WW-1); u=r*WW+c; v=u+1; }
  else     { int t=e-EHH; u=t; v=t+WW; }
}

__device__ __forceinline__ void pick_src(int f, const float* lowf, const float* hf1,
                                         const float* hf2, const float* hf3,
                                         const float*& src, int& sh, int& C){
  if(f==0){src=lowf; sh=192; C=3;}
  else if(f==1){src=hf1; sh=24; C=512;}
  else if(f==2){src=hf2; sh=12; C=512;}
  else        {src=hf3; sh=6;  C=512;}
}

// ---------------------------------------------------------------------------
// Edge-distance partials, with softmax blocks appended at the end of the grid.
__global__ __launch_bounds__(TPE) void k_edges(
  const float* __restrict__ lowf, const float* __restrict__ hf1,
  const float* __restrict__ hf2, const float* __restrict__ hf3,
  const float* __restrict__ preds, float* __restrict__ probf,
  double* __restrict__ pd_low, double* __restrict__ pd_hf, int nchunk)
{
  __shared__ float up[4*NN+64];   // 37120 B (pad: guarded-unused over-reads)
  __shared__ int   y0t[48], y1t[48];
  __shared__ float wyt[48];
  const int tid=threadIdx.x;
  const int nEB=8+24*nchunk;

  if(blockIdx.x>=nEB){            // ---- softmax blocks ----
    int t=(blockIdx.x-nEB)*TPE+tid;
    if(t<BB*NN){
      int b=t/NN, i=t-b*NN;
      const float* p=preds+(size_t)b*KK*NN+i;
      float x0=p[0],x1=p[NN],x2=p[2*NN],x3=p[3*NN];
      float mx=fmaxf(fmaxf(x0,x1),fmaxf(x2,x3));
      float e0=expf(x0-mx),e1=expf(x1-mx),e2=expf(x2-mx),e3=expf(x3-mx);
      float s=((e0+e1)+(e2+e3));
      float* q=probf+(size_t)b*KK*NN+i;
      q[0]=e0/s; q[NN]=e1/s; q[2*NN]=e2/s; q[3*NN]=e3/s;
    }
    return;
  }

  int pidx, chunk, hfidx=0;
  if(blockIdx.x<8){ pidx=blockIdx.x; chunk=0; }
  else { int t=blockIdx.x-8; hfidx=t/nchunk; chunk=t-hfidx*nchunk; pidx=8+hfidx; }
  const int f=pidx>>3, b=pidx&7;
  const float* src; int sh,C;
  pick_src(f,lowf,hf1,hf2,hf3,src,sh,C);
  const int shw=sh*sh;
  const float* srcb=src+(size_t)b*C*shw;
  const int cpc=(f==0)?3:(512/nchunk);
  const int c_begin=chunk*cpc;
  const int c_end=(c_begin+cpc<C)?(c_begin+cpc):C;

  if(tid<48){
    float sy=(float)sh/48.0f;
    float ys=fmaxf(((float)tid+0.5f)*sy-0.5f,0.0f);
    int y0=(int)ys; if(y0>sh-1) y0=sh-1;
    int y1=y0+1; if(y1>sh-1) y1=sh-1;
    y0t[tid]=y0; y1t[tid]=y1; wyt[tid]=ys-(float)y0;
  }

  double accH[NPN], accV[NPN];
  #pragma unroll
  for(int j=0;j<NPN;j++){ accH[j]=0.0; accV[j]=0.0; }

  for(int c0=c_begin;c0<c_end;c0+=4){
    const int nc=(c_end-c0<4)?(c_end-c0):4;
    __syncthreads();               // protect previous sub-stage reads (and table init)
    for(int i=tid;i<NN;i+=TPE){
      int r=i/WW, c=i-r*WW;
      int y0=y0t[r], y1=y1t[r]; float wy=wyt[r];
      int x0=y0t[c], x1=y1t[c]; float wx=wyt[c];
      float w00=(1.0f-wy)*(1.0f-wx), w01=(1.0f-wy)*wx;
      float w10=wy*(1.0f-wx),        w11=wy*wx;
      int o00=y0*sh+x0, o01=y0*sh+x1, o10=y1*sh+x0, o11=y1*sh+x1;
      const float* pl=srcb+(size_t)c0*shw;
      for(int cc=0;cc<nc;cc++){
        const float* p=pl+(size_t)cc*shw;
        up[cc*NN+i]=w00*p[o00]+w01*p[o01]+w10*p[o10]+w11*p[o11];
      }
    }
    __syncthreads();
    #pragma unroll
    for(int j=0;j<NPN;j++){
      int u=tid+j*TPE;
      if(u<NN){
        int r=u/WW, c=u-r*WW;
        bool hOK=(c<WW-1), vOK=(r<HH-1);
        for(int cc=0;cc<nc;cc++){
          const float* pu=up+cc*NN+u;
          float a=pu[0], b1=pu[1], c1=pu[WW];
          if(hOK){ double d=(double)a-(double)b1; accH[j]=fma(d,d,accH[j]); }
          if(vOK){ double d=(double)a-(double)c1; accV[j]=fma(d,d,accV[j]); }
        }
      }
    }
  }
  double* outp=(f==0)? pd_low+(size_t)pidx*EEE
                     : pd_hf+((size_t)hfidx*nchunk+chunk)*EEE;
  #pragma unroll
  for(int j=0;j<NPN;j++){
    int u=tid+j*TPE;
    if(u<NN){
      int r=u/WW, c=u-r*WW;
      if(c<WW-1) outp[r*(WW-1)+c]=accH[j];
      if(r<HH-1) outp[EHH+u]=accV[j];
    }
  }
}

// ---------------------------------------------------------------------------
// Parallel fixed-order chunk reduction: dkeyG[pidx][e].  Also zeroes the
// loss completion counter for this call.
__global__ __launch_bounds__(TPB) void k_redux(
  const double* __restrict__ pd_low, const double* __restrict__ pd_hf,
  int nchunk, double* __restrict__ dkeyG, int* __restrict__ cnt)
{
  int t=blockIdx.x*TPB+threadIdx.x;
  if(t==0) *cnt=0;
  if(t>=32*EEE) return;
  int pidx=t/EEE, e=t-pidx*EEE;
  double s;
  if(pidx<8) s=pd_low[(size_t)pidx*EEE+e];
  else {
    const double* p0=pd_hf+((size_t)(pidx-8)*nchunk)*EEE+e;
    s=0.0;
    for(int k=0;k<nchunk;k++) s+=p0[(size_t)k*EEE];
  }
  dkeyG[t]=s;
}

// ---------------------------------------------------------------------------
// FUSED structure kernel: Boruvka MST (single-sweep packed-key argmin) ->
// COMPACTED Euler-tour rooting (Wyllie over exactly LVE slots; dense ids via
// degree prefix-sum, id(u,d) = nodeoff[u] + rank(d in mask)) -> packed int2
// pointer-doubling level tables.  One 1024-thread block per (forest,batch).
__global__ __launch_bounds__(TPW) void k_struct(
  const double* __restrict__ dkeyG, int* __restrict__ sbase,
  int2* __restrict__ apT)
{
  __shared__ __align__(16) char smem[123600];
  // phase A (Boruvka):
  unsigned long long* keyE =(unsigned long long*)(smem+0);     // [0,36096)
  unsigned char*      mstf =(unsigned char*)(smem+36096);      // [36096,40608)
  unsigned long long* best =(unsigned long long*)(smem+40608); // [40608,59040)
  int*                comp =(int*)(smem+59040);                // [59040,68256)
  unsigned short*     uEdg =(unsigned short*)(smem+68256);     // [68256,77280)
  int*                lnk  =(int*)(smem+77472);                // [77472,86688)
  // transition (over dead best/uEdg and lnk):
  float4*             adjw =(float4*)(smem+40608);             // [40608,77472)
  unsigned char*      adjS =(unsigned char*)(smem+77472);      // [77472,79776)
  int*                chunkS=(int*)(smem+79776);               // [79776,83872)
  // phase B (compacted root; over dead keyE/mstf and the tail region):
  unsigned int*       eA   =(unsigned int*)(smem+0);           // [0,18432)
  unsigned int*       eB   =(unsigned int*)(smem+18432);       // [18432,36864)
  unsigned short*     uDE  =(unsigned short*)(smem+83872);     // [83872,93088)
  int*                nodeoff=(int*)(smem+93088);              // [93088,102308)
  int*                flags=(int*)(smem+123552);               // [123552,123568)
  // phase C (tables; over dead eA/eB):
  int*                ancA =(int*)(smem+0);
  float*              prmA =(float*)(smem+9216);
  int*                ancB =(int*)(smem+18432);
  float*              prmB =(float*)(smem+27648);

  const int tid=threadIdx.x;
  const int pidx=blockIdx.x;
  const int f=pidx>>3;
  const float sigma=(f==0)?0.02f:1.0f;
  const double* p0=dkeyG+(size_t)pidx*EEE;
  const int lane=tid&63, wid=tid>>6;   // 16 waves

  // ================= phase A: Boruvka (single-sweep packed keys) ==========
  {
    for(int e=tid;e<EEE;e+=TPW){
      int u,v; edge_uv(e,u,v);
      uEdg[e]=(unsigned short)u;
      keyE[e]=(((unsigned long long)__double_as_longlong(p0[e]))&~0x1FFFull)
              |(unsigned long long)e;
      mstf[e]=0;
    }
    for(int i=tid;i<NN;i+=TPW){ comp[i]=i; best[i]=~0ull; lnk[i]=i; }
    if(tid==0) flags[1]=0;
    __syncthreads();

    for(int round=0;round<20;++round){
      for(int i=tid;i<NN;i+=TPW) lnk[i]=i;
      for(int e=tid;e<EEE;e+=TPW){
        int u=uEdg[e]; int v=(e<EHH)?u+1:u+WW;
        int cu=comp[u], cv=comp[v];
        if(cu!=cv){
          unsigned long long k=keyE[e];
          atomicMin(&best[cu],k);
          atomicMin(&best[cv],k);
        }
      }
      __syncthreads();
      // hook (mutual pair resolved toward smaller id; mutual => SAME edge, order strict)
      for(int i=tid;i<NN;i+=TPW){
        if(comp[i]==i && best[i]!=~0ull){
          int e=(int)(best[i]&0x1FFFull);
          int u=uEdg[e]; int v=(e<EHH)?u+1:u+WW;
          int cu=comp[u], cv=comp[v];
          int other=(cu==i)?cv:cu;
          bool mutual=((best[other]&0x1FFFull)==(unsigned long long)e);
          if(!mutual || other<i){ lnk[i]=other; mstf[e]=1; flags[1]=1; }
        }
      }
      __syncthreads();
      if(flags[1]==0) break;
      // find (lock-free path-halving) + next-round init (disjoint arrays)
      {
        volatile int* vl=lnk;
        for(int i=tid;i<NN;i+=TPW){
          int x=comp[i];
          int p=vl[x];
          int gp=vl[p];
          while(p!=gp){
            vl[x]=gp;
            x=p; p=gp; gp=vl[p];
          }
          comp[i]=p;
        }
      }
      for(int i=tid;i<NN;i+=TPW) best[i]=~0ull;
      if(tid==0) flags[1]=0;
      __syncthreads();
    }
    __syncthreads();

    // ---- transition: adjS (mask) + adjw (weights; true dist from global) --
    for(int i=tid;i<NN;i+=TPW){
      int r=i/WW, c=i-r*WW;
      int mask=0; float4 w; w.x=0.0f; w.y=0.0f; w.z=0.0f; w.w=0.0f;
      if(c>0    && mstf[r*(WW-1)+c-1]){ mask|=1; w.x=expf(-(float)p0[r*(WW-1)+c-1]/sigma); }
      if(c<WW-1 && mstf[r*(WW-1)+c])  { mask|=2; w.y=expf(-(float)p0[r*(WW-1)+c]/sigma); }
      if(r>0    && mstf[EHH+i-WW])    { mask|=4; w.z=expf(-(float)p0[EHH+i-WW]/sigma); }
      if(r<HH-1 && mstf[EHH+i])       { mask|=8; w.w=expf(-(float)p0[EHH+i]/sigma); }
      adjw[i]=w;
      adjS[i]=(unsigned char)mask;
    }
    if(tid==0) flags[2]=0;   // maxdepth accumulator
    __syncthreads();
  }

  // ================= phase B: compacted Euler-tour rooting ================
  {
    // ---- degree prefix-sum -> nodeoff (exclusive), wave-shfl scan ----
    {
      const int base=tid*NIPT;
      int dg[NIPT], incl[NIPT]; int lsum=0;
      #pragma unroll
      for(int j=0;j<NIPT;j++){
        int i=base+j;
        dg[j]=(i<NN)?__popc((int)adjS[i]):0;
        lsum+=dg[j]; incl[j]=lsum;
      }
      int x=lsum;
      #pragma unroll
      for(int off=1;off<64;off<<=1){
        int y=__shfl_up(x,off,64);
        if(lane>=off) x+=y;
      }
      if(lane==63) chunkS[wid]=x;
      __syncthreads();
      if(wid==0 && lane<16){
        int w=chunkS[lane];
        #pragma unroll
        for(int off=1;off<16;off<<=1){
          int y=__shfl_up(w,off,64);
          if(lane>=off) w+=y;
        }
        chunkS[lane]=w;
      }
      __syncthreads();
      const int waveoff=(wid>0)?chunkS[wid-1]:0;
      const int myoff=x+waveoff-lsum;
      #pragma unroll
      for(int j=0;j<NIPT;j++){
        int i=base+j;
        if(i<NN) nodeoff[i]=myoff+incl[j]-dg[j];
      }
    }
    __syncthreads();

    // ---- build compact successor list (id = nodeoff[u] + rank(d)) ----
    for(int u=tid;u<NN;u+=TPW){
      int mu=adjS[u];
      int off=nodeoff[u];
      int m=mu;
      while(m){
        int d=__ffs(m)-1; m&=m-1;
        int ce=off+__popc(mu&((1<<d)-1));
        int v=(d==0)?u-1:(d==1)?u+1:(d==2)?u-WW:u+WW;
        int rd=d^1;
        int mv=adjS[v];
        int nd=rd;
        #pragma unroll
        for(int k2=4;k2>=1;k2--){ int dd=(rd+k2)&3; if(mv&(1<<dd)) nd=dd; }
        int ne=nodeoff[v]+__popc(mv&((1<<nd)-1));
        unsigned int nxt=(ne==0)?SENTN:(unsigned int)ne;   // slot 0 == tour start
        uDE[ce]=(unsigned short)((u<<2)|d);
        eA[ce]=(nxt<<16)|1u;
      }
    }
    __syncthreads();

    // ---- Wyllie doubling: 13 rounds over LVE slots ----
    unsigned int* P=eA; unsigned int* Q=eB;
    for(int r2=0;r2<13;r2++){
      for(int t=tid;t<LVE;t+=TPW){
        unsigned int pk=P[t];
        unsigned int dist=pk&0xFFFFu, nxt=pk>>16;
        if(nxt!=SENTN){
          unsigned int pk2=P[nxt];
          dist+=pk2&0xFFFFu;
          nxt=pk2>>16;
          pk=(nxt<<16)|dist;
        }
        Q[t]=pk;
      }
      __syncthreads();
      unsigned int* tmp=P; P=Q; Q=tmp;
    }
    for(int t=tid;t<LVE;t+=TPW){
      unsigned int dist=P[t]&0xFFFFu;
      Q[t]=(unsigned int)(LVE-(int)dist);
    }
    __syncthreads();

    // ---- scatter +-1 into scan array (down iff pos < pos(reverse)) ----
    int* scanA=(int*)P;
    for(int t=tid;t<LVE;t+=TPW){
      unsigned int pos=Q[t];
      int ud=uDE[t]; int u=ud>>2, d=ud&3;
      int v=(d==0)?u-1:(d==1)?u+1:(d==2)?u-WW:u+WW;
      int rce=nodeoff[v]+__popc(adjS[v]&((1<<(d^1))-1));
      unsigned int rpos=Q[rce];
      scanA[pos]=(pos<rpos)?1:-1;
    }
    __syncthreads();

    // ---- blocked inclusive scan (wave-shfl; 2 barriers) ----
    const int base=tid*RIPT;
    int vals[RIPT]; int lsum=0;
    #pragma unroll
    for(int j=0;j<RIPT;j++){
      int p=base+j;
      int v=(p<LVE)?scanA[p]:0;
      lsum+=v; vals[j]=lsum;
    }
    int x=lsum;
    #pragma unroll
    for(int off=1;off<64;off<<=1){
      int y=__shfl_up(x,off,64);
      if(lane>=off) x+=y;
    }
    if(lane==63) chunkS[wid]=x;          // wave totals
    __syncthreads();
    if(wid==0 && lane<16){
      int w=chunkS[lane];
      #pragma unroll
      for(int off=1;off<16;off<<=1){
        int y=__shfl_up(w,off,64);
        if(lane>=off) w+=y;
      }
      chunkS[lane]=w;
    }
    __syncthreads();
    const int waveoff=(wid>0)?chunkS[wid-1]:0;
    const int myoff=x+waveoff-lsum;      // == sum of lsum for tid' < tid
    int mymax=0;
    #pragma unroll
    for(int j=0;j<RIPT;j++){
      int p=base+j;
      if(p<LVE){ int s=vals[j]+myoff; scanA[p]=s; if(s>mymax) mymax=s; }
    }
    if(mymax>0) atomicMax(&flags[2],mymax);
    __syncthreads();

    int* sp=sbase+(size_t)pidx*SSTRIDE_W;
    int4* g_pk=(int4*)(sp+PK_OFF);
    if(tid==0){
      g_pk[0]=make_int4(0,__float_as_int(0.0f),0,0);
      sp[D_OFF]=flags[2];
    }
    for(int t=tid;t<LVE;t+=TPW){
      unsigned int pos=Q[t];
      int ud=uDE[t]; int u=ud>>2, d=ud&3;
      int v=(d==0)?u-1:(d==1)?u+1:(d==2)?u-WW:u+WW;
      int rce=nodeoff[v]+__popc(adjS[v]&((1<<(d^1))-1));
      unsigned int rpos=Q[rce];
      if(pos<rpos){                       // down edge: u = parent(v)
        float4 w4=adjw[u];
        float w=(d==0)?w4.x:(d==1)?w4.y:(d==2)?w4.z:w4.w;
        g_pk[v]=make_int4(u,__float_as_int(w),scanA[pos],0);
      }
    }
    __syncthreads();   // g_pk visible to whole block (global, same-block sync)
  }

  // ================= phase C: packed level tables =================
  {
    const int* sp=sbase+(size_t)pidx*SSTRIDE_W;
    const int4* g_pk=(const int4*)(sp+PK_OFF);
    const int maxD=flags[2];
    int T=1; while((1<<T)<=maxD) T++;
    int2* gAP=apT+(size_t)pidx*MAXT*NN;
    int* aP=ancA; int* aQ=ancB; float* pP=prmA; float* pQ=prmB;
    for(int i=tid;i<NN;i+=TPW){
      int4 rec=g_pk[i];
      aP[i]=rec.x; pP[i]=__int_as_float(rec.y);
      gAP[i]=make_int2(rec.x,rec.y);
    }
    __syncthreads();
    for(int t=1;t<T;t++){
      for(int i=tid;i<NN;i+=TPW){
        int a=aP[i];
        int a2=aP[a]; float pr=pP[i]*pP[a];
        aQ[i]=a2; pQ[i]=pr;
        gAP[(size_t)t*NN+i]=make_int2(a2,__float_as_int(pr));
      }
      __syncthreads();
      { int* t1=aP; aP=aQ; aQ=t1; float* t2=pP; pP=pQ; pQ=t2; }
    }
  }
}

// ---------------------------------------------------------------------------
// Value-only tree filter, ONE (problem, channel) per block.
// dv=0: load X[(b*KK+c)*NN+i].  dv=1: load FA 5-stride, divide by channel 4.
__global__ __launch_bounds__(TPF) void k_fchan(
  const float* __restrict__ X, float* __restrict__ Fout,
  const int* __restrict__ sbase, const int2* __restrict__ apT,
  int pidx0, int dv)
{
  __shared__ float S[NN];    // 9216 B
  __shared__ float Sb[NN];   // 9216 B
  const int tid=threadIdx.x;
  const int pg=blockIdx.x/5, c=blockIdx.x%5;
  const int pidx=pidx0+pg;
  const int xb=pg&7;
  const int* sp=sbase+(size_t)pidx*SSTRIDE_W;
  const int4* g_pk=(const int4*)(sp+PK_OFF);
  const int maxD=sp[D_OFF];
  int T=1; while((1<<T)<=maxD) T++;
  const int2* apP=apT+(size_t)pidx*MAXT*NN;

  int dep[NPL]; float wv[NPL];
  #pragma unroll
  for(int j=0;j<NPL;j++){
    int i=tid+j*TPF;
    if(i<NN){
      int4 rec=g_pk[i];
      dep[j]=rec.z; wv[j]=__int_as_float(rec.y);
      float val=1.0f;
      if(c<4){
        if(dv){
          float inv=1.0f/X[((size_t)xb*5+4)*NN+i];
          val=X[((size_t)xb*5+c)*NN+i]*inv;
        } else {
          val=X[((size_t)xb*KK+c)*NN+i];
        }
      }
      S[i]=val;
    } else { dep[j]=-1; wv[j]=0.0f; }
  }
  __syncthreads();

  // ---- upward ----
  for(int t=0;t<T;t++){
    float sn[NPL]; int aj[NPL]; float pj[NPL];
    #pragma unroll
    for(int j=0;j<NPL;j++){
      int i=tid+j*TPF;
      if(i<NN){
        int2 ap=apP[(size_t)t*NN+i];
        sn[j]=S[i]; aj[j]=ap.x; pj[j]=__int_as_float(ap.y);
      }
      else { sn[j]=0.0f; aj[j]=0; pj[j]=0.0f; }
    }
    __syncthreads();
    int bit=1<<t;
    #pragma unroll
    for(int j=0;j<NPL;j++){
      if(dep[j]>=bit) atomicAdd(&S[aj[j]], pj[j]*sn[j]);
    }
    __syncthreads();
  }

  // ---- downward init: b = (1-w^2)*A_up (root w=0 -> b=A_up) ----
  #pragma unroll
  for(int j=0;j<NPL;j++){
    int i=tid+j*TPF;
    if(i<NN){ float fq=1.0f-wv[j]*wv[j]; Sb[i]=fq*S[i]; }
  }
  __syncthreads();

  // ---- downward rounds (copy-free ping-pong) ----
  float* Sp=Sb; float* Sq=S;
  for(int t=0;t<T;t++){
    float bn[NPL];
    #pragma unroll
    for(int j=0;j<NPL;j++){
      int i=tid+j*TPF;
      if(i<NN){
        int2 ap=apP[(size_t)t*NN+i];
        bn[j]=fmaf(__int_as_float(ap.y),Sp[ap.x],Sp[i]);
      } else bn[j]=0.0f;
    }
    __syncthreads();
    #pragma unroll
    for(int j=0;j<NPL;j++){
      int i=tid+j*TPF;
      if(i<NN) Sq[i]=bn[j];
    }
    __syncthreads();
    { float* tmp=Sp; Sp=Sq; Sq=tmp; }
  }
  // a == 0 for all nodes after T rounds (2^T > maxD) -> F = b
  float* o=Fout+(size_t)blockIdx.x*NN;
  for(int i=tid;i<NN;i+=TPF) o[i]=Sp[i];
}

// ---------------------------------------------------------------------------
// ROI-masked L1 partials; the LAST block to finish also does the final
// reduction (fence + counter; partials are read in fixed order -> exact).
__global__ __launch_bounds__(TPB) void k_loss(
  const float* __restrict__ FB, const float* __restrict__ probf,
  const float* __restrict__ rois, float* __restrict__ partials,
  const float* __restrict__ wt, float* __restrict__ out, int* __restrict__ cnt)
{
  __shared__ float red[TPB];
  __shared__ int lastS;
  const int tid=threadIdx.x;
  const int fb=blockIdx.x;          // 0..23
  const int b=fb&7;
  const float* pb=probf+(size_t)b*KK*NN;
  float part=0.0f;
  for(int i=tid;i<NN;i+=TPB){
    int r=i/WW, c2=i-r*WW;
    float roi=rois[(size_t)b*(192*192)+(4*r)*192+(4*c2)];
    float inv=1.0f/FB[((size_t)fb*5+4)*NN+i];
    float s=fabsf(pb[i]      -FB[((size_t)fb*5+0)*NN+i]*inv)
          + fabsf(pb[NN+i]   -FB[((size_t)fb*5+1)*NN+i]*inv)
          + fabsf(pb[2*NN+i] -FB[((size_t)fb*5+2)*NN+i]*inv)
          + fabsf(pb[3*NN+i] -FB[((size_t)fb*5+3)*NN+i]*inv);
    part+=roi*s;
  }
  red[tid]=part; __syncthreads();
  for(int s2=TPB/2;s2>0;s2>>=1){ if(tid<s2) red[tid]+=red[tid+s2]; __syncthreads(); }
  if(tid==0){
    partials[fb]=red[0];
    __threadfence();
    int old=atomicAdd(cnt,1);
    lastS=(old==3*BB-1);
  }
  __syncthreads();
  if(!lastS) return;

  // ---- final reduction (exactly the old k_final) ----
  float n=0.0f;
  for(int t=tid;t<BB*NN;t+=TPB){
    int b2=t/NN, i=t-b2*NN; int r=i/WW, c=i-r*WW;
    n += rois[(size_t)b2*(192*192)+(4*r)*192+(4*c)];
  }
  red[tid]=n; __syncthreads();
  for(int s=TPB/2;s>0;s>>=1){ if(tid<s) red[tid]+=red[tid+s]; __syncthreads(); }
  if(tid==0){
    float loss=0.0f;
    for(int j=0;j<3*BB;j++) loss+=partials[j];
    float N=red[0];
    out[0]=wt[0]*((N>0.0f)?(loss/N):loss);
  }
}

// ---------------------------------------------------------------------------
extern "C" void kernel_launch(void* const* d_in, const int* in_sizes, int n_in,
                              void* d_out, int out_size, void* d_ws, size_t ws_size,
                              hipStream_t stream) {
  (void)in_sizes; (void)n_in; (void)out_size;
  const float* preds=(const float*)d_in[0];
  const float* lowf =(const float*)d_in[1];
  const float* hf1  =(const float*)d_in[2];
  const float* hf2  =(const float*)d_in[3];
  const float* hf3  =(const float*)d_in[4];
  const float* rois =(const float*)d_in[5];
  const float* wt   =(const float*)d_in[6];
  float* out=(float*)d_out;

  char* ws=(char*)d_ws;
  float* partials=(float*)ws;                                  // 24 floats @0
  int*   cnt=(int*)(ws+128);                                   // completion counter
  float* probf=(float*)(ws+256);                               // 294,912 B
  size_t sb_off=256+(size_t)2*BB*KK*NN*4;                      // 590,080
  int*   sbase=(int*)(ws+sb_off);                              // 1,180,672 B
  size_t dk_off=sb_off+(size_t)32*SSTRIDE_W*4;                 // 1,770,752 (8-mult)
  double* dkeyG=(double*)(ws+dk_off);                          // 1,155,072 B
  size_t pl_off=dk_off+(size_t)32*EEE*8;                       // 2,925,824
  double* pd_low=(double*)(ws+pl_off);                         // 288,768 B
  size_t ph_off=pl_off+(size_t)8*EEE*8;                        // 3,214,592
  double* pd_hf=(double*)(ws+ph_off);                          // 24*nchunk*EEE*8

  // table/F buffers ALIAS pd_hf (dead after k_redux); 8.56 MB <= 13.86 MB floor.
  int2*  apT=(int2*)(ws+ph_off);                               // 7,077,888 B
  float* FA =(float*)(ws+ph_off+(size_t)32*MAXT*NN*8);         // 40*NN*4
  float* FB =(float*)(ws+ph_off+(size_t)32*MAXT*NN*8+(size_t)40*NN*4); // 120*NN*4

  int nchunk=32;
  if(ph_off+(size_t)24*32*EEE*8>ws_size) nchunk=16;

  const int nEB=8+24*nchunk;
  const int nSM=(BB*NN+TPE-1)/TPE;    // softmax blocks appended to k_edges
  k_edges<<<nEB+nSM,TPE,0,stream>>>(lowf,hf1,hf2,hf3,preds,probf,pd_low,pd_hf,nchunk);
  k_redux<<<(32*EEE+TPB-1)/TPB,TPB,0,stream>>>(pd_low,pd_hf,nchunk,dkeyG,cnt);
  k_struct<<<32,TPW,0,stream>>>(dkeyG,sbase,apT);
  k_fchan<<<40,TPF,0,stream>>>(probf,FA,sbase,apT,0,0);
  k_fchan<<<120,TPF,0,stream>>>(FA,FB,sbase,apT,8,1);
  k_loss<<<3*BB,TPB,0,stream>>>(FB,probf,rois,partials,wt,out,cnt);
}